// Round 1
// baseline (1210.562 us; speedup 1.0000x reference)
//
#include <hip/hip_runtime.h>
#include <math.h>

constexpr int kB = 4, kN = 4096, kK = 16;
constexpr int kRows = kB * kN;          // 16384
constexpr float kEps = 1e-5f;
constexpr float kFltMax = 3.402823466e38f;

// ---------------- fc1: hpre = x @ fc1_w + fc1_b ----------------
__global__ void fc1_kernel(const float* __restrict__ x, const float* __restrict__ w,
                           const float* __restrict__ bias, float* __restrict__ out) {
  __shared__ float xs[16 * 64];
  __shared__ float ws[64 * 64];
  const int t = threadIdx.x;
  const int row0 = blockIdx.x * 16;
  #pragma unroll
  for (int i = 0; i < 4; ++i) xs[t + i * 256] = x[row0 * 64 + t + i * 256];
  #pragma unroll
  for (int i = 0; i < 16; ++i) ws[t + i * 256] = w[t + i * 256];
  __syncthreads();
  const int c = t & 63, rg = t >> 6;
  const float bc = bias[c];
  for (int rr = 0; rr < 4; ++rr) {
    const int r = rg + rr * 4;
    float acc = bc;
    #pragma unroll
    for (int kk = 0; kk < 64; ++kk) acc += xs[r * 64 + kk] * ws[kk * 64 + c];
    out[(row0 + r) * 64 + c] = acc;
  }
}

// ---------------- per-channel batchnorm stats over 16384 rows ----------------
__global__ void stats_kernel(const float* __restrict__ src, float* __restrict__ mu,
                             float* __restrict__ rs) {
  __shared__ double sd[256];
  __shared__ double sq2[256];
  const int c = blockIdx.x, t = threadIdx.x;
  double s = 0.0, s2 = 0.0;
  for (int i = t; i < kRows; i += 256) {
    float v = src[i * 64 + c];
    s += v; s2 += (double)v * (double)v;
  }
  sd[t] = s; sq2[t] = s2; __syncthreads();
  for (int off = 128; off > 0; off >>= 1) {
    if (t < off) { sd[t] += sd[t + off]; sq2[t] += sq2[t + off]; }
    __syncthreads();
  }
  if (t == 0) {
    double mean = sd[0] / (double)kRows;
    double var = sq2[0] / (double)kRows - mean * mean;
    mu[c] = (float)mean;
    rs[c] = (float)(1.0 / sqrt(var + (double)kEps));
  }
}

__global__ void bnrelu_kernel(const float* __restrict__ src, float* __restrict__ dst,
                              const float* __restrict__ g, const float* __restrict__ b,
                              const float* __restrict__ mu, const float* __restrict__ rs) {
  int i = blockIdx.x * 256 + threadIdx.x;
  int c = i & 63;
  float v = g[c] * (src[i] - mu[c]) * rs[c] + b[c];
  dst[i] = fmaxf(v, 0.0f);
}

// ---------------- qkv = h @ qkv_w (no bias) ----------------
__global__ void qkv_kernel(const float* __restrict__ h, const float* __restrict__ w,
                           float* __restrict__ out) {
  __shared__ float ws[64 * 192];
  __shared__ float hs[8 * 64];
  const int t = threadIdx.x;          // 192 threads
  const int row0 = blockIdx.x * 8;
  for (int j = t; j < 64 * 192; j += 192) ws[j] = w[j];
  for (int j = t; j < 512; j += 192) hs[j] = h[row0 * 64 + j];
  __syncthreads();
  for (int r = 0; r < 8; ++r) {
    float acc = 0.f;
    #pragma unroll
    for (int kk = 0; kk < 64; ++kk) acc += hs[r * 64 + kk] * ws[kk * 192 + t];
    out[(row0 + r) * 192 + t] = acc;
  }
}

__global__ void sq_kernel(const float* __restrict__ p, float* __restrict__ sq) {
  int i = blockIdx.x * 256 + threadIdx.x; // < 16384
  float x = p[i * 3], y = p[i * 3 + 1], z = p[i * 3 + 2];
  sq[i] = x * x + y * y + z * z;
}

// ---------------- kNN: partial top-16 over a quarter of the stream ----------------
__global__ void knn_partial_kernel(const float* __restrict__ p, const float* __restrict__ sq,
                                   float* __restrict__ pd, int* __restrict__ pi) {
  __shared__ float4 pts[256];
  const int t = threadIdx.x;          // 64
  const int bid = blockIdx.x;         // 1024
  const int s = bid & 3, qg = (bid >> 2) & 63, b = bid >> 8;
  const int n = qg * 64 + t;
  const int gq = b * kN + n;
  const float qx = p[gq * 3], qy = p[gq * 3 + 1], qz = p[gq * 3 + 2], sqq = sq[gq];
  float bd[kK]; int bi[kK];
  #pragma unroll
  for (int i = 0; i < kK; ++i) { bd[i] = kFltMax; bi[i] = 0; }
  float wval = kFltMax; int wslot = 0;
  for (int c0 = s * 1024; c0 < s * 1024 + 1024; c0 += 256) {
    __syncthreads();
    for (int jj = t; jj < 256; jj += 64) {
      int g = b * kN + c0 + jj;
      pts[jj] = make_float4(p[g * 3], p[g * 3 + 1], p[g * 3 + 2], sq[g]);
    }
    __syncthreads();
    #pragma unroll 4
    for (int jj = 0; jj < 256; ++jj) {
      float4 pt = pts[jj];
      float d2 = sqq + pt.w - 2.0f * (qx * pt.x + qy * pt.y + qz * pt.z);
      if (d2 < wval) {
        int j = c0 + jj;
        #pragma unroll
        for (int ss = 0; ss < kK; ++ss) if (ss == wslot) { bd[ss] = d2; bi[ss] = j; }
        wval = bd[0]; wslot = 0;
        #pragma unroll
        for (int ss = 1; ss < kK; ++ss) if (bd[ss] > wval) { wval = bd[ss]; wslot = ss; }
      }
    }
  }
  const int base = ((s * kB + b) * kN + n) * kK;
  #pragma unroll
  for (int i = 0; i < kK; ++i) { pd[base + i] = bd[i]; pi[base + i] = bi[i]; }
}

__global__ void knn_merge_kernel(const float* __restrict__ pd, const int* __restrict__ pi,
                                 int* __restrict__ idxf) {
  const int q = blockIdx.x * 256 + threadIdx.x;  // < 16384
  const int b = q >> 12, n = q & (kN - 1);
  float bd[kK]; int bi[kK];
  #pragma unroll
  for (int i = 0; i < kK; ++i) { bd[i] = kFltMax; bi[i] = 0; }
  float wval = kFltMax; int wslot = 0;
  for (int s = 0; s < 4; ++s) {   // ascending chunk order -> lower-index tie preference
    const int base = ((s * kB + b) * kN + n) * kK;
    #pragma unroll
    for (int i = 0; i < kK; ++i) {
      float d = pd[base + i]; int j = pi[base + i];
      if (d < wval) {
        #pragma unroll
        for (int ss = 0; ss < kK; ++ss) if (ss == wslot) { bd[ss] = d; bi[ss] = j; }
        wval = bd[0]; wslot = 0;
        #pragma unroll
        for (int ss = 1; ss < kK; ++ss) if (bd[ss] > wval) { wval = bd[ss]; wslot = ss; }
      }
    }
  }
  #pragma unroll
  for (int i = 0; i < kK; ++i) idxf[q * kK + i] = bi[i];
}

// ---------------- attention core: one block per (b,n) ----------------
__global__ __launch_bounds__(256) void attn_kernel(
    const float* __restrict__ p, const float* __restrict__ qkv,
    const int* __restrict__ idxf,
    const float* __restrict__ pos_w1, const float* __restrict__ pos_b1,
    const float* __restrict__ pos_w2, const float* __restrict__ pos_b2,
    const float* __restrict__ attn_w1, const float* __restrict__ attn_b1,
    const float* __restrict__ attn_w2, const float* __restrict__ attn_b2,
    float* __restrict__ agg) {
  __shared__ float qv[64];
  __shared__ float pns[4];
  __shared__ int   idxs[16];
  __shared__ float pjs[64];                       // [k][4]
  __shared__ __align__(16) float u_t[64 * 20];    // [c][k] stride 20 (b128-alignable, conflict-limited)
  __shared__ float vvv[16 * 64];                  // [k][c]
  __shared__ float pehid[16 * 32];                // [k][h]
  __shared__ __align__(16) float hid_t[256 * 20]; // [m][k] stride 20
  __shared__ float sim_s[16 * 64];                // [k][c]
  __shared__ float wbuf[4096];                    // staged w1/w2 chunk
  __shared__ float pw1s[96], pb1s[32], pw2s[2048], pb2s[64], b1s[256], b2s[64];

  const int t = threadIdx.x;
  const int bid = blockIdx.x;
  const int b = bid >> 12, n = bid & (kN - 1);
  const int rowg = b * kN + n;

  // phase 0: small weights + per-point data
  if (t < 96) pw1s[t] = pos_w1[t];
  if (t >= 96 && t < 128) pb1s[t - 96] = pos_b1[t - 96];
  for (int j = t; j < 2048; j += 256) pw2s[j] = pos_w2[j];
  if (t < 64) pb2s[t] = pos_b2[t];
  b1s[t] = attn_b1[t];
  if (t >= 128 && t < 192) b2s[t - 128] = attn_b2[t - 128];
  if (t < 64) qv[t] = qkv[rowg * 192 + t];
  if (t >= 192 && t < 208) idxs[t - 192] = idxf[rowg * 16 + (t - 192)];
  if (t >= 208 && t < 211) pns[t - 208] = p[rowg * 3 + (t - 208)];
  __syncthreads();

  // phase 2: gather kj -> u_t (= q - kj), vj -> vvv, pj
  if (t < 48) {
    int k = t / 3, d = t - k * 3;
    pjs[k * 4 + d] = p[(b * kN + idxs[k]) * 3 + d];
  }
  #pragma unroll
  for (int i = 0; i < 4; ++i) {
    int e = t + i * 256;
    int k = e >> 6, c = e & 63;
    const float* rowp = qkv + (b * kN + idxs[k]) * 192;
    u_t[c * 20 + k] = qv[c] - rowp[64 + c];
    vvv[k * 64 + c] = rowp[128 + c];
  }
  __syncthreads();

  // phase 3: pe hidden = relu(rel_pos @ pos_w1 + pos_b1)
  #pragma unroll
  for (int i = 0; i < 2; ++i) {
    int e = t + i * 256;
    int hh = e & 31, k = e >> 5;
    float rx = pns[0] - pjs[k * 4 + 0];
    float ry = pns[1] - pjs[k * 4 + 1];
    float rz = pns[2] - pjs[k * 4 + 2];
    float v = pb1s[hh] + rx * pw1s[hh] + ry * pw1s[32 + hh] + rz * pw1s[64 + hh];
    pehid[k * 32 + hh] = fmaxf(v, 0.0f);
  }
  __syncthreads();

  // phase 4: pe = hid @ pos_w2 + pos_b2 ; u += pe ; vv = vj + pe
  #pragma unroll
  for (int i = 0; i < 4; ++i) {
    int e = t + i * 256;
    int k = e >> 6, c = e & 63;
    float val = pb2s[c];
    #pragma unroll
    for (int hh = 0; hh < 32; ++hh) val += pehid[k * 32 + hh] * pw2s[hh * 64 + c];
    u_t[c * 20 + k] += val;
    vvv[k * 64 + c] += val;
  }
  __syncthreads();

  // phase 5: hid[k][m] = relu(sum_c u[k][c]*w1[c][m] + b1[m]) ; thread owns m = t
  float acc[16];
  {
    float bm = b1s[t];
    #pragma unroll
    for (int k = 0; k < 16; ++k) acc[k] = bm;
  }
  for (int ch = 0; ch < 4; ++ch) {
    #pragma unroll
    for (int j = 0; j < 16; ++j) wbuf[t + j * 256] = attn_w1[ch * 4096 + t + j * 256];
    __syncthreads();
    #pragma unroll
    for (int cc = 0; cc < 16; ++cc) {
      const int c = ch * 16 + cc;
      const float w = wbuf[cc * 256 + t];
      #pragma unroll
      for (int g = 0; g < 4; ++g) {
        const float4 u4 = *reinterpret_cast<const float4*>(&u_t[c * 20 + 4 * g]);
        acc[4 * g + 0] += u4.x * w;
        acc[4 * g + 1] += u4.y * w;
        acc[4 * g + 2] += u4.z * w;
        acc[4 * g + 3] += u4.w * w;
      }
    }
    __syncthreads();
  }
  #pragma unroll
  for (int k = 0; k < 16; ++k) hid_t[t * 20 + k] = fmaxf(acc[k], 0.0f);
  __syncthreads();

  // phase 6: sim[k][c] = sum_m hid[k][m]*w2[m][c] + b2[c]
  float acc2[4] = {0.f, 0.f, 0.f, 0.f};
  const int c6 = t & 63, kg = t >> 6;
  for (int ch = 0; ch < 4; ++ch) {
    #pragma unroll
    for (int j = 0; j < 16; ++j) wbuf[t + j * 256] = attn_w2[ch * 4096 + t + j * 256];
    __syncthreads();
    #pragma unroll
    for (int mm = 0; mm < 64; ++mm) {
      const int m = ch * 64 + mm;
      const float w = wbuf[mm * 64 + c6];
      const float4 h4 = *reinterpret_cast<const float4*>(&hid_t[m * 20 + 4 * kg]);
      acc2[0] += h4.x * w; acc2[1] += h4.y * w;
      acc2[2] += h4.z * w; acc2[3] += h4.w * w;
    }
    __syncthreads();
  }
  #pragma unroll
  for (int i = 0; i < 4; ++i) sim_s[(4 * kg + i) * 64 + c6] = acc2[i] + b2s[c6];
  __syncthreads();

  // phase 7: per-channel softmax over k, weighted sum of vv
  if (t < 64) {
    const int c = t;
    float e[16];
    float mx = -kFltMax;
    #pragma unroll
    for (int k = 0; k < 16; ++k) { e[k] = sim_s[k * 64 + c]; mx = fmaxf(mx, e[k]); }
    float sum = 0.f;
    #pragma unroll
    for (int k = 0; k < 16; ++k) { e[k] = __expf(e[k] - mx); sum += e[k]; }
    const float inv = 1.0f / sum;
    float a = 0.f;
    #pragma unroll
    for (int k = 0; k < 16; ++k) a += e[k] * vvv[k * 64 + c];
    agg[rowg * 64 + c] = a * inv;
  }
}

// ---------------- fc2 fused with bn2+relu+residual add ----------------
__global__ void fc2_kernel(const float* __restrict__ aggp, const float* __restrict__ hres,
                           const float* __restrict__ g2, const float* __restrict__ b2,
                           const float* __restrict__ mu2, const float* __restrict__ rs2,
                           const float* __restrict__ w, const float* __restrict__ bias,
                           float* __restrict__ z) {
  __shared__ float ss[16 * 64];
  __shared__ float ws[64 * 64];
  const int t = threadIdx.x;
  const int row0 = blockIdx.x * 16;
  #pragma unroll
  for (int i = 0; i < 4; ++i) {
    int e = t + i * 256;
    int c = e & 63;
    float a = aggp[row0 * 64 + e];
    float h2 = fmaxf(g2[c] * (a - mu2[c]) * rs2[c] + b2[c], 0.0f);
    ss[e] = h2 + hres[row0 * 64 + e];
  }
  #pragma unroll
  for (int i = 0; i < 16; ++i) ws[t + i * 256] = w[t + i * 256];
  __syncthreads();
  const int c = t & 63, rg = t >> 6;
  const float bc = bias[c];
  for (int rr = 0; rr < 4; ++rr) {
    const int r = rg + rr * 4;
    float acc = bc;
    #pragma unroll
    for (int kk = 0; kk < 64; ++kk) acc += ss[r * 64 + kk] * ws[kk * 64 + c];
    z[(row0 + r) * 64 + c] = acc;
  }
}

__global__ void final_kernel(const float* __restrict__ z, const float* __restrict__ g,
                             const float* __restrict__ b, const float* __restrict__ mu,
                             const float* __restrict__ rs, float* __restrict__ y) {
  int i = blockIdx.x * 256 + threadIdx.x;
  int c = i & 63;
  y[i] = fmaxf(g[c] * (z[i] - mu[c]) * rs[c] + b[c], 0.0f);
}

__global__ void copyp_kernel(const float* __restrict__ p, float* __restrict__ out) {
  int i = blockIdx.x * 256 + threadIdx.x;
  out[i] = p[i];
}

extern "C" void kernel_launch(void* const* d_in, const int* in_sizes, int n_in,
                              void* d_out, int out_size, void* d_ws, size_t ws_size,
                              hipStream_t stream) {
  const float* x       = (const float*)d_in[0];
  const float* p       = (const float*)d_in[1];
  const float* fc1_w   = (const float*)d_in[2];
  const float* fc1_b   = (const float*)d_in[3];
  const float* bn1_g   = (const float*)d_in[4];
  const float* bn1_b   = (const float*)d_in[5];
  const float* qkv_w   = (const float*)d_in[6];
  const float* pos_w1  = (const float*)d_in[7];
  const float* pos_b1  = (const float*)d_in[8];
  const float* pos_w2  = (const float*)d_in[9];
  const float* pos_b2  = (const float*)d_in[10];
  const float* attn_w1 = (const float*)d_in[11];
  const float* attn_b1 = (const float*)d_in[12];
  const float* attn_w2 = (const float*)d_in[13];
  const float* attn_b2 = (const float*)d_in[14];
  const float* bn2_g   = (const float*)d_in[15];
  const float* bn2_b   = (const float*)d_in[16];
  const float* fc2_w   = (const float*)d_in[17];
  const float* fc2_b   = (const float*)d_in[18];
  const float* bn3_g   = (const float*)d_in[19];
  const float* bn3_b   = (const float*)d_in[20];

  float* ws   = (float*)d_ws;
  float* h    = ws;                     // 1048576  (residual)
  float* qkvb = ws + 1048576;           // 3145728
  float* hpre = ws + 4194304;           // 1048576  (reused as pdist after bn1)
  float* aggv = ws + 5242880;           // 1048576
  float* z    = ws + 6291456;           // 1048576
  float* sq   = ws + 7340032;           // 16384
  float* st   = ws + 7356416;           // 384
  int*   pidx = (int*)(ws + 7356800);   // 1048576 ints
  int*   idxf = (int*)(ws + 8405376);   // 262144 ints
  float* pdist = hpre;

  float* mu1 = st,       *rs1 = st + 64;
  float* mu2 = st + 128, *rs2 = st + 192;
  float* mu3 = st + 256, *rs3 = st + 320;
  float* y = (float*)d_out;

  fc1_kernel<<<1024, 256, 0, stream>>>(x, fc1_w, fc1_b, hpre);
  stats_kernel<<<64, 256, 0, stream>>>(hpre, mu1, rs1);
  bnrelu_kernel<<<4096, 256, 0, stream>>>(hpre, h, bn1_g, bn1_b, mu1, rs1);
  qkv_kernel<<<2048, 192, 0, stream>>>(h, qkv_w, qkvb);
  sq_kernel<<<64, 256, 0, stream>>>(p, sq);
  knn_partial_kernel<<<1024, 64, 0, stream>>>(p, sq, pdist, pidx);
  knn_merge_kernel<<<64, 256, 0, stream>>>(pdist, pidx, idxf);
  attn_kernel<<<16384, 256, 0, stream>>>(p, qkvb, idxf, pos_w1, pos_b1, pos_w2, pos_b2,
                                         attn_w1, attn_b1, attn_w2, attn_b2, aggv);
  stats_kernel<<<64, 256, 0, stream>>>(aggv, mu2, rs2);
  fc2_kernel<<<1024, 256, 0, stream>>>(aggv, h, bn2_g, bn2_b, mu2, rs2, fc2_w, fc2_b, z);
  stats_kernel<<<64, 256, 0, stream>>>(z, mu3, rs3);
  final_kernel<<<4096, 256, 0, stream>>>(z, bn3_g, bn3_b, mu3, rs3, y);
  copyp_kernel<<<192, 256, 0, stream>>>(p, y + 1048576);
}

// Round 2
// 729.101 us; speedup vs baseline: 1.6603x; 1.6603x over previous
//
#include <hip/hip_runtime.h>
#include <math.h>

constexpr int kB = 4, kN = 4096, kK = 16;
constexpr int kRows = kB * kN;          // 16384
constexpr float kEps = 1e-5f;
constexpr float kFltMax = 3.402823466e38f;

typedef __attribute__((ext_vector_type(8))) short short8;
typedef __attribute__((ext_vector_type(4))) float f32x4;

__device__ __forceinline__ unsigned short f2bf(float x) {
  unsigned int u = __float_as_uint(x);
  unsigned int r = (u + 0x7fffu + ((u >> 16) & 1u)) >> 16;
  return (unsigned short)r;
}
__device__ __forceinline__ float bf2f(unsigned int b) {
  return __uint_as_float(b << 16);
}

// ---------------- fc1: hpre = x @ fc1_w + fc1_b ----------------
__global__ void fc1_kernel(const float* __restrict__ x, const float* __restrict__ w,
                           const float* __restrict__ bias, float* __restrict__ out) {
  __shared__ float xs[16 * 64];
  __shared__ float ws[64 * 64];
  const int t = threadIdx.x;
  const int row0 = blockIdx.x * 16;
  #pragma unroll
  for (int i = 0; i < 4; ++i) xs[t + i * 256] = x[row0 * 64 + t + i * 256];
  #pragma unroll
  for (int i = 0; i < 16; ++i) ws[t + i * 256] = w[t + i * 256];
  __syncthreads();
  const int c = t & 63, rg = t >> 6;
  const float bc = bias[c];
  for (int rr = 0; rr < 4; ++rr) {
    const int r = rg + rr * 4;
    float acc = bc;
    #pragma unroll
    for (int kk = 0; kk < 64; ++kk) acc += xs[r * 64 + kk] * ws[kk * 64 + c];
    out[(row0 + r) * 64 + c] = acc;
  }
}

// ---------------- batchnorm stats: coalesced partial pass + finalize ----------------
__global__ void stats_part_kernel(const float* __restrict__ src, float* __restrict__ part) {
  __shared__ float sb[256], sb2[256];
  const int t = threadIdx.x, blk = blockIdx.x;
  const int c = t & 63, rg = t >> 6;
  float s = 0.f, s2 = 0.f;
  for (int r = rg; r < 64; r += 4) {
    float v = src[(blk * 64 + r) * 64 + c];
    s += v; s2 += v * v;
  }
  sb[t] = s; sb2[t] = s2; __syncthreads();
  if (t < 64) {
    float ts  = sb[t] + sb[64 + t] + sb[128 + t] + sb[192 + t];
    float ts2 = sb2[t] + sb2[64 + t] + sb2[128 + t] + sb2[192 + t];
    part[blk * 128 + t] = ts;
    part[blk * 128 + 64 + t] = ts2;
  }
}

__global__ void stats_fin_kernel(const float* __restrict__ part, float* __restrict__ mu,
                                 float* __restrict__ rs) {
  const int c = threadIdx.x;  // 64
  double s = 0.0, s2 = 0.0;
  for (int i = 0; i < 256; ++i) { s += part[i * 128 + c]; s2 += part[i * 128 + 64 + c]; }
  double mean = s / (double)kRows;
  double var = s2 / (double)kRows - mean * mean;
  mu[c] = (float)mean;
  rs[c] = (float)(1.0 / sqrt(var + (double)kEps));
}

__global__ void bnrelu_kernel(const float* __restrict__ src, float* __restrict__ dst,
                              const float* __restrict__ g, const float* __restrict__ b,
                              const float* __restrict__ mu, const float* __restrict__ rs) {
  int i = blockIdx.x * 256 + threadIdx.x;
  int c = i & 63;
  float v = g[c] * (src[i] - mu[c]) * rs[c] + b[c];
  dst[i] = fmaxf(v, 0.0f);
}

// ---------------- qkv = h @ qkv_w (no bias) ----------------
__global__ void qkv_kernel(const float* __restrict__ h, const float* __restrict__ w,
                           float* __restrict__ out) {
  __shared__ float ws[64 * 192];
  __shared__ float hs[8 * 64];
  const int t = threadIdx.x;          // 192 threads
  const int row0 = blockIdx.x * 8;
  for (int j = t; j < 64 * 192; j += 192) ws[j] = w[j];
  for (int j = t; j < 512; j += 192) hs[j] = h[row0 * 64 + j];
  __syncthreads();
  for (int r = 0; r < 8; ++r) {
    float acc = 0.f;
    #pragma unroll
    for (int kk = 0; kk < 64; ++kk) acc += hs[r * 64 + kk] * ws[kk * 192 + t];
    out[(row0 + r) * 192 + t] = acc;
  }
}

__global__ void sq_kernel(const float* __restrict__ p, float* __restrict__ sq) {
  int i = blockIdx.x * 256 + threadIdx.x; // < 16384
  float x = p[i * 3], y = p[i * 3 + 1], z = p[i * 3 + 2];
  sq[i] = x * x + y * y + z * z;
}

// ---------------- kNN: partial top-16 over a quarter of the stream ----------------
__global__ void knn_partial_kernel(const float* __restrict__ p, const float* __restrict__ sq,
                                   float* __restrict__ pd, int* __restrict__ pi) {
  __shared__ float4 pts[256];
  const int t = threadIdx.x;          // 64
  const int bid = blockIdx.x;         // 1024
  const int s = bid & 3, qg = (bid >> 2) & 63, b = bid >> 8;
  const int n = qg * 64 + t;
  const int gq = b * kN + n;
  const float qx = p[gq * 3], qy = p[gq * 3 + 1], qz = p[gq * 3 + 2], sqq = sq[gq];
  float bd[kK]; int bi[kK];
  #pragma unroll
  for (int i = 0; i < kK; ++i) { bd[i] = kFltMax; bi[i] = 0; }
  float wval = kFltMax; int wslot = 0;
  for (int c0 = s * 1024; c0 < s * 1024 + 1024; c0 += 256) {
    __syncthreads();
    for (int jj = t; jj < 256; jj += 64) {
      int g = b * kN + c0 + jj;
      pts[jj] = make_float4(p[g * 3], p[g * 3 + 1], p[g * 3 + 2], sq[g]);
    }
    __syncthreads();
    #pragma unroll 4
    for (int jj = 0; jj < 256; ++jj) {
      float4 pt = pts[jj];
      float d2 = sqq + pt.w - 2.0f * (qx * pt.x + qy * pt.y + qz * pt.z);
      if (d2 < wval) {
        int j = c0 + jj;
        #pragma unroll
        for (int ss = 0; ss < kK; ++ss) if (ss == wslot) { bd[ss] = d2; bi[ss] = j; }
        wval = bd[0]; wslot = 0;
        #pragma unroll
        for (int ss = 1; ss < kK; ++ss) if (bd[ss] > wval) { wval = bd[ss]; wslot = ss; }
      }
    }
  }
  const int base = ((s * kB + b) * kN + n) * kK;
  #pragma unroll
  for (int i = 0; i < kK; ++i) { pd[base + i] = bd[i]; pi[base + i] = bi[i]; }
}

__global__ void knn_merge_kernel(const float* __restrict__ pd, const int* __restrict__ pi,
                                 int* __restrict__ idxf) {
  const int q = blockIdx.x * 256 + threadIdx.x;  // < 16384
  const int b = q >> 12, n = q & (kN - 1);
  float bd[kK]; int bi[kK];
  #pragma unroll
  for (int i = 0; i < kK; ++i) { bd[i] = kFltMax; bi[i] = 0; }
  float wval = kFltMax; int wslot = 0;
  for (int s = 0; s < 4; ++s) {   // ascending chunk order -> lower-index tie preference
    const int base = ((s * kB + b) * kN + n) * kK;
    #pragma unroll
    for (int i = 0; i < kK; ++i) {
      float d = pd[base + i]; int j = pi[base + i];
      if (d < wval) {
        #pragma unroll
        for (int ss = 0; ss < kK; ++ss) if (ss == wslot) { bd[ss] = d; bi[ss] = j; }
        wval = bd[0]; wslot = 0;
        #pragma unroll
        for (int ss = 1; ss < kK; ++ss) if (bd[ss] > wval) { wval = bd[ss]; wslot = ss; }
      }
    }
  }
  #pragma unroll
  for (int i = 0; i < kK; ++i) idxf[q * kK + i] = bi[i];
}

// ---------------- weight convert/transpose to bf16 (runs once per call) ----------------
__global__ void convert_w_kernel(const float* __restrict__ w1, const float* __restrict__ w2,
                                 const float* __restrict__ pw2,
                                 unsigned short* __restrict__ w1t,
                                 unsigned short* __restrict__ w2t,
                                 unsigned short* __restrict__ pw2t) {
  int id = blockIdx.x * 256 + threadIdx.x;
  if (id < 16384) {                       // w1t[h][c] = w1[c][h], 256x64
    int hh = id >> 6, c = id & 63;
    w1t[id] = f2bf(w1[c * 256 + hh]);
  } else if (id < 32768) {                // w2t[c][k2] = w2[k2][c], 64x256
    int i = id - 16384;
    int c = i >> 8, k2 = i & 255;
    w2t[i] = f2bf(w2[k2 * 64 + c]);
  } else if (id < 34816) {                // pw2t[c][h] = pw2[h][c], 64x32
    int i = id - 32768;
    int c = i >> 5, hh = i & 31;
    pw2t[i] = f2bf(pw2[hh * 64 + c]);
  }
}

// ---------------- fused MFMA attention: 4 points (64 rows) per block ----------------
// GEMM1 computed transposed (D = W1^T * U^T) so C-layout packs into row-major H.
__global__ __launch_bounds__(256) void attn_mfma_kernel(
    const float* __restrict__ p, const float* __restrict__ qkv,
    const int* __restrict__ idxf,
    const float* __restrict__ pos_w1, const float* __restrict__ pos_b1,
    const float* __restrict__ pos_b2,
    const float* __restrict__ attn_b1, const float* __restrict__ attn_b2,
    const unsigned short* __restrict__ w1t,   // [256][64] bf16
    const unsigned short* __restrict__ w2t,   // [64][256] bf16
    const unsigned short* __restrict__ pw2t,  // [64][32]  bf16
    float* __restrict__ agg) {
  __shared__ unsigned short Ulds[64 * 72];    // u = q - kj (+pe), bf16, stride 72
  __shared__ float VVlds[64 * 68];            // vv = vj (+pe), fp32, stride 68
  __shared__ unsigned short Hlds[64 * 264];   // H (relu'd hidden), bf16, stride 264
  __shared__ float qs[4 * 64];
  __shared__ int idxs[64];
  unsigned short* PEH = Hlds;                 // pehid [64][40] bf16 aliases H (dead before H written)

  const int t = threadIdx.x;
  const int blk = blockIdx.x;                 // 4096 blocks
  const int b = blk >> 10;                    // 1024 blocks per batch
  const int n0 = (blk & 1023) * 4;

  // phase 0: indices + q rows
  if (t < 64) idxs[t] = idxf[blk * 64 + t];
  {
    const int pt = t >> 6, c = t & 63;
    qs[pt * 64 + c] = qkv[(b * kN + n0 + pt) * 192 + c];
  }
  __syncthreads();

  // phase 1a: gather k/v, write U = bf16(q - kj), VV = vj
  {
    const int row = t >> 2, seg = t & 3;
    const int pt = row >> 4;
    const int jrow = (b * kN + idxs[row]) * 192;
    const float4* kb = reinterpret_cast<const float4*>(qkv + jrow + 64 + seg * 16);
    const float4* vb = reinterpret_cast<const float4*>(qkv + jrow + 128 + seg * 16);
    const float4* q4 = reinterpret_cast<const float4*>(&qs[pt * 64 + seg * 16]);
    #pragma unroll
    for (int i = 0; i < 4; ++i) {
      float4 kv = kb[i], vv4 = vb[i], qq = q4[i];
      int c = seg * 16 + i * 4;
      uint2 u2;
      u2.x = (unsigned int)f2bf(qq.x - kv.x) | ((unsigned int)f2bf(qq.y - kv.y) << 16);
      u2.y = (unsigned int)f2bf(qq.z - kv.z) | ((unsigned int)f2bf(qq.w - kv.w) << 16);
      *reinterpret_cast<uint2*>(&Ulds[row * 72 + c]) = u2;
      *reinterpret_cast<float4*>(&VVlds[row * 68 + c]) = vv4;
    }
  }
  // phase 1b: pe hidden layer (3->32), bf16 into PEH
  {
    const int row = t & 63, hs = t >> 6;
    const int pt = row >> 4;
    const float* pn = p + (b * kN + n0 + pt) * 3;
    const float* pj = p + (b * kN + idxs[row]) * 3;
    float rx = pn[0] - pj[0], ry = pn[1] - pj[1], rz = pn[2] - pj[2];
    unsigned short tmp[8];
    #pragma unroll
    for (int j = 0; j < 8; ++j) {
      int hh = hs * 8 + j;
      float v = pos_b1[hh] + rx * pos_w1[hh] + ry * pos_w1[32 + hh] + rz * pos_w1[64 + hh];
      tmp[j] = f2bf(fmaxf(v, 0.0f));
    }
    uint4 pk;
    pk.x = (unsigned int)tmp[0] | ((unsigned int)tmp[1] << 16);
    pk.y = (unsigned int)tmp[2] | ((unsigned int)tmp[3] << 16);
    pk.z = (unsigned int)tmp[4] | ((unsigned int)tmp[5] << 16);
    pk.w = (unsigned int)tmp[6] | ((unsigned int)tmp[7] << 16);
    *reinterpret_cast<uint4*>(&PEH[row * 40 + hs * 8]) = pk;
  }
  __syncthreads();

  const int w = t >> 6;
  const int lane = t & 63, l = lane & 15, quad = lane >> 4;
  const f32x4 zero = {0.f, 0.f, 0.f, 0.f};

  // phase 2: pe = pehid @ pos_w2 (transposed MFMA: D[c][row]); RMW U and VV
  {
    short8 pbf = *reinterpret_cast<const short8*>(&PEH[(w * 16 + l) * 40 + quad * 8]);
    const int row = w * 16 + l;
    #pragma unroll
    for (int mt = 0; mt < 4; ++mt) {
      short8 paf = *reinterpret_cast<const short8*>(&pw2t[(mt * 16 + l) * 32 + quad * 8]);
      f32x4 pe = __builtin_amdgcn_mfma_f32_16x16x32_bf16(paf, pbf, zero, 0, 0, 0);
      const int c0 = mt * 16 + quad * 4;
      float4 b2v = *reinterpret_cast<const float4*>(&pos_b2[c0]);
      float pe0 = pe[0] + b2v.x, pe1 = pe[1] + b2v.y;
      float pe2 = pe[2] + b2v.z, pe3 = pe[3] + b2v.w;
      uint2 u2 = *reinterpret_cast<uint2*>(&Ulds[row * 72 + c0]);
      float u0 = bf2f(u2.x & 0xffffu) + pe0;
      float u1 = bf2f(u2.x >> 16) + pe1;
      float u2f = bf2f(u2.y & 0xffffu) + pe2;
      float u3 = bf2f(u2.y >> 16) + pe3;
      uint2 o;
      o.x = (unsigned int)f2bf(u0) | ((unsigned int)f2bf(u1) << 16);
      o.y = (unsigned int)f2bf(u2f) | ((unsigned int)f2bf(u3) << 16);
      *reinterpret_cast<uint2*>(&Ulds[row * 72 + c0]) = o;
      float4 vv4 = *reinterpret_cast<float4*>(&VVlds[row * 68 + c0]);
      vv4.x += pe0; vv4.y += pe1; vv4.z += pe2; vv4.w += pe3;
      *reinterpret_cast<float4*>(&VVlds[row * 68 + c0]) = vv4;
    }
  }
  __syncthreads();

  // phase 3: GEMM1 transposed: H^T tiles, A = W1^T (from global), B = U (LDS)
  {
    const int row = w * 16 + l;
    short8 ub0 = *reinterpret_cast<const short8*>(&Ulds[row * 72 + quad * 8]);
    short8 ub1 = *reinterpret_cast<const short8*>(&Ulds[row * 72 + 32 + quad * 8]);
    f32x4 acc[16];
    #pragma unroll
    for (int mt = 0; mt < 16; ++mt) acc[mt] = zero;
    #pragma unroll
    for (int mt = 0; mt < 16; ++mt) {
      short8 a0 = *reinterpret_cast<const short8*>(&w1t[(mt * 16 + l) * 64 + quad * 8]);
      short8 a1 = *reinterpret_cast<const short8*>(&w1t[(mt * 16 + l) * 64 + 32 + quad * 8]);
      acc[mt] = __builtin_amdgcn_mfma_f32_16x16x32_bf16(a0, ub0, acc[mt], 0, 0, 0);
      acc[mt] = __builtin_amdgcn_mfma_f32_16x16x32_bf16(a1, ub1, acc[mt], 0, 0, 0);
    }
    __syncthreads();   // PEH (aliased in Hlds) fully consumed; safe to overwrite
    #pragma unroll
    for (int mt = 0; mt < 16; ++mt) {
      const int h0 = mt * 16 + quad * 4;
      float4 bb = *reinterpret_cast<const float4*>(&attn_b1[h0]);
      uint2 hw;
      hw.x = (unsigned int)f2bf(fmaxf(acc[mt][0] + bb.x, 0.f)) |
             ((unsigned int)f2bf(fmaxf(acc[mt][1] + bb.y, 0.f)) << 16);
      hw.y = (unsigned int)f2bf(fmaxf(acc[mt][2] + bb.z, 0.f)) |
             ((unsigned int)f2bf(fmaxf(acc[mt][3] + bb.w, 0.f)) << 16);
      *reinterpret_cast<uint2*>(&Hlds[row * 264 + h0]) = hw;
    }
  }
  __syncthreads();

  // phase 4: GEMM2: sim tiles D[row][c], A = H (LDS), B = W2^T (global); softmax + agg
  {
    f32x4 acc2[4];
    #pragma unroll
    for (int mt = 0; mt < 4; ++mt) acc2[mt] = zero;
    const int cw = w * 16 + l;
    #pragma unroll
    for (int f = 0; f < 8; ++f) {
      short8 bfr = *reinterpret_cast<const short8*>(&w2t[cw * 256 + f * 32 + quad * 8]);
      #pragma unroll
      for (int mt = 0; mt < 4; ++mt) {
        short8 afr = *reinterpret_cast<const short8*>(&Hlds[(mt * 16 + l) * 264 + f * 32 + quad * 8]);
        acc2[mt] = __builtin_amdgcn_mfma_f32_16x16x32_bf16(afr, bfr, acc2[mt], 0, 0, 0);
      }
    }
    const float b2v = attn_b2[cw];
    #pragma unroll
    for (int mt = 0; mt < 4; ++mt) {
      float s0 = acc2[mt][0] + b2v, s1 = acc2[mt][1] + b2v;
      float s2 = acc2[mt][2] + b2v, s3 = acc2[mt][3] + b2v;
      float mx = fmaxf(fmaxf(s0, s1), fmaxf(s2, s3));
      mx = fmaxf(mx, __shfl_xor(mx, 16, 64));
      mx = fmaxf(mx, __shfl_xor(mx, 32, 64));
      float e0 = __expf(s0 - mx), e1 = __expf(s1 - mx);
      float e2 = __expf(s2 - mx), e3 = __expf(s3 - mx);
      float se = e0 + e1 + e2 + e3;
      se += __shfl_xor(se, 16, 64);
      se += __shfl_xor(se, 32, 64);
      const float inv = 1.0f / se;
      const int rb = mt * 16 + quad * 4;
      float a = e0 * VVlds[(rb + 0) * 68 + cw] + e1 * VVlds[(rb + 1) * 68 + cw] +
                e2 * VVlds[(rb + 2) * 68 + cw] + e3 * VVlds[(rb + 3) * 68 + cw];
      a += __shfl_xor(a, 16, 64);
      a += __shfl_xor(a, 32, 64);
      if (quad == 0) agg[(blk * 4 + mt) * 64 + cw] = a * inv;
    }
  }
}

// ---------------- fc2 fused with bn2+relu+residual add ----------------
__global__ void fc2_kernel(const float* __restrict__ aggp, const float* __restrict__ hres,
                           const float* __restrict__ g2, const float* __restrict__ b2,
                           const float* __restrict__ mu2, const float* __restrict__ rs2,
                           const float* __restrict__ w, const float* __restrict__ bias,
                           float* __restrict__ z) {
  __shared__ float ss[16 * 64];
  __shared__ float ws[64 * 64];
  const int t = threadIdx.x;
  const int row0 = blockIdx.x * 16;
  #pragma unroll
  for (int i = 0; i < 4; ++i) {
    int e = t + i * 256;
    int c = e & 63;
    float a = aggp[row0 * 64 + e];
    float h2 = fmaxf(g2[c] * (a - mu2[c]) * rs2[c] + b2[c], 0.0f);
    ss[e] = h2 + hres[row0 * 64 + e];
  }
  #pragma unroll
  for (int i = 0; i < 16; ++i) ws[t + i * 256] = w[t + i * 256];
  __syncthreads();
  const int c = t & 63, rg = t >> 6;
  const float bc = bias[c];
  for (int rr = 0; rr < 4; ++rr) {
    const int r = rg + rr * 4;
    float acc = bc;
    #pragma unroll
    for (int kk = 0; kk < 64; ++kk) acc += ss[r * 64 + kk] * ws[kk * 64 + c];
    z[(row0 + r) * 64 + c] = acc;
  }
}

__global__ void final_kernel(const float* __restrict__ z, const float* __restrict__ g,
                             const float* __restrict__ b, const float* __restrict__ mu,
                             const float* __restrict__ rs, float* __restrict__ y) {
  int i = blockIdx.x * 256 + threadIdx.x;
  int c = i & 63;
  y[i] = fmaxf(g[c] * (z[i] - mu[c]) * rs[c] + b[c], 0.0f);
}

__global__ void copyp_kernel(const float* __restrict__ p, float* __restrict__ out) {
  int i = blockIdx.x * 256 + threadIdx.x;
  out[i] = p[i];
}

extern "C" void kernel_launch(void* const* d_in, const int* in_sizes, int n_in,
                              void* d_out, int out_size, void* d_ws, size_t ws_size,
                              hipStream_t stream) {
  const float* x       = (const float*)d_in[0];
  const float* p       = (const float*)d_in[1];
  const float* fc1_w   = (const float*)d_in[2];
  const float* fc1_b   = (const float*)d_in[3];
  const float* bn1_g   = (const float*)d_in[4];
  const float* bn1_b   = (const float*)d_in[5];
  const float* qkv_w   = (const float*)d_in[6];
  const float* pos_w1  = (const float*)d_in[7];
  const float* pos_b1  = (const float*)d_in[8];
  const float* pos_w2  = (const float*)d_in[9];
  const float* pos_b2  = (const float*)d_in[10];
  const float* attn_w1 = (const float*)d_in[11];
  const float* attn_b1 = (const float*)d_in[12];
  const float* attn_w2 = (const float*)d_in[13];
  const float* attn_b2 = (const float*)d_in[14];
  const float* bn2_g   = (const float*)d_in[15];
  const float* bn2_b   = (const float*)d_in[16];
  const float* fc2_w   = (const float*)d_in[17];
  const float* fc2_b   = (const float*)d_in[18];
  const float* bn3_g   = (const float*)d_in[19];
  const float* bn3_b   = (const float*)d_in[20];

  float* ws   = (float*)d_ws;
  float* h    = ws;                     // 1048576  (residual)
  float* qkvb = ws + 1048576;           // 3145728
  float* hpre = ws + 4194304;           // 1048576  (reused: pdist during knn, bf16 wts after)
  float* aggv = ws + 5242880;           // 1048576  (also partials for stats1/stats3)
  float* z    = ws + 6291456;           // 1048576  (also partials for stats2)
  float* sq   = ws + 7340032;           // 16384
  float* st   = ws + 7356416;           // 384
  int*   pidx = (int*)(ws + 7356800);   // 1048576 ints
  int*   idxf = (int*)(ws + 8405376);   // 262144 ints
  float* pdist = hpre;
  unsigned short* w1t  = (unsigned short*)hpre;         // 16384 bf16
  unsigned short* w2t  = w1t + 16384;                   // 16384 bf16
  unsigned short* pw2t = w1t + 32768;                   // 2048 bf16

  float* mu1 = st,       *rs1 = st + 64;
  float* mu2 = st + 128, *rs2 = st + 192;
  float* mu3 = st + 256, *rs3 = st + 320;
  float* y = (float*)d_out;

  fc1_kernel<<<1024, 256, 0, stream>>>(x, fc1_w, fc1_b, hpre);
  stats_part_kernel<<<256, 256, 0, stream>>>(hpre, aggv);
  stats_fin_kernel<<<1, 64, 0, stream>>>(aggv, mu1, rs1);
  bnrelu_kernel<<<4096, 256, 0, stream>>>(hpre, h, bn1_g, bn1_b, mu1, rs1);
  qkv_kernel<<<2048, 192, 0, stream>>>(h, qkv_w, qkvb);
  sq_kernel<<<64, 256, 0, stream>>>(p, sq);
  knn_partial_kernel<<<1024, 64, 0, stream>>>(p, sq, pdist, pidx);
  knn_merge_kernel<<<64, 256, 0, stream>>>(pdist, pidx, idxf);
  convert_w_kernel<<<136, 256, 0, stream>>>(attn_w1, attn_w2, pos_w2, w1t, w2t, pw2t);
  attn_mfma_kernel<<<4096, 256, 0, stream>>>(p, qkvb, idxf, pos_w1, pos_b1, pos_b2,
                                             attn_b1, attn_b2, w1t, w2t, pw2t, aggv);
  stats_part_kernel<<<256, 256, 0, stream>>>(aggv, z);
  stats_fin_kernel<<<1, 64, 0, stream>>>(z, mu2, rs2);
  fc2_kernel<<<1024, 256, 0, stream>>>(aggv, h, bn2_g, bn2_b, mu2, rs2, fc2_w, fc2_b, z);
  stats_part_kernel<<<256, 256, 0, stream>>>(z, aggv);
  stats_fin_kernel<<<1, 64, 0, stream>>>(aggv, mu3, rs3);
  final_kernel<<<4096, 256, 0, stream>>>(z, bn3_g, bn3_b, mu3, rs3, y);
  copyp_kernel<<<192, 256, 0, stream>>>(p, y + 1048576);
}

// Round 3
// 666.553 us; speedup vs baseline: 1.8162x; 1.0938x over previous
//
#include <hip/hip_runtime.h>
#include <math.h>

constexpr int kB = 4, kN = 4096, kK = 16;
constexpr int kRows = kB * kN;          // 16384
constexpr float kEps = 1e-5f;
constexpr float kFltMax = 3.402823466e38f;

typedef __attribute__((ext_vector_type(8))) short short8;
typedef __attribute__((ext_vector_type(4))) float f32x4;

__device__ __forceinline__ unsigned short f2bf(float x) {
  unsigned int u = __float_as_uint(x);
  unsigned int r = (u + 0x7fffu + ((u >> 16) & 1u)) >> 16;
  return (unsigned short)r;
}
__device__ __forceinline__ float bf2f(unsigned int b) {
  return __uint_as_float(b << 16);
}

// ---------------- fc1: hpre = x @ fc1_w + fc1_b ----------------
__global__ void fc1_kernel(const float* __restrict__ x, const float* __restrict__ w,
                           const float* __restrict__ bias, float* __restrict__ out) {
  __shared__ float xs[16 * 64];
  __shared__ float ws[64 * 64];
  const int t = threadIdx.x;
  const int row0 = blockIdx.x * 16;
  #pragma unroll
  for (int i = 0; i < 4; ++i) xs[t + i * 256] = x[row0 * 64 + t + i * 256];
  #pragma unroll
  for (int i = 0; i < 16; ++i) ws[t + i * 256] = w[t + i * 256];
  __syncthreads();
  const int c = t & 63, rg = t >> 6;
  const float bc = bias[c];
  for (int rr = 0; rr < 4; ++rr) {
    const int r = rg + rr * 4;
    float acc = bc;
    #pragma unroll
    for (int kk = 0; kk < 64; ++kk) acc += xs[r * 64 + kk] * ws[kk * 64 + c];
    out[(row0 + r) * 64 + c] = acc;
  }
}

// ---------------- batchnorm stats: coalesced partial pass + finalize ----------------
__global__ void stats_part_kernel(const float* __restrict__ src, float* __restrict__ part) {
  __shared__ float sb[256], sb2[256];
  const int t = threadIdx.x, blk = blockIdx.x;
  const int c = t & 63, rg = t >> 6;
  float s = 0.f, s2 = 0.f;
  for (int r = rg; r < 64; r += 4) {
    float v = src[(blk * 64 + r) * 64 + c];
    s += v; s2 += v * v;
  }
  sb[t] = s; sb2[t] = s2; __syncthreads();
  if (t < 64) {
    float ts  = sb[t] + sb[64 + t] + sb[128 + t] + sb[192 + t];
    float ts2 = sb2[t] + sb2[64 + t] + sb2[128 + t] + sb2[192 + t];
    part[blk * 128 + t] = ts;
    part[blk * 128 + 64 + t] = ts2;
  }
}

__global__ void stats_fin_kernel(const float* __restrict__ part, float* __restrict__ mu,
                                 float* __restrict__ rs) {
  const int c = threadIdx.x;  // 64
  double s = 0.0, s2 = 0.0;
  for (int i = 0; i < 256; ++i) { s += part[i * 128 + c]; s2 += part[i * 128 + 64 + c]; }
  double mean = s / (double)kRows;
  double var = s2 / (double)kRows - mean * mean;
  mu[c] = (float)mean;
  rs[c] = (float)(1.0 / sqrt(var + (double)kEps));
}

__global__ void bnrelu_kernel(const float* __restrict__ src, float* __restrict__ dst,
                              const float* __restrict__ g, const float* __restrict__ b,
                              const float* __restrict__ mu, const float* __restrict__ rs) {
  int i = blockIdx.x * 256 + threadIdx.x;
  int c = i & 63;
  float v = g[c] * (src[i] - mu[c]) * rs[c] + b[c];
  dst[i] = fmaxf(v, 0.0f);
}

// ---------------- qkv = h @ qkv_w (no bias) ----------------
__global__ void qkv_kernel(const float* __restrict__ h, const float* __restrict__ w,
                           float* __restrict__ out) {
  __shared__ float ws[64 * 192];
  __shared__ float hs[8 * 64];
  const int t = threadIdx.x;          // 192 threads
  const int row0 = blockIdx.x * 8;
  for (int j = t; j < 64 * 192; j += 192) ws[j] = w[j];
  for (int j = t; j < 512; j += 192) hs[j] = h[row0 * 64 + j];
  __syncthreads();
  for (int r = 0; r < 8; ++r) {
    float acc = 0.f;
    #pragma unroll
    for (int kk = 0; kk < 64; ++kk) acc += hs[r * 64 + kk] * ws[kk * 192 + t];
    out[(row0 + r) * 192 + t] = acc;
  }
}

__global__ void sq_kernel(const float* __restrict__ p, float* __restrict__ sq) {
  int i = blockIdx.x * 256 + threadIdx.x; // < 16384
  float x = p[i * 3], y = p[i * 3 + 1], z = p[i * 3 + 2];
  sq[i] = x * x + y * y + z * z;
}

// ---------------- kNN: wave-cooperative top-16, one wave per query ----------------
// 64 lanes evaluate 64 candidates; ballot finds qualifiers; serial insert only
// when needed (~105 inserts/query total). Lanes 0..15 hold the top-16 list.
__global__ __launch_bounds__(256) void knn_coop_kernel(
    const float* __restrict__ p, const float* __restrict__ sq,
    int* __restrict__ idxf) {
  __shared__ float4 pts[1024];     // 16 KB candidate chunk, shared by 4 waves
  const int t = threadIdx.x;
  const int lane = t & 63, w = t >> 6;
  const int blk = blockIdx.x;      // 4096 blocks, 4 queries each
  const int b = blk >> 10;         // batch
  const int q = blk * 4 + w;       // global query id (16384 total)
  const float qx = p[q * 3], qy = p[q * 3 + 1], qz = p[q * 3 + 2];
  const float sqq = sq[q];

  float bdv = kFltMax;             // lanes 0..15: stored distance
  int   bdi = 0;                   // lanes 0..15: stored index
  float wval = kFltMax;            // broadcast threshold (stale-high is safe)

  for (int c0 = 0; c0 < kN; c0 += 1024) {
    __syncthreads();
    #pragma unroll
    for (int i = 0; i < 4; ++i) {
      int j = t + i * 256;
      int g = b * kN + c0 + j;
      pts[j] = make_float4(p[g * 3], p[g * 3 + 1], p[g * 3 + 2], sq[g]);
    }
    __syncthreads();
    for (int i64 = 0; i64 < 16; ++i64) {
      float4 pt = pts[i64 * 64 + lane];
      float d2 = sqq + pt.w - 2.0f * (qx * pt.x + qy * pt.y + qz * pt.z);
      int cj = c0 + i64 * 64 + lane;
      unsigned long long m = __ballot(d2 < wval);
      while (m) {
        int src = __builtin_ctzll(m);
        m &= (m - 1);
        float dj = __shfl(d2, src);
        int   ij = __shfl(cj, src);
        // fresh argmax over the 16-entry list (butterfly within each 16-lane group;
        // group 0 is authoritative, then broadcast wave-wide from lane 0)
        float mv = bdv; int ml = lane & 15;
        #pragma unroll
        for (int s = 8; s >= 1; s >>= 1) {
          float ov = __shfl_xor(mv, s);
          int   ol = __shfl_xor(ml, s);
          if (ov > mv) { mv = ov; ml = ol; }
        }
        mv = __shfl(mv, 0);
        ml = __shfl(ml, 0);
        wval = mv;                  // tighten threshold for subsequent ballots
        if (dj < mv) {              // wave-uniform branch (dj, mv uniform)
          if (lane == ml) { bdv = dj; bdi = ij; }
        }
      }
    }
  }
  if (lane < 16) idxf[q * 16 + lane] = bdi;
}

// ---------------- weight convert/transpose to bf16 (runs once per call) ----------------
__global__ void convert_w_kernel(const float* __restrict__ w1, const float* __restrict__ w2,
                                 const float* __restrict__ pw2,
                                 unsigned short* __restrict__ w1t,
                                 unsigned short* __restrict__ w2t,
                                 unsigned short* __restrict__ pw2t) {
  int id = blockIdx.x * 256 + threadIdx.x;
  if (id < 16384) {                       // w1t[h][c] = w1[c][h], 256x64
    int hh = id >> 6, c = id & 63;
    w1t[id] = f2bf(w1[c * 256 + hh]);
  } else if (id < 32768) {                // w2t[c][k2] = w2[k2][c], 64x256
    int i = id - 16384;
    int c = i >> 8, k2 = i & 255;
    w2t[i] = f2bf(w2[k2 * 64 + c]);
  } else if (id < 34816) {                // pw2t[c][h] = pw2[h][c], 64x32
    int i = id - 32768;
    int c = i >> 5, hh = i & 31;
    pw2t[i] = f2bf(pw2[hh * 64 + c]);
  }
}

// ---------------- fused MFMA attention: 4 points (64 rows) per block ----------------
// GEMM1 computed transposed (D = W1^T * U^T) so C-layout packs into row-major H.
__global__ __launch_bounds__(256) void attn_mfma_kernel(
    const float* __restrict__ p, const float* __restrict__ qkv,
    const int* __restrict__ idxf,
    const float* __restrict__ pos_w1, const float* __restrict__ pos_b1,
    const float* __restrict__ pos_b2,
    const float* __restrict__ attn_b1, const float* __restrict__ attn_b2,
    const unsigned short* __restrict__ w1t,   // [256][64] bf16
    const unsigned short* __restrict__ w2t,   // [64][256] bf16
    const unsigned short* __restrict__ pw2t,  // [64][32]  bf16
    float* __restrict__ agg) {
  __shared__ unsigned short Ulds[64 * 72];    // u = q - kj (+pe), bf16, stride 72
  __shared__ float VVlds[64 * 68];            // vv = vj (+pe), fp32, stride 68
  __shared__ unsigned short Hlds[64 * 264];   // H (relu'd hidden), bf16, stride 264
  __shared__ float qs[4 * 64];
  __shared__ int idxs[64];
  unsigned short* PEH = Hlds;                 // pehid [64][40] bf16 aliases H (dead before H written)

  const int t = threadIdx.x;
  const int blk = blockIdx.x;                 // 4096 blocks
  const int b = blk >> 10;                    // 1024 blocks per batch
  const int n0 = (blk & 1023) * 4;

  // phase 0: indices + q rows
  if (t < 64) idxs[t] = idxf[blk * 64 + t];
  {
    const int pt = t >> 6, c = t & 63;
    qs[pt * 64 + c] = qkv[(b * kN + n0 + pt) * 192 + c];
  }
  __syncthreads();

  // phase 1a: gather k/v, write U = bf16(q - kj), VV = vj
  {
    const int row = t >> 2, seg = t & 3;
    const int pt = row >> 4;
    const int jrow = (b * kN + idxs[row]) * 192;
    const float4* kb = reinterpret_cast<const float4*>(qkv + jrow + 64 + seg * 16);
    const float4* vb = reinterpret_cast<const float4*>(qkv + jrow + 128 + seg * 16);
    const float4* q4 = reinterpret_cast<const float4*>(&qs[pt * 64 + seg * 16]);
    #pragma unroll
    for (int i = 0; i < 4; ++i) {
      float4 kv = kb[i], vv4 = vb[i], qq = q4[i];
      int c = seg * 16 + i * 4;
      uint2 u2;
      u2.x = (unsigned int)f2bf(qq.x - kv.x) | ((unsigned int)f2bf(qq.y - kv.y) << 16);
      u2.y = (unsigned int)f2bf(qq.z - kv.z) | ((unsigned int)f2bf(qq.w - kv.w) << 16);
      *reinterpret_cast<uint2*>(&Ulds[row * 72 + c]) = u2;
      *reinterpret_cast<float4*>(&VVlds[row * 68 + c]) = vv4;
    }
  }
  // phase 1b: pe hidden layer (3->32), bf16 into PEH
  {
    const int row = t & 63, hs = t >> 6;
    const int pt = row >> 4;
    const float* pn = p + (b * kN + n0 + pt) * 3;
    const float* pj = p + (b * kN + idxs[row]) * 3;
    float rx = pn[0] - pj[0], ry = pn[1] - pj[1], rz = pn[2] - pj[2];
    unsigned short tmp[8];
    #pragma unroll
    for (int j = 0; j < 8; ++j) {
      int hh = hs * 8 + j;
      float v = pos_b1[hh] + rx * pos_w1[hh] + ry * pos_w1[32 + hh] + rz * pos_w1[64 + hh];
      tmp[j] = f2bf(fmaxf(v, 0.0f));
    }
    uint4 pk;
    pk.x = (unsigned int)tmp[0] | ((unsigned int)tmp[1] << 16);
    pk.y = (unsigned int)tmp[2] | ((unsigned int)tmp[3] << 16);
    pk.z = (unsigned int)tmp[4] | ((unsigned int)tmp[5] << 16);
    pk.w = (unsigned int)tmp[6] | ((unsigned int)tmp[7] << 16);
    *reinterpret_cast<uint4*>(&PEH[row * 40 + hs * 8]) = pk;
  }
  __syncthreads();

  const int w = t >> 6;
  const int lane = t & 63, l = lane & 15, quad = lane >> 4;
  const f32x4 zero = {0.f, 0.f, 0.f, 0.f};

  // phase 2: pe = pehid @ pos_w2 (transposed MFMA: D[c][row]); RMW U and VV
  {
    short8 pbf = *reinterpret_cast<const short8*>(&PEH[(w * 16 + l) * 40 + quad * 8]);
    const int row = w * 16 + l;
    #pragma unroll
    for (int mt = 0; mt < 4; ++mt) {
      short8 paf = *reinterpret_cast<const short8*>(&pw2t[(mt * 16 + l) * 32 + quad * 8]);
      f32x4 pe = __builtin_amdgcn_mfma_f32_16x16x32_bf16(paf, pbf, zero, 0, 0, 0);
      const int c0 = mt * 16 + quad * 4;
      float4 b2v = *reinterpret_cast<const float4*>(&pos_b2[c0]);
      float pe0 = pe[0] + b2v.x, pe1 = pe[1] + b2v.y;
      float pe2 = pe[2] + b2v.z, pe3 = pe[3] + b2v.w;
      uint2 u2 = *reinterpret_cast<uint2*>(&Ulds[row * 72 + c0]);
      float u0 = bf2f(u2.x & 0xffffu) + pe0;
      float u1 = bf2f(u2.x >> 16) + pe1;
      float u2f = bf2f(u2.y & 0xffffu) + pe2;
      float u3 = bf2f(u2.y >> 16) + pe3;
      uint2 o;
      o.x = (unsigned int)f2bf(u0) | ((unsigned int)f2bf(u1) << 16);
      o.y = (unsigned int)f2bf(u2f) | ((unsigned int)f2bf(u3) << 16);
      *reinterpret_cast<uint2*>(&Ulds[row * 72 + c0]) = o;
      float4 vv4 = *reinterpret_cast<float4*>(&VVlds[row * 68 + c0]);
      vv4.x += pe0; vv4.y += pe1; vv4.z += pe2; vv4.w += pe3;
      *reinterpret_cast<float4*>(&VVlds[row * 68 + c0]) = vv4;
    }
  }
  __syncthreads();

  // phase 3: GEMM1 transposed: H^T tiles, A = W1^T (from global), B = U (LDS)
  {
    const int row = w * 16 + l;
    short8 ub0 = *reinterpret_cast<const short8*>(&Ulds[row * 72 + quad * 8]);
    short8 ub1 = *reinterpret_cast<const short8*>(&Ulds[row * 72 + 32 + quad * 8]);
    f32x4 acc[16];
    #pragma unroll
    for (int mt = 0; mt < 16; ++mt) acc[mt] = zero;
    #pragma unroll
    for (int mt = 0; mt < 16; ++mt) {
      short8 a0 = *reinterpret_cast<const short8*>(&w1t[(mt * 16 + l) * 64 + quad * 8]);
      short8 a1 = *reinterpret_cast<const short8*>(&w1t[(mt * 16 + l) * 64 + 32 + quad * 8]);
      acc[mt] = __builtin_amdgcn_mfma_f32_16x16x32_bf16(a0, ub0, acc[mt], 0, 0, 0);
      acc[mt] = __builtin_amdgcn_mfma_f32_16x16x32_bf16(a1, ub1, acc[mt], 0, 0, 0);
    }
    __syncthreads();   // PEH (aliased in Hlds) fully consumed; safe to overwrite
    #pragma unroll
    for (int mt = 0; mt < 16; ++mt) {
      const int h0 = mt * 16 + quad * 4;
      float4 bb = *reinterpret_cast<const float4*>(&attn_b1[h0]);
      uint2 hw;
      hw.x = (unsigned int)f2bf(fmaxf(acc[mt][0] + bb.x, 0.f)) |
             ((unsigned int)f2bf(fmaxf(acc[mt][1] + bb.y, 0.f)) << 16);
      hw.y = (unsigned int)f2bf(fmaxf(acc[mt][2] + bb.z, 0.f)) |
             ((unsigned int)f2bf(fmaxf(acc[mt][3] + bb.w, 0.f)) << 16);
      *reinterpret_cast<uint2*>(&Hlds[row * 264 + h0]) = hw;
    }
  }
  __syncthreads();

  // phase 4: GEMM2: sim tiles D[row][c], A = H (LDS), B = W2^T (global); softmax + agg
  {
    f32x4 acc2[4];
    #pragma unroll
    for (int mt = 0; mt < 4; ++mt) acc2[mt] = zero;
    const int cw = w * 16 + l;
    #pragma unroll
    for (int f = 0; f < 8; ++f) {
      short8 bfr = *reinterpret_cast<const short8*>(&w2t[cw * 256 + f * 32 + quad * 8]);
      #pragma unroll
      for (int mt = 0; mt < 4; ++mt) {
        short8 afr = *reinterpret_cast<const short8*>(&Hlds[(mt * 16 + l) * 264 + f * 32 + quad * 8]);
        acc2[mt] = __builtin_amdgcn_mfma_f32_16x16x32_bf16(afr, bfr, acc2[mt], 0, 0, 0);
      }
    }
    const float b2v = attn_b2[cw];
    #pragma unroll
    for (int mt = 0; mt < 4; ++mt) {
      float s0 = acc2[mt][0] + b2v, s1 = acc2[mt][1] + b2v;
      float s2 = acc2[mt][2] + b2v, s3 = acc2[mt][3] + b2v;
      float mx = fmaxf(fmaxf(s0, s1), fmaxf(s2, s3));
      mx = fmaxf(mx, __shfl_xor(mx, 16, 64));
      mx = fmaxf(mx, __shfl_xor(mx, 32, 64));
      float e0 = __expf(s0 - mx), e1 = __expf(s1 - mx);
      float e2 = __expf(s2 - mx), e3 = __expf(s3 - mx);
      float se = e0 + e1 + e2 + e3;
      se += __shfl_xor(se, 16, 64);
      se += __shfl_xor(se, 32, 64);
      const float inv = 1.0f / se;
      const int rb = mt * 16 + quad * 4;
      float a = e0 * VVlds[(rb + 0) * 68 + cw] + e1 * VVlds[(rb + 1) * 68 + cw] +
                e2 * VVlds[(rb + 2) * 68 + cw] + e3 * VVlds[(rb + 3) * 68 + cw];
      a += __shfl_xor(a, 16, 64);
      a += __shfl_xor(a, 32, 64);
      if (quad == 0) agg[(blk * 4 + mt) * 64 + cw] = a * inv;
    }
  }
}

// ---------------- fc2 fused with bn2+relu+residual add ----------------
__global__ void fc2_kernel(const float* __restrict__ aggp, const float* __restrict__ hres,
                           const float* __restrict__ g2, const float* __restrict__ b2,
                           const float* __restrict__ mu2, const float* __restrict__ rs2,
                           const float* __restrict__ w, const float* __restrict__ bias,
                           float* __restrict__ z) {
  __shared__ float ss[16 * 64];
  __shared__ float ws[64 * 64];
  const int t = threadIdx.x;
  const int row0 = blockIdx.x * 16;
  #pragma unroll
  for (int i = 0; i < 4; ++i) {
    int e = t + i * 256;
    int c = e & 63;
    float a = aggp[row0 * 64 + e];
    float h2 = fmaxf(g2[c] * (a - mu2[c]) * rs2[c] + b2[c], 0.0f);
    ss[e] = h2 + hres[row0 * 64 + e];
  }
  #pragma unroll
  for (int i = 0; i < 16; ++i) ws[t + i * 256] = w[t + i * 256];
  __syncthreads();
  const int c = t & 63, rg = t >> 6;
  const float bc = bias[c];
  for (int rr = 0; rr < 4; ++rr) {
    const int r = rg + rr * 4;
    float acc = bc;
    #pragma unroll
    for (int kk = 0; kk < 64; ++kk) acc += ss[r * 64 + kk] * ws[kk * 64 + c];
    z[(row0 + r) * 64 + c] = acc;
  }
}

__global__ void final_kernel(const float* __restrict__ z, const float* __restrict__ g,
                             const float* __restrict__ b, const float* __restrict__ mu,
                             const float* __restrict__ rs, float* __restrict__ y) {
  int i = blockIdx.x * 256 + threadIdx.x;
  int c = i & 63;
  y[i] = fmaxf(g[c] * (z[i] - mu[c]) * rs[c] + b[c], 0.0f);
}

__global__ void copyp_kernel(const float* __restrict__ p, float* __restrict__ out) {
  int i = blockIdx.x * 256 + threadIdx.x;
  out[i] = p[i];
}

extern "C" void kernel_launch(void* const* d_in, const int* in_sizes, int n_in,
                              void* d_out, int out_size, void* d_ws, size_t ws_size,
                              hipStream_t stream) {
  const float* x       = (const float*)d_in[0];
  const float* p       = (const float*)d_in[1];
  const float* fc1_w   = (const float*)d_in[2];
  const float* fc1_b   = (const float*)d_in[3];
  const float* bn1_g   = (const float*)d_in[4];
  const float* bn1_b   = (const float*)d_in[5];
  const float* qkv_w   = (const float*)d_in[6];
  const float* pos_w1  = (const float*)d_in[7];
  const float* pos_b1  = (const float*)d_in[8];
  const float* pos_w2  = (const float*)d_in[9];
  const float* pos_b2  = (const float*)d_in[10];
  const float* attn_w1 = (const float*)d_in[11];
  const float* attn_b1 = (const float*)d_in[12];
  const float* attn_w2 = (const float*)d_in[13];
  const float* attn_b2 = (const float*)d_in[14];
  const float* bn2_g   = (const float*)d_in[15];
  const float* bn2_b   = (const float*)d_in[16];
  const float* fc2_w   = (const float*)d_in[17];
  const float* fc2_b   = (const float*)d_in[18];
  const float* bn3_g   = (const float*)d_in[19];
  const float* bn3_b   = (const float*)d_in[20];

  float* ws   = (float*)d_ws;
  float* h    = ws;                     // 1048576  (residual)
  float* qkvb = ws + 1048576;           // 3145728
  float* hpre = ws + 4194304;           // 1048576  (reused: bf16 weights after bnrelu)
  float* aggv = ws + 5242880;           // 1048576  (also partials for stats1/stats3)
  float* z    = ws + 6291456;           // 1048576  (also partials for stats2)
  float* sq   = ws + 7340032;           // 16384
  float* st   = ws + 7356416;           // 384
  int*   idxf = (int*)(ws + 7356800);   // 262144 ints
  unsigned short* w1t  = (unsigned short*)hpre;         // 16384 bf16
  unsigned short* w2t  = w1t + 16384;                   // 16384 bf16
  unsigned short* pw2t = w1t + 32768;                   // 2048 bf16

  float* mu1 = st,       *rs1 = st + 64;
  float* mu2 = st + 128, *rs2 = st + 192;
  float* mu3 = st + 256, *rs3 = st + 320;
  float* y = (float*)d_out;

  fc1_kernel<<<1024, 256, 0, stream>>>(x, fc1_w, fc1_b, hpre);
  stats_part_kernel<<<256, 256, 0, stream>>>(hpre, aggv);
  stats_fin_kernel<<<1, 64, 0, stream>>>(aggv, mu1, rs1);
  bnrelu_kernel<<<4096, 256, 0, stream>>>(hpre, h, bn1_g, bn1_b, mu1, rs1);
  qkv_kernel<<<2048, 192, 0, stream>>>(h, qkv_w, qkvb);
  sq_kernel<<<64, 256, 0, stream>>>(p, sq);
  knn_coop_kernel<<<4096, 256, 0, stream>>>(p, sq, idxf);
  convert_w_kernel<<<136, 256, 0, stream>>>(attn_w1, attn_w2, pos_w2, w1t, w2t, pw2t);
  attn_mfma_kernel<<<4096, 256, 0, stream>>>(p, qkvb, idxf, pos_w1, pos_b1, pos_b2,
                                             attn_b1, attn_b2, w1t, w2t, pw2t, aggv);
  stats_part_kernel<<<256, 256, 0, stream>>>(aggv, z);
  stats_fin_kernel<<<1, 64, 0, stream>>>(z, mu2, rs2);
  fc2_kernel<<<1024, 256, 0, stream>>>(aggv, h, bn2_g, bn2_b, mu2, rs2, fc2_w, fc2_b, z);
  stats_part_kernel<<<256, 256, 0, stream>>>(z, aggv);
  stats_fin_kernel<<<1, 64, 0, stream>>>(aggv, mu3, rs3);
  final_kernel<<<4096, 256, 0, stream>>>(z, bn3_g, bn3_b, mu3, rs3, y);
  copyp_kernel<<<192, 256, 0, stream>>>(p, y + 1048576);
}

// Round 5
// 443.673 us; speedup vs baseline: 2.7285x; 1.5024x over previous
//
#include <hip/hip_runtime.h>
#include <math.h>

constexpr int kB = 4, kN = 4096, kK = 16;
constexpr int kRows = kB * kN;          // 16384
constexpr float kEps = 1e-5f;
constexpr float kFltMax = 3.402823466e38f;
constexpr int kCap = 240;               // per-wave qualifier buffer

typedef __attribute__((ext_vector_type(8))) short short8;
typedef __attribute__((ext_vector_type(4))) float f32x4;

__device__ __forceinline__ unsigned short f2bf(float x) {
  unsigned int u = __float_as_uint(x);
  unsigned int r = (u + 0x7fffu + ((u >> 16) & 1u)) >> 16;
  return (unsigned short)r;
}
__device__ __forceinline__ float bf2f(unsigned int b) {
  return __uint_as_float(b << 16);
}

// Full 64-lane bitonic sort, ascending by (v, i) lexicographic. Works on
// arbitrary input; lanes 0..15 end up holding the 16 smallest.
__device__ __forceinline__ void bitonic64(float& sv, int& si, int lane) {
  #pragma unroll
  for (int k = 2; k <= 64; k <<= 1) {
    #pragma unroll
    for (int j = k >> 1; j > 0; j >>= 1) {
      float ov = __shfl_xor(sv, j);
      int   oi = __shfl_xor(si, j);
      bool up = ((lane & k) == 0);
      bool lower = ((lane & j) == 0);
      bool osm = (ov < sv) || (ov == sv && oi < si);
      bool take = (lower == up) ? osm : !osm;
      if (take) { sv = ov; si = oi; }
    }
  }
}

// ---------------- fc1: hpre = x @ fc1_w + fc1_b ----------------
__global__ void fc1_kernel(const float* __restrict__ x, const float* __restrict__ w,
                           const float* __restrict__ bias, float* __restrict__ out) {
  __shared__ float xs[16 * 64];
  __shared__ float ws[64 * 64];
  const int t = threadIdx.x;
  const int row0 = blockIdx.x * 16;
  #pragma unroll
  for (int i = 0; i < 4; ++i) xs[t + i * 256] = x[row0 * 64 + t + i * 256];
  #pragma unroll
  for (int i = 0; i < 16; ++i) ws[t + i * 256] = w[t + i * 256];
  __syncthreads();
  const int c = t & 63, rg = t >> 6;
  const float bc = bias[c];
  for (int rr = 0; rr < 4; ++rr) {
    const int r = rg + rr * 4;
    float acc = bc;
    #pragma unroll
    for (int kk = 0; kk < 64; ++kk) acc += xs[r * 64 + kk] * ws[kk * 64 + c];
    out[(row0 + r) * 64 + c] = acc;
  }
}

// ---------------- batchnorm stats: coalesced partial pass + finalize ----------------
__global__ void stats_part_kernel(const float* __restrict__ src, float* __restrict__ part) {
  __shared__ float sb[256], sb2[256];
  const int t = threadIdx.x, blk = blockIdx.x;
  const int c = t & 63, rg = t >> 6;
  float s = 0.f, s2 = 0.f;
  for (int r = rg; r < 64; r += 4) {
    float v = src[(blk * 64 + r) * 64 + c];
    s += v; s2 += v * v;
  }
  sb[t] = s; sb2[t] = s2; __syncthreads();
  if (t < 64) {
    float ts  = sb[t] + sb[64 + t] + sb[128 + t] + sb[192 + t];
    float ts2 = sb2[t] + sb2[64 + t] + sb2[128 + t] + sb2[192 + t];
    part[blk * 128 + t] = ts;
    part[blk * 128 + 64 + t] = ts2;
  }
}

__global__ void stats_fin_kernel(const float* __restrict__ part, float* __restrict__ mu,
                                 float* __restrict__ rs) {
  const int c = threadIdx.x;  // 64
  double s = 0.0, s2 = 0.0;
  for (int i = 0; i < 256; ++i) { s += part[i * 128 + c]; s2 += part[i * 128 + 64 + c]; }
  double mean = s / (double)kRows;
  double var = s2 / (double)kRows - mean * mean;
  mu[c] = (float)mean;
  rs[c] = (float)(1.0 / sqrt(var + (double)kEps));
}

__global__ void bnrelu_kernel(const float* __restrict__ src, float* __restrict__ dst,
                              const float* __restrict__ g, const float* __restrict__ b,
                              const float* __restrict__ mu, const float* __restrict__ rs) {
  int i = blockIdx.x * 256 + threadIdx.x;
  int c = i & 63;
  float v = g[c] * (src[i] - mu[c]) * rs[c] + b[c];
  dst[i] = fmaxf(v, 0.0f);
}

// ---------------- qkv = h @ qkv_w (no bias) ----------------
__global__ void qkv_kernel(const float* __restrict__ h, const float* __restrict__ w,
                           float* __restrict__ out) {
  __shared__ float ws[64 * 192];
  __shared__ float hs[8 * 64];
  const int t = threadIdx.x;          // 192 threads
  const int row0 = blockIdx.x * 8;
  for (int j = t; j < 64 * 192; j += 192) ws[j] = w[j];
  for (int j = t; j < 512; j += 192) hs[j] = h[row0 * 64 + j];
  __syncthreads();
  for (int r = 0; r < 8; ++r) {
    float acc = 0.f;
    #pragma unroll
    for (int kk = 0; kk < 64; ++kk) acc += hs[r * 64 + kk] * ws[kk * 192 + t];
    out[(row0 + r) * 192 + t] = acc;
  }
}

__global__ void sq_kernel(const float* __restrict__ p, float* __restrict__ sq) {
  int i = blockIdx.x * 256 + threadIdx.x; // < 16384
  float x = p[i * 3], y = p[i * 3 + 1], z = p[i * 3 + 2];
  sq[i] = x * x + y * y + z * z;
}

// ---------------- kNN: filtered top-16, one wave per query ----------------
// Pass A: per-lane min over its 64 candidates; bitonic-sort the 64 minima ->
// tau = 16th smallest (upper bound on global 16th distance). Pass B: append
// candidates with d2 <= thr to a per-wave LDS buffer; merge 48 at a time into
// a sorted-16 (lanes 0..15) via a 64-lane bitonic sort keyed (d2, idx).
// NOTE: tau crosses two codegen sites of the d2 expression; -ffp-contract=fast
// can make the pass-B d2 differ by ulps from pass-A's. thrA adds an absolute
// margin (1e-3 >> max contraction wobble ~1e-4) so the 16 tau-defining
// candidates always pass the filter. Tightening by sv15 is same-site exact.
__global__ __launch_bounds__(256) void knn_kernel(
    const float* __restrict__ p, const float* __restrict__ sq,
    int* __restrict__ idxf) {
  __shared__ float4 pts[1024];          // 16 KB candidate chunk, shared by 4 waves
  __shared__ float bufv[4][kCap];
  __shared__ int   bufi[4][kCap];
  __shared__ int   cnt[4];
  const int t = threadIdx.x;
  const int lane = t & 63, w = t >> 6;
  const int blk = blockIdx.x;           // 4096 blocks, 4 queries each
  const int b = blk >> 10;
  const int q = blk * 4 + w;
  const float qx = p[q * 3], qy = p[q * 3 + 1], qz = p[q * 3 + 2];
  const float sqq = sq[q];
  if (lane == 0) cnt[w] = 0;

  // ---- pass A: lane minima ----
  float lmin = kFltMax;
  for (int c0 = 0; c0 < kN; c0 += 1024) {
    __syncthreads();
    #pragma unroll
    for (int i = 0; i < 4; ++i) {
      int j = t + i * 256;
      int g = b * kN + c0 + j;
      pts[j] = make_float4(p[g * 3], p[g * 3 + 1], p[g * 3 + 2], sq[g]);
    }
    __syncthreads();
    #pragma unroll
    for (int i = 0; i < 16; ++i) {
      float4 pt = pts[i * 64 + lane];
      float d2 = sqq + pt.w - 2.0f * (qx * pt.x + qy * pt.y + qz * pt.z);
      lmin = fminf(lmin, d2);
    }
  }
  {
    int dummy = lane;
    bitonic64(lmin, dummy, lane);
  }
  const float tau = __shfl(lmin, 15);   // >= global 16th-smallest distance
  const float thrA = tau + 1e-3f;       // cross-site FMA-contraction margin

  float sv = kFltMax;                   // sorted-16 in lanes 0..15 (ascending)
  int   si = 0x7fffffff;
  float thr = thrA;

  // ---- pass B: filter + merge ----
  for (int c0 = 0; c0 < kN; c0 += 1024) {
    __syncthreads();
    #pragma unroll
    for (int i = 0; i < 4; ++i) {
      int j = t + i * 256;
      int g = b * kN + c0 + j;
      pts[j] = make_float4(p[g * 3], p[g * 3 + 1], p[g * 3 + 2], sq[g]);
    }
    __syncthreads();
    #pragma unroll
    for (int i = 0; i < 16; ++i) {
      float4 pt = pts[i * 64 + lane];
      float d2 = sqq + pt.w - 2.0f * (qx * pt.x + qy * pt.y + qz * pt.z);
      if (d2 <= thr) {
        int pos = atomicAdd(&cnt[w], 1);
        if (pos < kCap) { bufv[w][pos] = d2; bufi[w][pos] = c0 + i * 64 + lane; }
      }
    }
    int n = cnt[w];   // same-wave DS ops are pipeline-ordered; post-append value
    if (n > 0) {
      if (n > kCap) {
        // overflow (degenerate data): discard buffer, merge the whole chunk
        for (int g0 = 0; g0 < 1024; g0 += 48) {
          float mv; int mi;
          if (lane < 16) { mv = sv; mi = si; }
          else {
            int jj = g0 + (lane - 16);
            if (jj < 1024) {
              float4 pt = pts[jj];
              mv = sqq + pt.w - 2.0f * (qx * pt.x + qy * pt.y + qz * pt.z);
              mi = c0 + jj;
            } else { mv = kFltMax; mi = 0x7fffffff; }
          }
          bitonic64(mv, mi, lane);
          sv = mv; si = mi;
        }
      } else {
        for (int g0 = 0; g0 < n; g0 += 48) {
          float mv; int mi;
          if (lane < 16) { mv = sv; mi = si; }
          else {
            int pos = g0 + (lane - 16);
            if (pos < n) { mv = bufv[w][pos]; mi = bufi[w][pos]; }
            else { mv = kFltMax; mi = 0x7fffffff; }
          }
          bitonic64(mv, mi, lane);
          sv = mv; si = mi;
        }
      }
      if (lane == 0) cnt[w] = 0;
      thr = fminf(thrA, __shfl(sv, 15));
    }
  }
  if (lane < 16) {
    int out = si;
    if ((unsigned)out >= (unsigned)kN) out = 0;  // safety net: wrong beats fault
    idxf[q * 16 + lane] = out;
  }
}

// ---------------- weight convert/transpose to bf16 (runs once per call) ----------------
__global__ void convert_w_kernel(const float* __restrict__ w1, const float* __restrict__ w2,
                                 const float* __restrict__ pw2,
                                 unsigned short* __restrict__ w1t,
                                 unsigned short* __restrict__ w2t,
                                 unsigned short* __restrict__ pw2t) {
  int id = blockIdx.x * 256 + threadIdx.x;
  if (id < 16384) {                       // w1t[h][c] = w1[c][h], 256x64
    int hh = id >> 6, c = id & 63;
    w1t[id] = f2bf(w1[c * 256 + hh]);
  } else if (id < 32768) {                // w2t[c][k2] = w2[k2][c], 64x256
    int i = id - 16384;
    int c = i >> 8, k2 = i & 255;
    w2t[i] = f2bf(w2[k2 * 64 + c]);
  } else if (id < 34816) {                // pw2t[c][h] = pw2[h][c], 64x32
    int i = id - 32768;
    int c = i >> 5, hh = i & 31;
    pw2t[i] = f2bf(pw2[hh * 64 + c]);
  }
}

// ---------------- fused MFMA attention: 4 points (64 rows) per block ----------------
// GEMM1 computed transposed (D = W1^T * U^T) so C-layout packs into row-major H.
__global__ __launch_bounds__(256) void attn_mfma_kernel(
    const float* __restrict__ p, const float* __restrict__ qkv,
    const int* __restrict__ idxf,
    const float* __restrict__ pos_w1, const float* __restrict__ pos_b1,
    const float* __restrict__ pos_b2,
    const float* __restrict__ attn_b1, const float* __restrict__ attn_b2,
    const unsigned short* __restrict__ w1t,   // [256][64] bf16
    const unsigned short* __restrict__ w2t,   // [64][256] bf16
    const unsigned short* __restrict__ pw2t,  // [64][32]  bf16
    float* __restrict__ agg) {
  __shared__ unsigned short Ulds[64 * 72];    // u = q - kj (+pe), bf16, stride 72
  __shared__ float VVlds[64 * 68];            // vv = vj (+pe), fp32, stride 68
  __shared__ unsigned short Hlds[64 * 264];   // H (relu'd hidden), bf16, stride 264
  __shared__ float qs[4 * 64];
  __shared__ int idxs[64];
  unsigned short* PEH = Hlds;                 // pehid [64][40] bf16 aliases H (dead before H written)

  const int t = threadIdx.x;
  const int blk = blockIdx.x;                 // 4096 blocks
  const int b = blk >> 10;                    // 1024 blocks per batch
  const int n0 = (blk & 1023) * 4;

  // phase 0: indices + q rows
  if (t < 64) idxs[t] = idxf[blk * 64 + t];
  {
    const int pt = t >> 6, c = t & 63;
    qs[pt * 64 + c] = qkv[(b * kN + n0 + pt) * 192 + c];
  }
  __syncthreads();

  // phase 1a: gather k/v, write U = bf16(q - kj), VV = vj
  {
    const int row = t >> 2, seg = t & 3;
    const int pt = row >> 4;
    const int jrow = (b * kN + idxs[row]) * 192;
    const float4* kb = reinterpret_cast<const float4*>(qkv + jrow + 64 + seg * 16);
    const float4* vb = reinterpret_cast<const float4*>(qkv + jrow + 128 + seg * 16);
    const float4* q4 = reinterpret_cast<const float4*>(&qs[pt * 64 + seg * 16]);
    #pragma unroll
    for (int i = 0; i < 4; ++i) {
      float4 kv = kb[i], vv4 = vb[i], qq = q4[i];
      int c = seg * 16 + i * 4;
      uint2 u2;
      u2.x = (unsigned int)f2bf(qq.x - kv.x) | ((unsigned int)f2bf(qq.y - kv.y) << 16);
      u2.y = (unsigned int)f2bf(qq.z - kv.z) | ((unsigned int)f2bf(qq.w - kv.w) << 16);
      *reinterpret_cast<uint2*>(&Ulds[row * 72 + c]) = u2;
      *reinterpret_cast<float4*>(&VVlds[row * 68 + c]) = vv4;
    }
  }
  // phase 1b: pe hidden layer (3->32), bf16 into PEH
  {
    const int row = t & 63, hs = t >> 6;
    const int pt = row >> 4;
    const float* pn = p + (b * kN + n0 + pt) * 3;
    const float* pj = p + (b * kN + idxs[row]) * 3;
    float rx = pn[0] - pj[0], ry = pn[1] - pj[1], rz = pn[2] - pj[2];
    unsigned short tmp[8];
    #pragma unroll
    for (int j = 0; j < 8; ++j) {
      int hh = hs * 8 + j;
      float v = pos_b1[hh] + rx * pos_w1[hh] + ry * pos_w1[32 + hh] + rz * pos_w1[64 + hh];
      tmp[j] = f2bf(fmaxf(v, 0.0f));
    }
    uint4 pk;
    pk.x = (unsigned int)tmp[0] | ((unsigned int)tmp[1] << 16);
    pk.y = (unsigned int)tmp[2] | ((unsigned int)tmp[3] << 16);
    pk.z = (unsigned int)tmp[4] | ((unsigned int)tmp[5] << 16);
    pk.w = (unsigned int)tmp[6] | ((unsigned int)tmp[7] << 16);
    *reinterpret_cast<uint4*>(&PEH[row * 40 + hs * 8]) = pk;
  }
  __syncthreads();

  const int w = t >> 6;
  const int lane = t & 63, l = lane & 15, quad = lane >> 4;
  const f32x4 zero = {0.f, 0.f, 0.f, 0.f};

  // phase 2: pe = pehid @ pos_w2 (transposed MFMA: D[c][row]); RMW U and VV
  {
    short8 pbf = *reinterpret_cast<const short8*>(&PEH[(w * 16 + l) * 40 + quad * 8]);
    const int row = w * 16 + l;
    #pragma unroll
    for (int mt = 0; mt < 4; ++mt) {
      short8 paf = *reinterpret_cast<const short8*>(&pw2t[(mt * 16 + l) * 32 + quad * 8]);
      f32x4 pe = __builtin_amdgcn_mfma_f32_16x16x32_bf16(paf, pbf, zero, 0, 0, 0);
      const int c0 = mt * 16 + quad * 4;
      float4 b2v = *reinterpret_cast<const float4*>(&pos_b2[c0]);
      float pe0 = pe[0] + b2v.x, pe1 = pe[1] + b2v.y;
      float pe2 = pe[2] + b2v.z, pe3 = pe[3] + b2v.w;
      uint2 u2 = *reinterpret_cast<uint2*>(&Ulds[row * 72 + c0]);
      float u0 = bf2f(u2.x & 0xffffu) + pe0;
      float u1 = bf2f(u2.x >> 16) + pe1;
      float u2f = bf2f(u2.y & 0xffffu) + pe2;
      float u3 = bf2f(u2.y >> 16) + pe3;
      uint2 o;
      o.x = (unsigned int)f2bf(u0) | ((unsigned int)f2bf(u1) << 16);
      o.y = (unsigned int)f2bf(u2f) | ((unsigned int)f2bf(u3) << 16);
      *reinterpret_cast<uint2*>(&Ulds[row * 72 + c0]) = o;
      float4 vv4 = *reinterpret_cast<float4*>(&VVlds[row * 68 + c0]);
      vv4.x += pe0; vv4.y += pe1; vv4.z += pe2; vv4.w += pe3;
      *reinterpret_cast<float4*>(&VVlds[row * 68 + c0]) = vv4;
    }
  }
  __syncthreads();

  // phase 3: GEMM1 transposed: H^T tiles, A = W1^T (from global), B = U (LDS)
  {
    const int row = w * 16 + l;
    short8 ub0 = *reinterpret_cast<const short8*>(&Ulds[row * 72 + quad * 8]);
    short8 ub1 = *reinterpret_cast<const short8*>(&Ulds[row * 72 + 32 + quad * 8]);
    f32x4 acc[16];
    #pragma unroll
    for (int mt = 0; mt < 16; ++mt) acc[mt] = zero;
    #pragma unroll
    for (int mt = 0; mt < 16; ++mt) {
      short8 a0 = *reinterpret_cast<const short8*>(&w1t[(mt * 16 + l) * 64 + quad * 8]);
      short8 a1 = *reinterpret_cast<const short8*>(&w1t[(mt * 16 + l) * 64 + 32 + quad * 8]);
      acc[mt] = __builtin_amdgcn_mfma_f32_16x16x32_bf16(a0, ub0, acc[mt], 0, 0, 0);
      acc[mt] = __builtin_amdgcn_mfma_f32_16x16x32_bf16(a1, ub1, acc[mt], 0, 0, 0);
    }
    __syncthreads();   // PEH (aliased in Hlds) fully consumed; safe to overwrite
    #pragma unroll
    for (int mt = 0; mt < 16; ++mt) {
      const int h0 = mt * 16 + quad * 4;
      float4 bb = *reinterpret_cast<const float4*>(&attn_b1[h0]);
      uint2 hw;
      hw.x = (unsigned int)f2bf(fmaxf(acc[mt][0] + bb.x, 0.f)) |
             ((unsigned int)f2bf(fmaxf(acc[mt][1] + bb.y, 0.f)) << 16);
      hw.y = (unsigned int)f2bf(fmaxf(acc[mt][2] + bb.z, 0.f)) |
             ((unsigned int)f2bf(fmaxf(acc[mt][3] + bb.w, 0.f)) << 16);
      *reinterpret_cast<uint2*>(&Hlds[row * 264 + h0]) = hw;
    }
  }
  __syncthreads();

  // phase 4: GEMM2: sim tiles D[row][c], A = H (LDS), B = W2^T (global); softmax + agg
  {
    f32x4 acc2[4];
    #pragma unroll
    for (int mt = 0; mt < 4; ++mt) acc2[mt] = zero;
    const int cw = w * 16 + l;
    #pragma unroll
    for (int f = 0; f < 8; ++f) {
      short8 bfr = *reinterpret_cast<const short8*>(&w2t[cw * 256 + f * 32 + quad * 8]);
      #pragma unroll
      for (int mt = 0; mt < 4; ++mt) {
        short8 afr = *reinterpret_cast<const short8*>(&Hlds[(mt * 16 + l) * 264 + f * 32 + quad * 8]);
        acc2[mt] = __builtin_amdgcn_mfma_f32_16x16x32_bf16(afr, bfr, acc2[mt], 0, 0, 0);
      }
    }
    const float b2v = attn_b2[cw];
    #pragma unroll
    for (int mt = 0; mt < 4; ++mt) {
      float s0 = acc2[mt][0] + b2v, s1 = acc2[mt][1] + b2v;
      float s2 = acc2[mt][2] + b2v, s3 = acc2[mt][3] + b2v;
      float mx = fmaxf(fmaxf(s0, s1), fmaxf(s2, s3));
      mx = fmaxf(mx, __shfl_xor(mx, 16, 64));
      mx = fmaxf(mx, __shfl_xor(mx, 32, 64));
      float e0 = __expf(s0 - mx), e1 = __expf(s1 - mx);
      float e2 = __expf(s2 - mx), e3 = __expf(s3 - mx);
      float se = e0 + e1 + e2 + e3;
      se += __shfl_xor(se, 16, 64);
      se += __shfl_xor(se, 32, 64);
      const float inv = 1.0f / se;
      const int rb = mt * 16 + quad * 4;
      float a = e0 * VVlds[(rb + 0) * 68 + cw] + e1 * VVlds[(rb + 1) * 68 + cw] +
                e2 * VVlds[(rb + 2) * 68 + cw] + e3 * VVlds[(rb + 3) * 68 + cw];
      a += __shfl_xor(a, 16, 64);
      a += __shfl_xor(a, 32, 64);
      if (quad == 0) agg[(blk * 4 + mt) * 64 + cw] = a * inv;
    }
  }
}

// ---------------- fc2 fused with bn2+relu+residual add ----------------
__global__ void fc2_kernel(const float* __restrict__ aggp, const float* __restrict__ hres,
                           const float* __restrict__ g2, const float* __restrict__ b2,
                           const float* __restrict__ mu2, const float* __restrict__ rs2,
                           const float* __restrict__ w, const float* __restrict__ bias,
                           float* __restrict__ z) {
  __shared__ float ss[16 * 64];
  __shared__ float ws[64 * 64];
  const int t = threadIdx.x;
  const int row0 = blockIdx.x * 16;
  #pragma unroll
  for (int i = 0; i < 4; ++i) {
    int e = t + i * 256;
    int c = e & 63;
    float a = aggp[row0 * 64 + e];
    float h2 = fmaxf(g2[c] * (a - mu2[c]) * rs2[c] + b2[c], 0.0f);
    ss[e] = h2 + hres[row0 * 64 + e];
  }
  #pragma unroll
  for (int i = 0; i < 16; ++i) ws[t + i * 256] = w[t + i * 256];
  __syncthreads();
  const int c = t & 63, rg = t >> 6;
  const float bc = bias[c];
  for (int rr = 0; rr < 4; ++rr) {
    const int r = rg + rr * 4;
    float acc = bc;
    #pragma unroll
    for (int kk = 0; kk < 64; ++kk) acc += ss[r * 64 + kk] * ws[kk * 64 + c];
    z[(row0 + r) * 64 + c] = acc;
  }
}

__global__ void final_kernel(const float* __restrict__ z, const float* __restrict__ g,
                             const float* __restrict__ b, const float* __restrict__ mu,
                             const float* __restrict__ rs, float* __restrict__ y) {
  int i = blockIdx.x * 256 + threadIdx.x;
  int c = i & 63;
  y[i] = fmaxf(g[c] * (z[i] - mu[c]) * rs[c] + b[c], 0.0f);
}

__global__ void copyp_kernel(const float* __restrict__ p, float* __restrict__ out) {
  int i = blockIdx.x * 256 + threadIdx.x;
  out[i] = p[i];
}

extern "C" void kernel_launch(void* const* d_in, const int* in_sizes, int n_in,
                              void* d_out, int out_size, void* d_ws, size_t ws_size,
                              hipStream_t stream) {
  const float* x       = (const float*)d_in[0];
  const float* p       = (const float*)d_in[1];
  const float* fc1_w   = (const float*)d_in[2];
  const float* fc1_b   = (const float*)d_in[3];
  const float* bn1_g   = (const float*)d_in[4];
  const float* bn1_b   = (const float*)d_in[5];
  const float* qkv_w   = (const float*)d_in[6];
  const float* pos_w1  = (const float*)d_in[7];
  const float* pos_b1  = (const float*)d_in[8];
  const float* pos_w2  = (const float*)d_in[9];
  const float* pos_b2  = (const float*)d_in[10];
  const float* attn_w1 = (const float*)d_in[11];
  const float* attn_b1 = (const float*)d_in[12];
  const float* attn_w2 = (const float*)d_in[13];
  const float* attn_b2 = (const float*)d_in[14];
  const float* bn2_g   = (const float*)d_in[15];
  const float* bn2_b   = (const float*)d_in[16];
  const float* fc2_w   = (const float*)d_in[17];
  const float* fc2_b   = (const float*)d_in[18];
  const float* bn3_g   = (const float*)d_in[19];
  const float* bn3_b   = (const float*)d_in[20];

  float* ws   = (float*)d_ws;
  float* h    = ws;                     // 1048576  (residual)
  float* qkvb = ws + 1048576;           // 3145728
  float* hpre = ws + 4194304;           // 1048576  (reused: bf16 weights after bnrelu)
  float* aggv = ws + 5242880;           // 1048576  (also partials for stats1/stats3)
  float* z    = ws + 6291456;           // 1048576  (also partials for stats2)
  float* sq   = ws + 7340032;           // 16384
  float* st   = ws + 7356416;           // 384
  int*   idxf = (int*)(ws + 7356800);   // 262144 ints
  unsigned short* w1t  = (unsigned short*)hpre;         // 16384 bf16
  unsigned short* w2t  = w1t + 16384;                   // 16384 bf16
  unsigned short* pw2t = w1t + 32768;                   // 2048 bf16

  float* mu1 = st,       *rs1 = st + 64;
  float* mu2 = st + 128, *rs2 = st + 192;
  float* mu3 = st + 256, *rs3 = st + 320;
  float* y = (float*)d_out;

  fc1_kernel<<<1024, 256, 0, stream>>>(x, fc1_w, fc1_b, hpre);
  stats_part_kernel<<<256, 256, 0, stream>>>(hpre, aggv);
  stats_fin_kernel<<<1, 64, 0, stream>>>(aggv, mu1, rs1);
  bnrelu_kernel<<<4096, 256, 0, stream>>>(hpre, h, bn1_g, bn1_b, mu1, rs1);
  qkv_kernel<<<2048, 192, 0, stream>>>(h, qkv_w, qkvb);
  sq_kernel<<<64, 256, 0, stream>>>(p, sq);
  knn_kernel<<<4096, 256, 0, stream>>>(p, sq, idxf);
  convert_w_kernel<<<136, 256, 0, stream>>>(attn_w1, attn_w2, pos_w2, w1t, w2t, pw2t);
  attn_mfma_kernel<<<4096, 256, 0, stream>>>(p, qkvb, idxf, pos_w1, pos_b1, pos_b2,
                                             attn_b1, attn_b2, w1t, w2t, pw2t, aggv);
  stats_part_kernel<<<256, 256, 0, stream>>>(aggv, z);
  stats_fin_kernel<<<1, 64, 0, stream>>>(z, mu2, rs2);
  fc2_kernel<<<1024, 256, 0, stream>>>(aggv, h, bn2_g, bn2_b, mu2, rs2, fc2_w, fc2_b, z);
  stats_part_kernel<<<256, 256, 0, stream>>>(z, aggv);
  stats_fin_kernel<<<1, 64, 0, stream>>>(aggv, mu3, rs3);
  final_kernel<<<4096, 256, 0, stream>>>(z, bn3_g, bn3_b, mu3, rs3, y);
  copyp_kernel<<<192, 256, 0, stream>>>(p, y + 1048576);
}

// Round 6
// 350.296 us; speedup vs baseline: 3.4558x; 1.2666x over previous
//
#include <hip/hip_runtime.h>
#include <math.h>

constexpr int kB = 4, kN = 4096, kK = 16;
constexpr int kRows = kB * kN;          // 16384
constexpr float kEps = 1e-5f;
constexpr float kFltMax = 3.402823466e38f;
constexpr int kCap = 240;               // per-wave qualifier buffer (knn)

typedef __attribute__((ext_vector_type(8))) short short8;
typedef __attribute__((ext_vector_type(4))) float f32x4;

__device__ __forceinline__ unsigned short f2bf(float x) {
  unsigned int u = __float_as_uint(x);
  unsigned int r = (u + 0x7fffu + ((u >> 16) & 1u)) >> 16;
  return (unsigned short)r;
}
__device__ __forceinline__ float bf2f(unsigned int b) {
  return __uint_as_float(b << 16);
}

// Full 64-lane bitonic sort, ascending by (v, i) lexicographic.
__device__ __forceinline__ void bitonic64(float& sv, int& si, int lane) {
  #pragma unroll
  for (int k = 2; k <= 64; k <<= 1) {
    #pragma unroll
    for (int j = k >> 1; j > 0; j >>= 1) {
      float ov = __shfl_xor(sv, j);
      int   oi = __shfl_xor(si, j);
      bool up = ((lane & k) == 0);
      bool lower = ((lane & j) == 0);
      bool osm = (ov < sv) || (ov == sv && oi < si);
      bool take = (lower == up) ? osm : !osm;
      if (take) { sv = ov; si = oi; }
    }
  }
}

// ---------------- fc1: hpre = x @ fc1_w + fc1_b ----------------
__global__ void fc1_kernel(const float* __restrict__ x, const float* __restrict__ w,
                           const float* __restrict__ bias, float* __restrict__ out) {
  __shared__ float xs[16 * 64];
  __shared__ float ws[64 * 64];
  const int t = threadIdx.x;
  const int row0 = blockIdx.x * 16;
  #pragma unroll
  for (int i = 0; i < 4; ++i) xs[t + i * 256] = x[row0 * 64 + t + i * 256];
  #pragma unroll
  for (int i = 0; i < 16; ++i) ws[t + i * 256] = w[t + i * 256];
  __syncthreads();
  const int c = t & 63, rg = t >> 6;
  const float bc = bias[c];
  for (int rr = 0; rr < 4; ++rr) {
    const int r = rg + rr * 4;
    float acc = bc;
    #pragma unroll
    for (int kk = 0; kk < 64; ++kk) acc += xs[r * 64 + kk] * ws[kk * 64 + c];
    out[(row0 + r) * 64 + c] = acc;
  }
}

// ---------------- batchnorm stats ----------------
__global__ void stats_part_kernel(const float* __restrict__ src, float* __restrict__ part) {
  __shared__ float sb[256], sb2[256];
  const int t = threadIdx.x, blk = blockIdx.x;
  const int c = t & 63, rg = t >> 6;
  float s = 0.f, s2 = 0.f;
  for (int r = rg; r < 64; r += 4) {
    float v = src[(blk * 64 + r) * 64 + c];
    s += v; s2 += v * v;
  }
  sb[t] = s; sb2[t] = s2; __syncthreads();
  if (t < 64) {
    float ts  = sb[t] + sb[64 + t] + sb[128 + t] + sb[192 + t];
    float ts2 = sb2[t] + sb2[64 + t] + sb2[128 + t] + sb2[192 + t];
    part[blk * 128 + t] = ts;
    part[blk * 128 + 64 + t] = ts2;
  }
}

__global__ void stats_fin_kernel(const float* __restrict__ part, float* __restrict__ mu,
                                 float* __restrict__ rs) {
  const int c = threadIdx.x;  // 64
  double s = 0.0, s2 = 0.0;
  for (int i = 0; i < 256; ++i) { s += part[i * 128 + c]; s2 += part[i * 128 + 64 + c]; }
  double mean = s / (double)kRows;
  double var = s2 / (double)kRows - mean * mean;
  mu[c] = (float)mean;
  rs[c] = (float)(1.0 / sqrt(var + (double)kEps));
}

// bnrelu also emits a bf16 copy of h for the MFMA qkv GEMM
__global__ void bnrelu_kernel(const float* __restrict__ src, float* __restrict__ dst,
                              unsigned short* __restrict__ dstbf,
                              const float* __restrict__ g, const float* __restrict__ b,
                              const float* __restrict__ mu, const float* __restrict__ rs) {
  int i = blockIdx.x * 256 + threadIdx.x;
  int c = i & 63;
  float v = fmaxf(g[c] * (src[i] - mu[c]) * rs[c] + b[c], 0.0f);
  dst[i] = v;
  dstbf[i] = f2bf(v);
}

// ---------------- qkv = h @ qkv_w via MFMA (bf16) ----------------
__global__ __launch_bounds__(256) void qkv_mfma_kernel(
    const unsigned short* __restrict__ hbf,   // [16384][64] bf16
    const unsigned short* __restrict__ wqf,   // [(ct*2+h)*64+lane]*8 B-frags
    float* __restrict__ out) {                // [16384][192]
  const int t = threadIdx.x, lane = t & 63, w = t >> 6;
  const int l = lane & 15, q = lane >> 4;
  const int r0 = blockIdx.x * 64;
  const f32x4 zero = {0.f, 0.f, 0.f, 0.f};
  short8 af[4][2];
  #pragma unroll
  for (int rt = 0; rt < 4; ++rt)
    #pragma unroll
    for (int h = 0; h < 2; ++h)
      af[rt][h] = *reinterpret_cast<const short8*>(&hbf[(r0 + rt * 16 + l) * 64 + h * 32 + q * 8]);
  #pragma unroll
  for (int cc = 0; cc < 3; ++cc) {
    const int ct = w * 3 + cc;
    short8 b0 = *reinterpret_cast<const short8*>(&wqf[((ct * 2 + 0) * 64 + lane) * 8]);
    short8 b1 = *reinterpret_cast<const short8*>(&wqf[((ct * 2 + 1) * 64 + lane) * 8]);
    #pragma unroll
    for (int rt = 0; rt < 4; ++rt) {
      f32x4 acc = __builtin_amdgcn_mfma_f32_16x16x32_bf16(af[rt][0], b0, zero, 0, 0, 0);
      acc = __builtin_amdgcn_mfma_f32_16x16x32_bf16(af[rt][1], b1, acc, 0, 0, 0);
      #pragma unroll
      for (int i = 0; i < 4; ++i)
        out[(r0 + rt * 16 + q * 4 + i) * 192 + ct * 16 + l] = acc[i];
    }
  }
}

__global__ void sq_kernel(const float* __restrict__ p, float* __restrict__ sq) {
  int i = blockIdx.x * 256 + threadIdx.x; // < 16384
  float x = p[i * 3], y = p[i * 3 + 1], z = p[i * 3 + 2];
  sq[i] = x * x + y * y + z * z;
}

// ---------------- kNN: filtered top-16, one wave per query (unchanged, R4-passing) ----------------
__global__ __launch_bounds__(256) void knn_kernel(
    const float* __restrict__ p, const float* __restrict__ sq,
    int* __restrict__ idxf) {
  __shared__ float4 pts[1024];
  __shared__ float bufv[4][kCap];
  __shared__ int   bufi[4][kCap];
  __shared__ int   cnt[4];
  const int t = threadIdx.x;
  const int lane = t & 63, w = t >> 6;
  const int blk = blockIdx.x;
  const int b = blk >> 10;
  const int q = blk * 4 + w;
  const float qx = p[q * 3], qy = p[q * 3 + 1], qz = p[q * 3 + 2];
  const float sqq = sq[q];
  if (lane == 0) cnt[w] = 0;

  float lmin = kFltMax;
  for (int c0 = 0; c0 < kN; c0 += 1024) {
    __syncthreads();
    #pragma unroll
    for (int i = 0; i < 4; ++i) {
      int j = t + i * 256;
      int g = b * kN + c0 + j;
      pts[j] = make_float4(p[g * 3], p[g * 3 + 1], p[g * 3 + 2], sq[g]);
    }
    __syncthreads();
    #pragma unroll
    for (int i = 0; i < 16; ++i) {
      float4 pt = pts[i * 64 + lane];
      float d2 = sqq + pt.w - 2.0f * (qx * pt.x + qy * pt.y + qz * pt.z);
      lmin = fminf(lmin, d2);
    }
  }
  {
    int dummy = lane;
    bitonic64(lmin, dummy, lane);
  }
  const float tau = __shfl(lmin, 15);
  const float thrA = tau + 1e-3f;

  float sv = kFltMax;
  int   si = 0x7fffffff;
  float thr = thrA;

  for (int c0 = 0; c0 < kN; c0 += 1024) {
    __syncthreads();
    #pragma unroll
    for (int i = 0; i < 4; ++i) {
      int j = t + i * 256;
      int g = b * kN + c0 + j;
      pts[j] = make_float4(p[g * 3], p[g * 3 + 1], p[g * 3 + 2], sq[g]);
    }
    __syncthreads();
    #pragma unroll
    for (int i = 0; i < 16; ++i) {
      float4 pt = pts[i * 64 + lane];
      float d2 = sqq + pt.w - 2.0f * (qx * pt.x + qy * pt.y + qz * pt.z);
      if (d2 <= thr) {
        int pos = atomicAdd(&cnt[w], 1);
        if (pos < kCap) { bufv[w][pos] = d2; bufi[w][pos] = c0 + i * 64 + lane; }
      }
    }
    int n = cnt[w];
    if (n > 0) {
      if (n > kCap) {
        for (int g0 = 0; g0 < 1024; g0 += 48) {
          float mv; int mi;
          if (lane < 16) { mv = sv; mi = si; }
          else {
            int jj = g0 + (lane - 16);
            if (jj < 1024) {
              float4 pt = pts[jj];
              mv = sqq + pt.w - 2.0f * (qx * pt.x + qy * pt.y + qz * pt.z);
              mi = c0 + jj;
            } else { mv = kFltMax; mi = 0x7fffffff; }
          }
          bitonic64(mv, mi, lane);
          sv = mv; si = mi;
        }
      } else {
        for (int g0 = 0; g0 < n; g0 += 48) {
          float mv; int mi;
          if (lane < 16) { mv = sv; mi = si; }
          else {
            int pos = g0 + (lane - 16);
            if (pos < n) { mv = bufv[w][pos]; mi = bufi[w][pos]; }
            else { mv = kFltMax; mi = 0x7fffffff; }
          }
          bitonic64(mv, mi, lane);
          sv = mv; si = mi;
        }
      }
      if (lane == 0) cnt[w] = 0;
      thr = fminf(thrA, __shfl(sv, 15));
    }
  }
  if (lane < 16) {
    int out = si;
    if ((unsigned)out >= (unsigned)kN) out = 0;
    idxf[q * 16 + lane] = out;
  }
}

// ---------------- weight pre-pack: bf16 MFMA fragments ----------------
// w1f: GEMM1 A-frags  [(mt*2+h)*64+lane]*8  = attn_w1[32h+8q+j][mt*16+l]
// w2f: GEMM2 B-frags  [(ct*8+f)*64+lane]*8  = attn_w2[32f+8q+j][ct*16+l]
// pw2t: pe A-operand  [c][h] = pos_w2[h][c]
// wqf: qkv B-frags    [(ct*2+h)*64+lane]*8  = qkv_w[32h+8q+j][ct*16+l]
__global__ void convert_w_kernel(const float* __restrict__ w1, const float* __restrict__ w2,
                                 const float* __restrict__ pw2, const float* __restrict__ qw,
                                 unsigned short* __restrict__ w1f,
                                 unsigned short* __restrict__ w2f,
                                 unsigned short* __restrict__ pw2t,
                                 unsigned short* __restrict__ wqf) {
  int id = blockIdx.x * 256 + threadIdx.x;
  if (id < 16384) {
    int j = id & 7, lane = (id >> 3) & 63, rest = id >> 9;
    int mt = rest >> 1, h = rest & 1;
    w1f[id] = f2bf(w1[(32 * h + 8 * (lane >> 4) + j) * 256 + mt * 16 + (lane & 15)]);
  } else if (id < 32768) {
    int i = id - 16384;
    int j = i & 7, lane = (i >> 3) & 63, rest = i >> 9;
    int ct = rest >> 3, f = rest & 7;
    w2f[i] = f2bf(w2[(32 * f + 8 * (lane >> 4) + j) * 64 + ct * 16 + (lane & 15)]);
  } else if (id < 34816) {
    int i = id - 32768;
    int c = i >> 5, hh = i & 31;
    pw2t[i] = f2bf(pw2[hh * 64 + c]);
  } else if (id < 47104) {
    int i = id - 34816;
    int j = i & 7, lane = (i >> 3) & 63, rest = i >> 9;   // rest 0..23
    int ct = rest >> 1, h = rest & 1;
    wqf[i] = f2bf(qw[(32 * h + 8 * (lane >> 4) + j) * 192 + ct * 16 + (lane & 15)]);
  }
}

// ---------------- fused MFMA attention v2: one WAVE per point, zero barriers ----------------
// All LDS regions are wave-local (rows w*16..w*16+15); same-wave DS ops are
// pipeline-ordered, so no __syncthreads anywhere. H never touches LDS: GEMM1's
// transposed C-layout is re-shaped into GEMM2 A-frags with 2 shfl + 1 select
// per element (holder: quad = j2+2(q&1), reg hr[2f+(q>=2)][j&3]).
__global__ __launch_bounds__(256) void attn_mfma2_kernel(
    const float* __restrict__ p, const float* __restrict__ qkv,
    const int* __restrict__ idxf,
    const float* __restrict__ pos_w1, const float* __restrict__ pos_b1,
    const float* __restrict__ pos_b2,
    const float* __restrict__ attn_b1, const float* __restrict__ attn_b2,
    const unsigned short* __restrict__ w1f,
    const unsigned short* __restrict__ w2f,
    const unsigned short* __restrict__ pw2t,
    float* __restrict__ agg) {
  __shared__ unsigned short Ulds[64 * 72];   // [row][c] bf16, stride 72 (16B-aligned rows)
  __shared__ float VVlds[64 * 65];           // [c][row] fp32 transposed, stride 65
  __shared__ unsigned short PEH[64 * 40];    // [row][h] bf16

  const int t = threadIdx.x;
  const int lane = t & 63, w = t >> 6;
  const int l = lane & 15, q = lane >> 4;
  const int blk = blockIdx.x;                // 4096
  const int b = blk >> 10;
  const int n0 = (blk & 1023) * 4;
  const int pt_row = b * kN + n0 + w;        // this wave's point
  const f32x4 zero = {0.f, 0.f, 0.f, 0.f};

  int idxv = 0;
  if (lane < 16) idxv = idxf[(blk * 4 + w) * 16 + lane];

  // phase 1a: gather k/v; U = bf16(q - kj) [row][c]; VV^T[c][row] = vj
  {
    const int r = lane >> 2, seg = lane & 3;
    const int jrow = (b * kN + __shfl(idxv, r)) * 192;
    const int c0 = seg * 16;
    const float4* kb = reinterpret_cast<const float4*>(qkv + jrow + 64 + c0);
    const float4* vb = reinterpret_cast<const float4*>(qkv + jrow + 128 + c0);
    const float4* qb = reinterpret_cast<const float4*>(qkv + pt_row * 192 + c0);
    #pragma unroll
    for (int i = 0; i < 4; ++i) {
      float4 kv = kb[i], vv4 = vb[i], qq = qb[i];
      int c = c0 + i * 4;
      uint2 u2;
      u2.x = (unsigned int)f2bf(qq.x - kv.x) | ((unsigned int)f2bf(qq.y - kv.y) << 16);
      u2.y = (unsigned int)f2bf(qq.z - kv.z) | ((unsigned int)f2bf(qq.w - kv.w) << 16);
      *reinterpret_cast<uint2*>(&Ulds[(w * 16 + r) * 72 + c]) = u2;
      VVlds[(c + 0) * 65 + w * 16 + r] = vv4.x;
      VVlds[(c + 1) * 65 + w * 16 + r] = vv4.y;
      VVlds[(c + 2) * 65 + w * 16 + r] = vv4.z;
      VVlds[(c + 3) * 65 + w * 16 + r] = vv4.w;
    }
  }
  // phase 1b: pe hidden (3->32) for row l, hidden chunk q*8
  {
    const float* pn = p + pt_row * 3;
    const int nj = __shfl(idxv, l);
    const float* pj = p + (b * kN + nj) * 3;
    float rx = pn[0] - pj[0], ry = pn[1] - pj[1], rz = pn[2] - pj[2];
    unsigned short tmp[8];
    #pragma unroll
    for (int j = 0; j < 8; ++j) {
      int hh = q * 8 + j;
      float v = pos_b1[hh] + rx * pos_w1[hh] + ry * pos_w1[32 + hh] + rz * pos_w1[64 + hh];
      tmp[j] = f2bf(fmaxf(v, 0.0f));
    }
    uint4 pk;
    pk.x = (unsigned int)tmp[0] | ((unsigned int)tmp[1] << 16);
    pk.y = (unsigned int)tmp[2] | ((unsigned int)tmp[3] << 16);
    pk.z = (unsigned int)tmp[4] | ((unsigned int)tmp[5] << 16);
    pk.w = (unsigned int)tmp[6] | ((unsigned int)tmp[7] << 16);
    *reinterpret_cast<uint4*>(&PEH[(w * 16 + l) * 40 + q * 8]) = pk;
  }

  // phase 2: pe = pehid @ pos_w2 (transposed MFMA, D[c][row]); RMW U and VV
  {
    short8 pbf = *reinterpret_cast<const short8*>(&PEH[(w * 16 + l) * 40 + q * 8]);
    const int urow = (w * 16 + l) * 72;
    #pragma unroll
    for (int mt = 0; mt < 4; ++mt) {
      short8 paf = *reinterpret_cast<const short8*>(&pw2t[(mt * 16 + l) * 32 + q * 8]);
      f32x4 pe = __builtin_amdgcn_mfma_f32_16x16x32_bf16(paf, pbf, zero, 0, 0, 0);
      const int c0 = mt * 16 + q * 4;
      float4 b2v = *reinterpret_cast<const float4*>(&pos_b2[c0]);
      float pe0 = pe[0] + b2v.x, pe1 = pe[1] + b2v.y;
      float pe2 = pe[2] + b2v.z, pe3 = pe[3] + b2v.w;
      uint2 u2 = *reinterpret_cast<uint2*>(&Ulds[urow + c0]);
      uint2 o;
      o.x = (unsigned int)f2bf(bf2f(u2.x & 0xffffu) + pe0) |
            ((unsigned int)f2bf(bf2f(u2.x >> 16) + pe1) << 16);
      o.y = (unsigned int)f2bf(bf2f(u2.y & 0xffffu) + pe2) |
            ((unsigned int)f2bf(bf2f(u2.y >> 16) + pe3) << 16);
      *reinterpret_cast<uint2*>(&Ulds[urow + c0]) = o;
      VVlds[(c0 + 0) * 65 + w * 16 + l] += pe0;
      VVlds[(c0 + 1) * 65 + w * 16 + l] += pe1;
      VVlds[(c0 + 2) * 65 + w * 16 + l] += pe2;
      VVlds[(c0 + 3) * 65 + w * 16 + l] += pe3;
    }
  }

  // phase 3: GEMM1 transposed (D = W1^T · U^T): hr[mt] = H[row w*16+l][mt*16+q*4+i]
  f32x4 hr[16];
  {
    const int urow = (w * 16 + l) * 72;
    short8 ub0 = *reinterpret_cast<const short8*>(&Ulds[urow + q * 8]);
    short8 ub1 = *reinterpret_cast<const short8*>(&Ulds[urow + 32 + q * 8]);
    #pragma unroll
    for (int mt = 0; mt < 16; ++mt) {
      short8 a0 = *reinterpret_cast<const short8*>(&w1f[(mt * 2 + 0) * 512 + lane * 8]);
      short8 a1 = *reinterpret_cast<const short8*>(&w1f[(mt * 2 + 1) * 512 + lane * 8]);
      f32x4 acc = __builtin_amdgcn_mfma_f32_16x16x32_bf16(a0, ub0, zero, 0, 0, 0);
      acc = __builtin_amdgcn_mfma_f32_16x16x32_bf16(a1, ub1, acc, 0, 0, 0);
      float4 bb = *reinterpret_cast<const float4*>(&attn_b1[mt * 16 + q * 4]);
      hr[mt][0] = fmaxf(acc[0] + bb.x, 0.f);
      hr[mt][1] = fmaxf(acc[1] + bb.y, 0.f);
      hr[mt][2] = fmaxf(acc[2] + bb.z, 0.f);
      hr[mt][3] = fmaxf(acc[3] + bb.w, 0.f);
    }
  }

  // phase 4: GEMM2 via in-register repack; softmax over k; weighted sum of VV
  {
    f32x4 acc2[4];
    #pragma unroll
    for (int ct = 0; ct < 4; ++ct) acc2[ct] = zero;
    const int s0 = (2 * (q & 1)) * 16 + l;        // src lane, j2=0
    const int s1 = (1 + 2 * (q & 1)) * 16 + l;    // src lane, j2=1
    const bool hiq = (q >= 2);
    #pragma unroll
    for (int f = 0; f < 8; ++f) {
      unsigned short fr[8];
      #pragma unroll
      for (int j = 0; j < 8; ++j) {
        const int src = (j < 4) ? s0 : s1;
        float va = __shfl(hr[2 * f + 0][j & 3], src);
        float vb = __shfl(hr[2 * f + 1][j & 3], src);
        fr[j] = f2bf(hiq ? vb : va);
      }
      union { unsigned int u[4]; short8 s; } pk;
      #pragma unroll
      for (int ii = 0; ii < 4; ++ii)
        pk.u[ii] = (unsigned int)fr[2 * ii] | ((unsigned int)fr[2 * ii + 1] << 16);
      short8 afr = pk.s;
      #pragma unroll
      for (int ct = 0; ct < 4; ++ct) {
        short8 bfr = *reinterpret_cast<const short8*>(&w2f[((ct * 8 + f) * 64 + lane) * 8]);
        acc2[ct] = __builtin_amdgcn_mfma_f32_16x16x32_bf16(afr, bfr, acc2[ct], 0, 0, 0);
      }
    }
    // lane (l,q) holds sim[k = q*4+i][channel = ct*16+l] for point pt_row
    #pragma unroll
    for (int ct = 0; ct < 4; ++ct) {
      const int ch = ct * 16 + l;
      const float bv = attn_b2[ch];
      float s0v = acc2[ct][0] + bv, s1v = acc2[ct][1] + bv;
      float s2v = acc2[ct][2] + bv, s3v = acc2[ct][3] + bv;
      float mx = fmaxf(fmaxf(s0v, s1v), fmaxf(s2v, s3v));
      mx = fmaxf(mx, __shfl_xor(mx, 16, 64));
      mx = fmaxf(mx, __shfl_xor(mx, 32, 64));
      float e0 = __expf(s0v - mx), e1 = __expf(s1v - mx);
      float e2 = __expf(s2v - mx), e3 = __expf(s3v - mx);
      float se = e0 + e1 + e2 + e3;
      se += __shfl_xor(se, 16, 64);
      se += __shfl_xor(se, 32, 64);
      const int vbase = ch * 65 + w * 16 + q * 4;
      float a = e0 * VVlds[vbase + 0] + e1 * VVlds[vbase + 1] +
                e2 * VVlds[vbase + 2] + e3 * VVlds[vbase + 3];
      a += __shfl_xor(a, 16, 64);
      a += __shfl_xor(a, 32, 64);
      if (q == 0) agg[(blk * 4 + w) * 64 + ch] = a / se;
    }
  }
}

// ---------------- fc2 fused with bn2+relu+residual add ----------------
__global__ void fc2_kernel(const float* __restrict__ aggp, const float* __restrict__ hres,
                           const float* __restrict__ g2, const float* __restrict__ b2,
                           const float* __restrict__ mu2, const float* __restrict__ rs2,
                           const float* __restrict__ w, const float* __restrict__ bias,
                           float* __restrict__ z) {
  __shared__ float ss[16 * 64];
  __shared__ float ws[64 * 64];
  const int t = threadIdx.x;
  const int row0 = blockIdx.x * 16;
  #pragma unroll
  for (int i = 0; i < 4; ++i) {
    int e = t + i * 256;
    int c = e & 63;
    float a = aggp[row0 * 64 + e];
    float h2 = fmaxf(g2[c] * (a - mu2[c]) * rs2[c] + b2[c], 0.0f);
    ss[e] = h2 + hres[row0 * 64 + e];
  }
  #pragma unroll
  for (int i = 0; i < 16; ++i) ws[t + i * 256] = w[t + i * 256];
  __syncthreads();
  const int c = t & 63, rg = t >> 6;
  const float bc = bias[c];
  for (int rr = 0; rr < 4; ++rr) {
    const int r = rg + rr * 4;
    float acc = bc;
    #pragma unroll
    for (int kk = 0; kk < 64; ++kk) acc += ss[r * 64 + kk] * ws[kk * 64 + c];
    z[(row0 + r) * 64 + c] = acc;
  }
}

__global__ void final_kernel(const float* __restrict__ z, const float* __restrict__ g,
                             const float* __restrict__ b, const float* __restrict__ mu,
                             const float* __restrict__ rs, float* __restrict__ y) {
  int i = blockIdx.x * 256 + threadIdx.x;
  int c = i & 63;
  y[i] = fmaxf(g[c] * (z[i] - mu[c]) * rs[c] + b[c], 0.0f);
}

__global__ void copyp_kernel(const float* __restrict__ p, float* __restrict__ out) {
  int i = blockIdx.x * 256 + threadIdx.x;
  out[i] = p[i];
}

extern "C" void kernel_launch(void* const* d_in, const int* in_sizes, int n_in,
                              void* d_out, int out_size, void* d_ws, size_t ws_size,
                              hipStream_t stream) {
  const float* x       = (const float*)d_in[0];
  const float* p       = (const float*)d_in[1];
  const float* fc1_w   = (const float*)d_in[2];
  const float* fc1_b   = (const float*)d_in[3];
  const float* bn1_g   = (const float*)d_in[4];
  const float* bn1_b   = (const float*)d_in[5];
  const float* qkv_w   = (const float*)d_in[6];
  const float* pos_w1  = (const float*)d_in[7];
  const float* pos_b1  = (const float*)d_in[8];
  const float* pos_w2  = (const float*)d_in[9];
  const float* pos_b2  = (const float*)d_in[10];
  const float* attn_w1 = (const float*)d_in[11];
  const float* attn_b1 = (const float*)d_in[12];
  const float* attn_w2 = (const float*)d_in[13];
  const float* attn_b2 = (const float*)d_in[14];
  const float* bn2_g   = (const float*)d_in[15];
  const float* bn2_b   = (const float*)d_in[16];
  const float* fc2_w   = (const float*)d_in[17];
  const float* fc2_b   = (const float*)d_in[18];
  const float* bn3_g   = (const float*)d_in[19];
  const float* bn3_b   = (const float*)d_in[20];

  float* ws   = (float*)d_ws;
  float* h    = ws;                     // 1048576  (residual, fp32)
  float* qkvb = ws + 1048576;           // 3145728
  float* hpre = ws + 4194304;           // 1048576  (reused: packed bf16 weights)
  float* aggv = ws + 5242880;           // 1048576  (also stats partials)
  float* z    = ws + 6291456;           // 1048576  (also stats partials)
  float* sq   = ws + 7340032;           // 16384
  float* st   = ws + 7356416;           // 384
  int*   idxf = (int*)(ws + 7356800);   // 262144 ints
  unsigned short* hbf = (unsigned short*)(ws + 7618944);  // 1048576 bf16 (2 MB)
  unsigned short* w1f  = (unsigned short*)hpre;           // 16384
  unsigned short* w2f  = w1f + 16384;                     // 16384
  unsigned short* pw2t = w1f + 32768;                     // 2048
  unsigned short* wqf  = w1f + 34816;                     // 12288

  float* mu1 = st,       *rs1 = st + 64;
  float* mu2 = st + 128, *rs2 = st + 192;
  float* mu3 = st + 256, *rs3 = st + 320;
  float* y = (float*)d_out;

  fc1_kernel<<<1024, 256, 0, stream>>>(x, fc1_w, fc1_b, hpre);
  stats_part_kernel<<<256, 256, 0, stream>>>(hpre, aggv);
  stats_fin_kernel<<<1, 64, 0, stream>>>(aggv, mu1, rs1);
  bnrelu_kernel<<<4096, 256, 0, stream>>>(hpre, h, hbf, bn1_g, bn1_b, mu1, rs1);
  convert_w_kernel<<<184, 256, 0, stream>>>(attn_w1, attn_w2, pos_w2, qkv_w,
                                            w1f, w2f, pw2t, wqf);
  qkv_mfma_kernel<<<256, 256, 0, stream>>>(hbf, wqf, qkvb);
  sq_kernel<<<64, 256, 0, stream>>>(p, sq);
  knn_kernel<<<4096, 256, 0, stream>>>(p, sq, idxf);
  attn_mfma2_kernel<<<4096, 256, 0, stream>>>(p, qkvb, idxf, pos_w1, pos_b1, pos_b2,
                                              attn_b1, attn_b2, w1f, w2f, pw2t, aggv);
  stats_part_kernel<<<256, 256, 0, stream>>>(aggv, z);
  stats_fin_kernel<<<1, 64, 0, stream>>>(z, mu2, rs2);
  fc2_kernel<<<1024, 256, 0, stream>>>(aggv, h, bn2_g, bn2_b, mu2, rs2, fc2_w, fc2_b, z);
  stats_part_kernel<<<256, 256, 0, stream>>>(z, aggv);
  stats_fin_kernel<<<1, 64, 0, stream>>>(aggv, mu3, rs3);
  final_kernel<<<4096, 256, 0, stream>>>(z, bn3_g, bn3_b, mu3, rs3, y);
  copyp_kernel<<<192, 256, 0, stream>>>(p, y + 1048576);
}

// Round 7
// 322.917 us; speedup vs baseline: 3.7488x; 1.0848x over previous
//
#include <hip/hip_runtime.h>
#include <math.h>

constexpr int kB = 4, kN = 4096, kK = 16;
constexpr int kRows = kB * kN;          // 16384
constexpr float kEps = 1e-5f;
constexpr float kFltMax = 3.402823466e38f;
constexpr int kCap = 240;               // per-wave qualifier buffer (knn)

typedef __attribute__((ext_vector_type(8))) short short8;
typedef __attribute__((ext_vector_type(4))) float f32x4;

__device__ __forceinline__ unsigned short f2bf(float x) {
  unsigned int u = __float_as_uint(x);
  unsigned int r = (u + 0x7fffu + ((u >> 16) & 1u)) >> 16;
  return (unsigned short)r;
}
__device__ __forceinline__ float bf2f(unsigned int b) {
  return __uint_as_float(b << 16);
}
__device__ __forceinline__ short8 pack8f(float4 a, float4 b) {
  union { unsigned int u[4]; short8 s; } pk;
  pk.u[0] = (unsigned int)f2bf(a.x) | ((unsigned int)f2bf(a.y) << 16);
  pk.u[1] = (unsigned int)f2bf(a.z) | ((unsigned int)f2bf(a.w) << 16);
  pk.u[2] = (unsigned int)f2bf(b.x) | ((unsigned int)f2bf(b.y) << 16);
  pk.u[3] = (unsigned int)f2bf(b.z) | ((unsigned int)f2bf(b.w) << 16);
  return pk.s;
}

// Full 64-lane bitonic sort, ascending by (v, i) lexicographic.
__device__ __forceinline__ void bitonic64(float& sv, int& si, int lane) {
  #pragma unroll
  for (int k = 2; k <= 64; k <<= 1) {
    #pragma unroll
    for (int j = k >> 1; j > 0; j >>= 1) {
      float ov = __shfl_xor(sv, j);
      int   oi = __shfl_xor(si, j);
      bool up = ((lane & k) == 0);
      bool lower = ((lane & j) == 0);
      bool osm = (ov < sv) || (ov == sv && oi < si);
      bool take = (lower == up) ? osm : !osm;
      if (take) { sv = ov; si = oi; }
    }
  }
}

// ---------------- fc1 (MFMA bf16) + fused weight pre-pack ----------------
// wpak layout: [0,16384) w1f | [16384,32768) w2f | [32768,34816) pw2t |
//              [34816,47104) wqf | [47104,51200) fc2f
__global__ __launch_bounds__(256) void fc1_conv_kernel(
    const float* __restrict__ x, const float* __restrict__ w,
    const float* __restrict__ bias,
    const float* __restrict__ aw1, const float* __restrict__ aw2,
    const float* __restrict__ pw2, const float* __restrict__ qw,
    const float* __restrict__ f2w,
    unsigned short* __restrict__ wpak,
    float* __restrict__ out) {
  __shared__ unsigned short wf[8 * 512];   // fc1_w B-frags, 8 KB
  const int t = threadIdx.x;
  const int blk = blockIdx.x;              // 256 blocks
  // fused global weight pre-pack (one id per thread; 51200 total < 65536)
  {
    int id = blk * 256 + t;
    if (id < 16384) {
      int j = id & 7, lane = (id >> 3) & 63, rest = id >> 9;
      int mt = rest >> 1, hh = rest & 1;
      wpak[id] = f2bf(aw1[(32 * hh + 8 * (lane >> 4) + j) * 256 + mt * 16 + (lane & 15)]);
    } else if (id < 32768) {
      int i = id - 16384;
      int j = i & 7, lane = (i >> 3) & 63, rest = i >> 9;
      int ct = rest >> 3, f = rest & 7;
      wpak[id] = f2bf(aw2[(32 * f + 8 * (lane >> 4) + j) * 64 + ct * 16 + (lane & 15)]);
    } else if (id < 34816) {
      int i = id - 32768;
      int c = i >> 5, hh = i & 31;
      wpak[id] = f2bf(pw2[hh * 64 + c]);
    } else if (id < 47104) {
      int i = id - 34816;
      int j = i & 7, lane = (i >> 3) & 63, rest = i >> 9;   // rest 0..23
      int ct = rest >> 1, hh = rest & 1;
      wpak[id] = f2bf(qw[(32 * hh + 8 * (lane >> 4) + j) * 192 + ct * 16 + (lane & 15)]);
    } else if (id < 51200) {
      int i = id - 47104;
      int j = i & 7, lane = (i >> 3) & 63, rest = i >> 9;   // rest 0..7
      int ct = rest >> 1, hh = rest & 1;
      wpak[id] = f2bf(f2w[(32 * hh + 8 * (lane >> 4) + j) * 64 + ct * 16 + (lane & 15)]);
    }
  }
  // per-block fc1_w frag pack
  for (int i = t; i < 4096; i += 256) {
    int j = i & 7, lane = (i >> 3) & 63, rest = i >> 9;
    int ct = rest >> 1, hh = rest & 1;
    wf[i] = f2bf(w[(32 * hh + 8 * (lane >> 4) + j) * 64 + ct * 16 + (lane & 15)]);
  }
  __syncthreads();
  const int lane = t & 63, wv = t >> 6;
  const int l = lane & 15, q = lane >> 4;
  const int r0 = blk * 64;
  const int row = r0 + wv * 16 + l;
  const f32x4 zero = {0.f, 0.f, 0.f, 0.f};
  float4 xa0 = *reinterpret_cast<const float4*>(&x[row * 64 + q * 8]);
  float4 xa1 = *reinterpret_cast<const float4*>(&x[row * 64 + q * 8 + 4]);
  float4 xb0 = *reinterpret_cast<const float4*>(&x[row * 64 + 32 + q * 8]);
  float4 xb1 = *reinterpret_cast<const float4*>(&x[row * 64 + 32 + q * 8 + 4]);
  short8 a0 = pack8f(xa0, xa1), a1 = pack8f(xb0, xb1);
  #pragma unroll
  for (int ct = 0; ct < 4; ++ct) {
    short8 b0 = *reinterpret_cast<const short8*>(&wf[(ct * 2 + 0) * 512 + lane * 8]);
    short8 b1 = *reinterpret_cast<const short8*>(&wf[(ct * 2 + 1) * 512 + lane * 8]);
    f32x4 acc = __builtin_amdgcn_mfma_f32_16x16x32_bf16(a0, b0, zero, 0, 0, 0);
    acc = __builtin_amdgcn_mfma_f32_16x16x32_bf16(a1, b1, acc, 0, 0, 0);
    const float bc = bias[ct * 16 + l];
    #pragma unroll
    for (int i = 0; i < 4; ++i)
      out[(r0 + wv * 16 + q * 4 + i) * 64 + ct * 16 + l] = acc[i] + bc;
  }
}

// ---------------- batchnorm stats ----------------
__global__ void stats_part_kernel(const float* __restrict__ src, float* __restrict__ part) {
  __shared__ float sb[256], sb2[256];
  const int t = threadIdx.x, blk = blockIdx.x;
  const int c = t & 63, rg = t >> 6;
  float s = 0.f, s2 = 0.f;
  for (int r = rg; r < 64; r += 4) {
    float v = src[(blk * 64 + r) * 64 + c];
    s += v; s2 += v * v;
  }
  sb[t] = s; sb2[t] = s2; __syncthreads();
  if (t < 64) {
    float ts  = sb[t] + sb[64 + t] + sb[128 + t] + sb[192 + t];
    float ts2 = sb2[t] + sb2[64 + t] + sb2[128 + t] + sb2[192 + t];
    part[blk * 128 + t] = ts;
    part[blk * 128 + 64 + t] = ts2;
  }
}

// emits affine form: A = g*rs, B = b - mu*g*rs  (bn(v) = A*v + B)
__global__ void stats_fin_kernel(const float* __restrict__ part,
                                 const float* __restrict__ g, const float* __restrict__ b,
                                 float* __restrict__ A, float* __restrict__ Bv) {
  const int c = threadIdx.x;  // 64
  double s = 0.0, s2 = 0.0;
  for (int i = 0; i < 256; ++i) { s += part[i * 128 + c]; s2 += part[i * 128 + 64 + c]; }
  double mean = s / (double)kRows;
  double var = s2 / (double)kRows - mean * mean;
  float rs = (float)(1.0 / sqrt(var + (double)kEps));
  float Af = g[c] * rs;
  A[c] = Af;
  Bv[c] = b[c] - (float)mean * Af;
}

// ---------------- qkv (MFMA) with fused bn1+relu; writes h fp32 + qkv fp32 ----------------
__global__ __launch_bounds__(256) void qkv_bn_kernel(
    const float* __restrict__ hpre, const float* __restrict__ A1,
    const float* __restrict__ B1, const unsigned short* __restrict__ wqf,
    float* __restrict__ hout, float* __restrict__ out) {
  const int t = threadIdx.x, lane = t & 63, wv = t >> 6;
  const int l = lane & 15, q = lane >> 4;
  const int r0 = blockIdx.x * 64;
  const int row = r0 + wv * 16 + l;
  const f32x4 zero = {0.f, 0.f, 0.f, 0.f};
  short8 af[2];
  #pragma unroll
  for (int hh = 0; hh < 2; ++hh) {
    const int c0 = 32 * hh + q * 8;
    float4 v0 = *reinterpret_cast<const float4*>(&hpre[row * 64 + c0]);
    float4 v1 = *reinterpret_cast<const float4*>(&hpre[row * 64 + c0 + 4]);
    float4 Aa = *reinterpret_cast<const float4*>(&A1[c0]);
    float4 Ab = *reinterpret_cast<const float4*>(&A1[c0 + 4]);
    float4 Ba = *reinterpret_cast<const float4*>(&B1[c0]);
    float4 Bb = *reinterpret_cast<const float4*>(&B1[c0 + 4]);
    v0.x = fmaxf(Aa.x * v0.x + Ba.x, 0.f); v0.y = fmaxf(Aa.y * v0.y + Ba.y, 0.f);
    v0.z = fmaxf(Aa.z * v0.z + Ba.z, 0.f); v0.w = fmaxf(Aa.w * v0.w + Ba.w, 0.f);
    v1.x = fmaxf(Ab.x * v1.x + Bb.x, 0.f); v1.y = fmaxf(Ab.y * v1.y + Bb.y, 0.f);
    v1.z = fmaxf(Ab.z * v1.z + Bb.z, 0.f); v1.w = fmaxf(Ab.w * v1.w + Bb.w, 0.f);
    *reinterpret_cast<float4*>(&hout[row * 64 + c0]) = v0;
    *reinterpret_cast<float4*>(&hout[row * 64 + c0 + 4]) = v1;
    af[hh] = pack8f(v0, v1);
  }
  #pragma unroll
  for (int ct = 0; ct < 12; ++ct) {
    short8 b0 = *reinterpret_cast<const short8*>(&wqf[((ct * 2 + 0) * 64 + lane) * 8]);
    short8 b1 = *reinterpret_cast<const short8*>(&wqf[((ct * 2 + 1) * 64 + lane) * 8]);
    f32x4 acc = __builtin_amdgcn_mfma_f32_16x16x32_bf16(af[0], b0, zero, 0, 0, 0);
    acc = __builtin_amdgcn_mfma_f32_16x16x32_bf16(af[1], b1, acc, 0, 0, 0);
    #pragma unroll
    for (int i = 0; i < 4; ++i)
      out[(r0 + wv * 16 + q * 4 + i) * 192 + ct * 16 + l] = acc[i];
  }
}

// ---------------- kNN v2: subset-tau + single filtered scan ----------------
// Chunk 0 is scanned once with d2 kept in registers; tau = 16th-smallest of
// the 64 lane-minima of chunk 0 (upper bound on the global 16th distance).
// Chunk-0 qualifiers replay from registers (same-site exact); chunks 1..3 get
// ONE filtered scan each. sq computed inline (sq_kernel removed).
__global__ __launch_bounds__(256) void knn_kernel(
    const float* __restrict__ p, int* __restrict__ idxf) {
  __shared__ float4 pts[1024];
  __shared__ float bufv[4][kCap];
  __shared__ int   bufi[4][kCap];
  __shared__ int   cnt[4];
  const int t = threadIdx.x;
  const int lane = t & 63, w = t >> 6;
  const int blk = blockIdx.x;
  const int b = blk >> 10;
  const int q = blk * 4 + w;
  const float qx = p[q * 3], qy = p[q * 3 + 1], qz = p[q * 3 + 2];
  const float sqq = qx * qx + qy * qy + qz * qz;
  if (lane == 0) cnt[w] = 0;

  float sv = kFltMax;
  int   si = 0x7fffffff;

  // ---- chunk 0: stage + scan (keep d2 in regs) ----
  #pragma unroll
  for (int i = 0; i < 4; ++i) {
    int j = t + i * 256;
    int g = b * kN + j;
    float px = p[g * 3], py = p[g * 3 + 1], pz = p[g * 3 + 2];
    pts[j] = make_float4(px, py, pz, px * px + py * py + pz * pz);
  }
  __syncthreads();
  float d2r[16];
  float lmin = kFltMax;
  #pragma unroll
  for (int i = 0; i < 16; ++i) {
    float4 pt = pts[i * 64 + lane];
    float d2 = sqq + pt.w - 2.0f * (qx * pt.x + qy * pt.y + qz * pt.z);
    d2r[i] = d2;
    lmin = fminf(lmin, d2);
  }
  {
    int dummy = lane;
    bitonic64(lmin, dummy, lane);
  }
  const float thrA = __shfl(lmin, 15) + 1e-3f;  // margin: cross-site FMA wobble
  float thr = thrA;

  // replay chunk-0 qualifiers from registers
  #pragma unroll
  for (int i = 0; i < 16; ++i) {
    if (d2r[i] <= thr) {
      int pos = atomicAdd(&cnt[w], 1);
      if (pos < kCap) { bufv[w][pos] = d2r[i]; bufi[w][pos] = i * 64 + lane; }
    }
  }
  {
    int n = cnt[w];
    if (n > 0) {
      if (n > kCap) {
        for (int g0 = 0; g0 < 1024; g0 += 48) {
          float mv; int mi;
          if (lane < 16) { mv = sv; mi = si; }
          else {
            int jj = g0 + (lane - 16);
            if (jj < 1024) {
              float4 pt = pts[jj];
              mv = sqq + pt.w - 2.0f * (qx * pt.x + qy * pt.y + qz * pt.z);
              mi = jj;
            } else { mv = kFltMax; mi = 0x7fffffff; }
          }
          bitonic64(mv, mi, lane);
          sv = mv; si = mi;
        }
      } else {
        for (int g0 = 0; g0 < n; g0 += 48) {
          float mv; int mi;
          if (lane < 16) { mv = sv; mi = si; }
          else {
            int pos = g0 + (lane - 16);
            if (pos < n) { mv = bufv[w][pos]; mi = bufi[w][pos]; }
            else { mv = kFltMax; mi = 0x7fffffff; }
          }
          bitonic64(mv, mi, lane);
          sv = mv; si = mi;
        }
      }
      if (lane == 0) cnt[w] = 0;
      thr = fminf(thrA, __shfl(sv, 15));
    }
  }

  // ---- chunks 1..3: single filtered scan ----
  for (int c0 = 1024; c0 < kN; c0 += 1024) {
    __syncthreads();
    #pragma unroll
    for (int i = 0; i < 4; ++i) {
      int j = t + i * 256;
      int g = b * kN + c0 + j;
      float px = p[g * 3], py = p[g * 3 + 1], pz = p[g * 3 + 2];
      pts[j] = make_float4(px, py, pz, px * px + py * py + pz * pz);
    }
    __syncthreads();
    #pragma unroll
    for (int i = 0; i < 16; ++i) {
      float4 pt = pts[i * 64 + lane];
      float d2 = sqq + pt.w - 2.0f * (qx * pt.x + qy * pt.y + qz * pt.z);
      if (d2 <= thr) {
        int pos = atomicAdd(&cnt[w], 1);
        if (pos < kCap) { bufv[w][pos] = d2; bufi[w][pos] = c0 + i * 64 + lane; }
      }
    }
    int n = cnt[w];
    if (n > 0) {
      if (n > kCap) {
        for (int g0 = 0; g0 < 1024; g0 += 48) {
          float mv; int mi;
          if (lane < 16) { mv = sv; mi = si; }
          else {
            int jj = g0 + (lane - 16);
            if (jj < 1024) {
              float4 pt = pts[jj];
              mv = sqq + pt.w - 2.0f * (qx * pt.x + qy * pt.y + qz * pt.z);
              mi = c0 + jj;
            } else { mv = kFltMax; mi = 0x7fffffff; }
          }
          bitonic64(mv, mi, lane);
          sv = mv; si = mi;
        }
      } else {
        for (int g0 = 0; g0 < n; g0 += 48) {
          float mv; int mi;
          if (lane < 16) { mv = sv; mi = si; }
          else {
            int pos = g0 + (lane - 16);
            if (pos < n) { mv = bufv[w][pos]; mi = bufi[w][pos]; }
            else { mv = kFltMax; mi = 0x7fffffff; }
          }
          bitonic64(mv, mi, lane);
          sv = mv; si = mi;
        }
      }
      if (lane == 0) cnt[w] = 0;
      thr = fminf(thrA, __shfl(sv, 15));
    }
  }
  if (lane < 16) {
    int out = si;
    if ((unsigned)out >= (unsigned)kN) out = 0;  // safety net: wrong beats fault
    idxf[q * 16 + lane] = out;
  }
}

// ---------------- fused MFMA attention v2 (unchanged, R6-verified) ----------------
__global__ __launch_bounds__(256) void attn_mfma2_kernel(
    const float* __restrict__ p, const float* __restrict__ qkv,
    const int* __restrict__ idxf,
    const float* __restrict__ pos_w1, const float* __restrict__ pos_b1,
    const float* __restrict__ pos_b2,
    const float* __restrict__ attn_b1, const float* __restrict__ attn_b2,
    const unsigned short* __restrict__ w1f,
    const unsigned short* __restrict__ w2f,
    const unsigned short* __restrict__ pw2t,
    float* __restrict__ agg) {
  __shared__ unsigned short Ulds[64 * 72];
  __shared__ float VVlds[64 * 65];
  __shared__ unsigned short PEH[64 * 40];

  const int t = threadIdx.x;
  const int lane = t & 63, w = t >> 6;
  const int l = lane & 15, q = lane >> 4;
  const int blk = blockIdx.x;
  const int b = blk >> 10;
  const int n0 = (blk & 1023) * 4;
  const int pt_row = b * kN + n0 + w;
  const f32x4 zero = {0.f, 0.f, 0.f, 0.f};

  int idxv = 0;
  if (lane < 16) idxv = idxf[(blk * 4 + w) * 16 + lane];

  {
    const int r = lane >> 2, seg = lane & 3;
    const int jrow = (b * kN + __shfl(idxv, r)) * 192;
    const int c0 = seg * 16;
    const float4* kb = reinterpret_cast<const float4*>(qkv + jrow + 64 + c0);
    const float4* vb = reinterpret_cast<const float4*>(qkv + jrow + 128 + c0);
    const float4* qb = reinterpret_cast<const float4*>(qkv + pt_row * 192 + c0);
    #pragma unroll
    for (int i = 0; i < 4; ++i) {
      float4 kv = kb[i], vv4 = vb[i], qq = qb[i];
      int c = c0 + i * 4;
      uint2 u2;
      u2.x = (unsigned int)f2bf(qq.x - kv.x) | ((unsigned int)f2bf(qq.y - kv.y) << 16);
      u2.y = (unsigned int)f2bf(qq.z - kv.z) | ((unsigned int)f2bf(qq.w - kv.w) << 16);
      *reinterpret_cast<uint2*>(&Ulds[(w * 16 + r) * 72 + c]) = u2;
      VVlds[(c + 0) * 65 + w * 16 + r] = vv4.x;
      VVlds[(c + 1) * 65 + w * 16 + r] = vv4.y;
      VVlds[(c + 2) * 65 + w * 16 + r] = vv4.z;
      VVlds[(c + 3) * 65 + w * 16 + r] = vv4.w;
    }
  }
  {
    const float* pn = p + pt_row * 3;
    const int nj = __shfl(idxv, l);
    const float* pj = p + (b * kN + nj) * 3;
    float rx = pn[0] - pj[0], ry = pn[1] - pj[1], rz = pn[2] - pj[2];
    unsigned short tmp[8];
    #pragma unroll
    for (int j = 0; j < 8; ++j) {
      int hh = q * 8 + j;
      float v = pos_b1[hh] + rx * pos_w1[hh] + ry * pos_w1[32 + hh] + rz * pos_w1[64 + hh];
      tmp[j] = f2bf(fmaxf(v, 0.0f));
    }
    uint4 pk;
    pk.x = (unsigned int)tmp[0] | ((unsigned int)tmp[1] << 16);
    pk.y = (unsigned int)tmp[2] | ((unsigned int)tmp[3] << 16);
    pk.z = (unsigned int)tmp[4] | ((unsigned int)tmp[5] << 16);
    pk.w = (unsigned int)tmp[6] | ((unsigned int)tmp[7] << 16);
    *reinterpret_cast<uint4*>(&PEH[(w * 16 + l) * 40 + q * 8]) = pk;
  }

  {
    short8 pbf = *reinterpret_cast<const short8*>(&PEH[(w * 16 + l) * 40 + q * 8]);
    const int urow = (w * 16 + l) * 72;
    #pragma unroll
    for (int mt = 0; mt < 4; ++mt) {
      short8 paf = *reinterpret_cast<const short8*>(&pw2t[(mt * 16 + l) * 32 + q * 8]);
      f32x4 pe = __builtin_amdgcn_mfma_f32_16x16x32_bf16(paf, pbf, zero, 0, 0, 0);
      const int c0 = mt * 16 + q * 4;
      float4 b2v = *reinterpret_cast<const float4*>(&pos_b2[c0]);
      float pe0 = pe[0] + b2v.x, pe1 = pe[1] + b2v.y;
      float pe2 = pe[2] + b2v.z, pe3 = pe[3] + b2v.w;
      uint2 u2 = *reinterpret_cast<uint2*>(&Ulds[urow + c0]);
      uint2 o;
      o.x = (unsigned int)f2bf(bf2f(u2.x & 0xffffu) + pe0) |
            ((unsigned int)f2bf(bf2f(u2.x >> 16) + pe1) << 16);
      o.y = (unsigned int)f2bf(bf2f(u2.y & 0xffffu) + pe2) |
            ((unsigned int)f2bf(bf2f(u2.y >> 16) + pe3) << 16);
      *reinterpret_cast<uint2*>(&Ulds[urow + c0]) = o;
      VVlds[(c0 + 0) * 65 + w * 16 + l] += pe0;
      VVlds[(c0 + 1) * 65 + w * 16 + l] += pe1;
      VVlds[(c0 + 2) * 65 + w * 16 + l] += pe2;
      VVlds[(c0 + 3) * 65 + w * 16 + l] += pe3;
    }
  }

  f32x4 hr[16];
  {
    const int urow = (w * 16 + l) * 72;
    short8 ub0 = *reinterpret_cast<const short8*>(&Ulds[urow + q * 8]);
    short8 ub1 = *reinterpret_cast<const short8*>(&Ulds[urow + 32 + q * 8]);
    #pragma unroll
    for (int mt = 0; mt < 16; ++mt) {
      short8 a0 = *reinterpret_cast<const short8*>(&w1f[(mt * 2 + 0) * 512 + lane * 8]);
      short8 a1 = *reinterpret_cast<const short8*>(&w1f[(mt * 2 + 1) * 512 + lane * 8]);
      f32x4 acc = __builtin_amdgcn_mfma_f32_16x16x32_bf16(a0, ub0, zero, 0, 0, 0);
      acc = __builtin_amdgcn_mfma_f32_16x16x32_bf16(a1, ub1, acc, 0, 0, 0);
      float4 bb = *reinterpret_cast<const float4*>(&attn_b1[mt * 16 + q * 4]);
      hr[mt][0] = fmaxf(acc[0] + bb.x, 0.f);
      hr[mt][1] = fmaxf(acc[1] + bb.y, 0.f);
      hr[mt][2] = fmaxf(acc[2] + bb.z, 0.f);
      hr[mt][3] = fmaxf(acc[3] + bb.w, 0.f);
    }
  }

  {
    f32x4 acc2[4];
    #pragma unroll
    for (int ct = 0; ct < 4; ++ct) acc2[ct] = zero;
    const int s0 = (2 * (q & 1)) * 16 + l;
    const int s1 = (1 + 2 * (q & 1)) * 16 + l;
    const bool hiq = (q >= 2);
    #pragma unroll
    for (int f = 0; f < 8; ++f) {
      unsigned short fr[8];
      #pragma unroll
      for (int j = 0; j < 8; ++j) {
        const int src = (j < 4) ? s0 : s1;
        float va = __shfl(hr[2 * f + 0][j & 3], src);
        float vb = __shfl(hr[2 * f + 1][j & 3], src);
        fr[j] = f2bf(hiq ? vb : va);
      }
      union { unsigned int u[4]; short8 s; } pk;
      #pragma unroll
      for (int ii = 0; ii < 4; ++ii)
        pk.u[ii] = (unsigned int)fr[2 * ii] | ((unsigned int)fr[2 * ii + 1] << 16);
      short8 afr = pk.s;
      #pragma unroll
      for (int ct = 0; ct < 4; ++ct) {
        short8 bfr = *reinterpret_cast<const short8*>(&w2f[((ct * 8 + f) * 64 + lane) * 8]);
        acc2[ct] = __builtin_amdgcn_mfma_f32_16x16x32_bf16(afr, bfr, acc2[ct], 0, 0, 0);
      }
    }
    #pragma unroll
    for (int ct = 0; ct < 4; ++ct) {
      const int ch = ct * 16 + l;
      const float bv = attn_b2[ch];
      float s0v = acc2[ct][0] + bv, s1v = acc2[ct][1] + bv;
      float s2v = acc2[ct][2] + bv, s3v = acc2[ct][3] + bv;
      float mx = fmaxf(fmaxf(s0v, s1v), fmaxf(s2v, s3v));
      mx = fmaxf(mx, __shfl_xor(mx, 16, 64));
      mx = fmaxf(mx, __shfl_xor(mx, 32, 64));
      float e0 = __expf(s0v - mx), e1 = __expf(s1v - mx);
      float e2 = __expf(s2v - mx), e3 = __expf(s3v - mx);
      float se = e0 + e1 + e2 + e3;
      se += __shfl_xor(se, 16, 64);
      se += __shfl_xor(se, 32, 64);
      const int vbase = ch * 65 + w * 16 + q * 4;
      float a = e0 * VVlds[vbase + 0] + e1 * VVlds[vbase + 1] +
                e2 * VVlds[vbase + 2] + e3 * VVlds[vbase + 3];
      a += __shfl_xor(a, 16, 64);
      a += __shfl_xor(a, 32, 64);
      if (q == 0) agg[(blk * 4 + w) * 64 + ch] = a / se;
    }
  }
}

// ---------------- fc2 (MFMA) with fused bn2+relu+residual prologue ----------------
__global__ __launch_bounds__(256) void fc2_mfma_kernel(
    const float* __restrict__ aggp, const float* __restrict__ hres,
    const float* __restrict__ A2, const float* __restrict__ B2,
    const unsigned short* __restrict__ fc2f, const float* __restrict__ bias,
    float* __restrict__ z) {
  const int t = threadIdx.x, lane = t & 63, wv = t >> 6;
  const int l = lane & 15, q = lane >> 4;
  const int r0 = blockIdx.x * 64;
  const int row = r0 + wv * 16 + l;
  const f32x4 zero = {0.f, 0.f, 0.f, 0.f};
  short8 af[2];
  #pragma unroll
  for (int hh = 0; hh < 2; ++hh) {
    const int c0 = 32 * hh + q * 8;
    float4 v0 = *reinterpret_cast<const float4*>(&aggp[row * 64 + c0]);
    float4 v1 = *reinterpret_cast<const float4*>(&aggp[row * 64 + c0 + 4]);
    float4 r0v = *reinterpret_cast<const float4*>(&hres[row * 64 + c0]);
    float4 r1v = *reinterpret_cast<const float4*>(&hres[row * 64 + c0 + 4]);
    float4 Aa = *reinterpret_cast<const float4*>(&A2[c0]);
    float4 Ab = *reinterpret_cast<const float4*>(&A2[c0 + 4]);
    float4 Ba = *reinterpret_cast<const float4*>(&B2[c0]);
    float4 Bb = *reinterpret_cast<const float4*>(&B2[c0 + 4]);
    v0.x = fmaxf(Aa.x * v0.x + Ba.x, 0.f) + r0v.x;
    v0.y = fmaxf(Aa.y * v0.y + Ba.y, 0.f) + r0v.y;
    v0.z = fmaxf(Aa.z * v0.z + Ba.z, 0.f) + r0v.z;
    v0.w = fmaxf(Aa.w * v0.w + Ba.w, 0.f) + r0v.w;
    v1.x = fmaxf(Ab.x * v1.x + Bb.x, 0.f) + r1v.x;
    v1.y = fmaxf(Ab.y * v1.y + Bb.y, 0.f) + r1v.y;
    v1.z = fmaxf(Ab.z * v1.z + Bb.z, 0.f) + r1v.z;
    v1.w = fmaxf(Ab.w * v1.w + Bb.w, 0.f) + r1v.w;
    af[hh] = pack8f(v0, v1);
  }
  #pragma unroll
  for (int ct = 0; ct < 4; ++ct) {
    short8 b0 = *reinterpret_cast<const short8*>(&fc2f[((ct * 2 + 0) * 64 + lane) * 8]);
    short8 b1 = *reinterpret_cast<const short8*>(&fc2f[((ct * 2 + 1) * 64 + lane) * 8]);
    f32x4 acc = __builtin_amdgcn_mfma_f32_16x16x32_bf16(af[0], b0, zero, 0, 0, 0);
    acc = __builtin_amdgcn_mfma_f32_16x16x32_bf16(af[1], b1, acc, 0, 0, 0);
    const float bc = bias[ct * 16 + l];
    #pragma unroll
    for (int i = 0; i < 4; ++i)
      z[(r0 + wv * 16 + q * 4 + i) * 64 + ct * 16 + l] = acc[i] + bc;
  }
}

// ---------------- final bn3+relu, fused p-copy ----------------
__global__ void final_kernel(const float* __restrict__ z, const float* __restrict__ A3,
                             const float* __restrict__ B3, const float* __restrict__ p,
                             float* __restrict__ y) {
  const int blk = blockIdx.x, t = threadIdx.x;
  if (blk < 4096) {
    int i = blk * 256 + t;
    int c = i & 63;
    y[i] = fmaxf(A3[c] * z[i] + B3[c], 0.0f);
  } else {
    int i = (blk - 4096) * 256 + t;
    y[1048576 + i] = p[i];
  }
}

extern "C" void kernel_launch(void* const* d_in, const int* in_sizes, int n_in,
                              void* d_out, int out_size, void* d_ws, size_t ws_size,
                              hipStream_t stream) {
  const float* x       = (const float*)d_in[0];
  const float* p       = (const float*)d_in[1];
  const float* fc1_w   = (const float*)d_in[2];
  const float* fc1_b   = (const float*)d_in[3];
  const float* bn1_g   = (const float*)d_in[4];
  const float* bn1_b   = (const float*)d_in[5];
  const float* qkv_w   = (const float*)d_in[6];
  const float* pos_w1  = (const float*)d_in[7];
  const float* pos_b1  = (const float*)d_in[8];
  const float* pos_w2  = (const float*)d_in[9];
  const float* pos_b2  = (const float*)d_in[10];
  const float* attn_w1 = (const float*)d_in[11];
  const float* attn_b1 = (const float*)d_in[12];
  const float* attn_w2 = (const float*)d_in[13];
  const float* attn_b2 = (const float*)d_in[14];
  const float* bn2_g   = (const float*)d_in[15];
  const float* bn2_b   = (const float*)d_in[16];
  const float* fc2_w   = (const float*)d_in[17];
  const float* fc2_b   = (const float*)d_in[18];
  const float* bn3_g   = (const float*)d_in[19];
  const float* bn3_b   = (const float*)d_in[20];

  float* ws   = (float*)d_ws;
  float* h    = ws;                     // 1048576  (residual, fp32)
  float* qkvb = ws + 1048576;           // 3145728
  float* hpre = ws + 4194304;           // 1048576
  float* aggv = ws + 5242880;           // 1048576  (also stats partials 1,3)
  float* z    = ws + 6291456;           // 1048576  (also stats partials 2)
  float* st   = ws + 7340032;           // 384 (A1,B1,A2,B2,A3,B3)
  int*   idxf = (int*)(ws + 7356800);   // 262144 ints
  unsigned short* wpak = (unsigned short*)(ws + 7618944);  // 51200 bf16
  unsigned short* w1f  = wpak;
  unsigned short* w2f  = wpak + 16384;
  unsigned short* pw2t = wpak + 32768;
  unsigned short* wqf  = wpak + 34816;
  unsigned short* fc2f = wpak + 47104;

  float* A1 = st,       *B1 = st + 64;
  float* A2 = st + 128, *B2 = st + 192;
  float* A3 = st + 256, *B3 = st + 320;
  float* y = (float*)d_out;

  fc1_conv_kernel<<<256, 256, 0, stream>>>(x, fc1_w, fc1_b, attn_w1, attn_w2,
                                           pos_w2, qkv_w, fc2_w, wpak, hpre);
  stats_part_kernel<<<256, 256, 0, stream>>>(hpre, aggv);
  stats_fin_kernel<<<1, 64, 0, stream>>>(aggv, bn1_g, bn1_b, A1, B1);
  qkv_bn_kernel<<<256, 256, 0, stream>>>(hpre, A1, B1, wqf, h, qkvb);
  knn_kernel<<<4096, 256, 0, stream>>>(p, idxf);
  attn_mfma2_kernel<<<4096, 256, 0, stream>>>(p, qkvb, idxf, pos_w1, pos_b1, pos_b2,
                                              attn_b1, attn_b2, w1f, w2f, pw2t, aggv);
  stats_part_kernel<<<256, 256, 0, stream>>>(aggv, z);
  stats_fin_kernel<<<1, 64, 0, stream>>>(z, bn2_g, bn2_b, A2, B2);
  fc2_mfma_kernel<<<256, 256, 0, stream>>>(aggv, h, A2, B2, fc2f, fc2_b, z);
  stats_part_kernel<<<256, 256, 0, stream>>>(z, aggv);
  stats_fin_kernel<<<1, 64, 0, stream>>>(aggv, bn3_g, bn3_b, A3, B3);
  final_kernel<<<4288, 256, 0, stream>>>(z, A3, B3, p, y);
}

// Round 8
// 316.832 us; speedup vs baseline: 3.8208x; 1.0192x over previous
//
#include <hip/hip_runtime.h>
#include <math.h>

constexpr int kB = 4, kN = 4096, kK = 16;
constexpr int kRows = kB * kN;          // 16384
constexpr float kEps = 1e-5f;
constexpr float kFltMax = 3.402823466e38f;
constexpr int kCap = 240;               // per-wave qualifier buffer (knn)

typedef __attribute__((ext_vector_type(8))) short short8;
typedef __attribute__((ext_vector_type(4))) float f32x4;

__device__ __forceinline__ unsigned short f2bf(float x) {
  unsigned int u = __float_as_uint(x);
  unsigned int r = (u + 0x7fffu + ((u >> 16) & 1u)) >> 16;
  return (unsigned short)r;
}
__device__ __forceinline__ float bf2f(unsigned int b) {
  return __uint_as_float(b << 16);
}
__device__ __forceinline__ short8 pack8f(float4 a, float4 b) {
  union { unsigned int u[4]; short8 s; } pk;
  pk.u[0] = (unsigned int)f2bf(a.x) | ((unsigned int)f2bf(a.y) << 16);
  pk.u[1] = (unsigned int)f2bf(a.z) | ((unsigned int)f2bf(a.w) << 16);
  pk.u[2] = (unsigned int)f2bf(b.x) | ((unsigned int)f2bf(b.y) << 16);
  pk.u[3] = (unsigned int)f2bf(b.z) | ((unsigned int)f2bf(b.w) << 16);
  return pk.s;
}

// Full 64-lane bitonic sort, ascending by (v, i) lexicographic.
__device__ __forceinline__ void bitonic64(float& sv, int& si, int lane) {
  #pragma unroll
  for (int k = 2; k <= 64; k <<= 1) {
    #pragma unroll
    for (int j = k >> 1; j > 0; j >>= 1) {
      float ov = __shfl_xor(sv, j);
      int   oi = __shfl_xor(si, j);
      bool up = ((lane & k) == 0);
      bool lower = ((lane & j) == 0);
      bool osm = (ov < sv) || (ov == sv && oi < si);
      bool take = (lower == up) ? osm : !osm;
      if (take) { sv = ov; si = oi; }
    }
  }
}

// ---------------- fc1 (MFMA bf16) + fused weight pre-pack ----------------
__global__ __launch_bounds__(256) void fc1_conv_kernel(
    const float* __restrict__ x, const float* __restrict__ w,
    const float* __restrict__ bias,
    const float* __restrict__ aw1, const float* __restrict__ aw2,
    const float* __restrict__ pw2, const float* __restrict__ qw,
    const float* __restrict__ f2w,
    unsigned short* __restrict__ wpak,
    float* __restrict__ out) {
  __shared__ unsigned short wf[8 * 512];   // fc1_w B-frags, 8 KB
  const int t = threadIdx.x;
  const int blk = blockIdx.x;              // 256 blocks
  {
    int id = blk * 256 + t;
    if (id < 16384) {
      int j = id & 7, lane = (id >> 3) & 63, rest = id >> 9;
      int mt = rest >> 1, hh = rest & 1;
      wpak[id] = f2bf(aw1[(32 * hh + 8 * (lane >> 4) + j) * 256 + mt * 16 + (lane & 15)]);
    } else if (id < 32768) {
      int i = id - 16384;
      int j = i & 7, lane = (i >> 3) & 63, rest = i >> 9;
      int ct = rest >> 3, f = rest & 7;
      wpak[id] = f2bf(aw2[(32 * f + 8 * (lane >> 4) + j) * 64 + ct * 16 + (lane & 15)]);
    } else if (id < 34816) {
      int i = id - 32768;
      int c = i >> 5, hh = i & 31;
      wpak[id] = f2bf(pw2[hh * 64 + c]);
    } else if (id < 47104) {
      int i = id - 34816;
      int j = i & 7, lane = (i >> 3) & 63, rest = i >> 9;
      int ct = rest >> 1, hh = rest & 1;
      wpak[id] = f2bf(qw[(32 * hh + 8 * (lane >> 4) + j) * 192 + ct * 16 + (lane & 15)]);
    } else if (id < 51200) {
      int i = id - 47104;
      int j = i & 7, lane = (i >> 3) & 63, rest = i >> 9;
      int ct = rest >> 1, hh = rest & 1;
      wpak[id] = f2bf(f2w[(32 * hh + 8 * (lane >> 4) + j) * 64 + ct * 16 + (lane & 15)]);
    }
  }
  for (int i = t; i < 4096; i += 256) {
    int j = i & 7, lane = (i >> 3) & 63, rest = i >> 9;
    int ct = rest >> 1, hh = rest & 1;
    wf[i] = f2bf(w[(32 * hh + 8 * (lane >> 4) + j) * 64 + ct * 16 + (lane & 15)]);
  }
  __syncthreads();
  const int lane = t & 63, wv = t >> 6;
  const int l = lane & 15, q = lane >> 4;
  const int r0 = blk * 64;
  const int row = r0 + wv * 16 + l;
  const f32x4 zero = {0.f, 0.f, 0.f, 0.f};
  float4 xa0 = *reinterpret_cast<const float4*>(&x[row * 64 + q * 8]);
  float4 xa1 = *reinterpret_cast<const float4*>(&x[row * 64 + q * 8 + 4]);
  float4 xb0 = *reinterpret_cast<const float4*>(&x[row * 64 + 32 + q * 8]);
  float4 xb1 = *reinterpret_cast<const float4*>(&x[row * 64 + 32 + q * 8 + 4]);
  short8 a0 = pack8f(xa0, xa1), a1 = pack8f(xb0, xb1);
  #pragma unroll
  for (int ct = 0; ct < 4; ++ct) {
    short8 b0 = *reinterpret_cast<const short8*>(&wf[(ct * 2 + 0) * 512 + lane * 8]);
    short8 b1 = *reinterpret_cast<const short8*>(&wf[(ct * 2 + 1) * 512 + lane * 8]);
    f32x4 acc = __builtin_amdgcn_mfma_f32_16x16x32_bf16(a0, b0, zero, 0, 0, 0);
    acc = __builtin_amdgcn_mfma_f32_16x16x32_bf16(a1, b1, acc, 0, 0, 0);
    const float bc = bias[ct * 16 + l];
    #pragma unroll
    for (int i = 0; i < 4; ++i)
      out[(r0 + wv * 16 + q * 4 + i) * 64 + ct * 16 + l] = acc[i] + bc;
  }
}

// ---------------- batchnorm stats ----------------
__global__ void stats_part_kernel(const float* __restrict__ src, float* __restrict__ part) {
  __shared__ float sb[256], sb2[256];
  const int t = threadIdx.x, blk = blockIdx.x;
  const int c = t & 63, rg = t >> 6;
  float s = 0.f, s2 = 0.f;
  for (int r = rg; r < 64; r += 4) {
    float v = src[(blk * 64 + r) * 64 + c];
    s += v; s2 += v * v;
  }
  sb[t] = s; sb2[t] = s2; __syncthreads();
  if (t < 64) {
    float ts  = sb[t] + sb[64 + t] + sb[128 + t] + sb[192 + t];
    float ts2 = sb2[t] + sb2[64 + t] + sb2[128 + t] + sb2[192 + t];
    part[blk * 128 + t] = ts;
    part[blk * 128 + 64 + t] = ts2;
  }
}

// emits affine form: A = g*rs, B = b - mu*g*rs  (bn(v) = A*v + B)
__global__ void stats_fin_kernel(const float* __restrict__ part,
                                 const float* __restrict__ g, const float* __restrict__ b,
                                 float* __restrict__ A, float* __restrict__ Bv) {
  const int c = threadIdx.x;  // 64
  double s = 0.0, s2 = 0.0;
  for (int i = 0; i < 256; ++i) { s += part[i * 128 + c]; s2 += part[i * 128 + 64 + c]; }
  double mean = s / (double)kRows;
  double var = s2 / (double)kRows - mean * mean;
  float rs = (float)(1.0 / sqrt(var + (double)kEps));
  float Af = g[c] * rs;
  A[c] = Af;
  Bv[c] = b[c] - (float)mean * Af;
}

// ---------------- qkv (MFMA) with fused bn1+relu; h fp32 + qkv BF16 out ----------------
__global__ __launch_bounds__(256) void qkv_bn_kernel(
    const float* __restrict__ hpre, const float* __restrict__ A1,
    const float* __restrict__ B1, const unsigned short* __restrict__ wqf,
    float* __restrict__ hout, unsigned short* __restrict__ out) {
  const int t = threadIdx.x, lane = t & 63, wv = t >> 6;
  const int l = lane & 15, q = lane >> 4;
  const int r0 = blockIdx.x * 64;
  const int row = r0 + wv * 16 + l;
  const f32x4 zero = {0.f, 0.f, 0.f, 0.f};
  short8 af[2];
  #pragma unroll
  for (int hh = 0; hh < 2; ++hh) {
    const int c0 = 32 * hh + q * 8;
    float4 v0 = *reinterpret_cast<const float4*>(&hpre[row * 64 + c0]);
    float4 v1 = *reinterpret_cast<const float4*>(&hpre[row * 64 + c0 + 4]);
    float4 Aa = *reinterpret_cast<const float4*>(&A1[c0]);
    float4 Ab = *reinterpret_cast<const float4*>(&A1[c0 + 4]);
    float4 Ba = *reinterpret_cast<const float4*>(&B1[c0]);
    float4 Bb = *reinterpret_cast<const float4*>(&B1[c0 + 4]);
    v0.x = fmaxf(Aa.x * v0.x + Ba.x, 0.f); v0.y = fmaxf(Aa.y * v0.y + Ba.y, 0.f);
    v0.z = fmaxf(Aa.z * v0.z + Ba.z, 0.f); v0.w = fmaxf(Aa.w * v0.w + Ba.w, 0.f);
    v1.x = fmaxf(Ab.x * v1.x + Bb.x, 0.f); v1.y = fmaxf(Ab.y * v1.y + Bb.y, 0.f);
    v1.z = fmaxf(Ab.z * v1.z + Bb.z, 0.f); v1.w = fmaxf(Ab.w * v1.w + Bb.w, 0.f);
    *reinterpret_cast<float4*>(&hout[row * 64 + c0]) = v0;
    *reinterpret_cast<float4*>(&hout[row * 64 + c0 + 4]) = v1;
    af[hh] = pack8f(v0, v1);
  }
  #pragma unroll
  for (int ct = 0; ct < 12; ++ct) {
    short8 b0 = *reinterpret_cast<const short8*>(&wqf[((ct * 2 + 0) * 64 + lane) * 8]);
    short8 b1 = *reinterpret_cast<const short8*>(&wqf[((ct * 2 + 1) * 64 + lane) * 8]);
    f32x4 acc = __builtin_amdgcn_mfma_f32_16x16x32_bf16(af[0], b0, zero, 0, 0, 0);
    acc = __builtin_amdgcn_mfma_f32_16x16x32_bf16(af[1], b1, acc, 0, 0, 0);
    #pragma unroll
    for (int i = 0; i < 4; ++i)
      out[(r0 + wv * 16 + q * 4 + i) * 192 + ct * 16 + l] = f2bf(acc[i]);
  }
}

// ---------------- kNN v2 (unchanged, R7-verified) ----------------
__global__ __launch_bounds__(256) void knn_kernel(
    const float* __restrict__ p, int* __restrict__ idxf) {
  __shared__ float4 pts[1024];
  __shared__ float bufv[4][kCap];
  __shared__ int   bufi[4][kCap];
  __shared__ int   cnt[4];
  const int t = threadIdx.x;
  const int lane = t & 63, w = t >> 6;
  const int blk = blockIdx.x;
  const int b = blk >> 10;
  const int q = blk * 4 + w;
  const float qx = p[q * 3], qy = p[q * 3 + 1], qz = p[q * 3 + 2];
  const float sqq = qx * qx + qy * qy + qz * qz;
  if (lane == 0) cnt[w] = 0;

  float sv = kFltMax;
  int   si = 0x7fffffff;

  #pragma unroll
  for (int i = 0; i < 4; ++i) {
    int j = t + i * 256;
    int g = b * kN + j;
    float px = p[g * 3], py = p[g * 3 + 1], pz = p[g * 3 + 2];
    pts[j] = make_float4(px, py, pz, px * px + py * py + pz * pz);
  }
  __syncthreads();
  float d2r[16];
  float lmin = kFltMax;
  #pragma unroll
  for (int i = 0; i < 16; ++i) {
    float4 pt = pts[i * 64 + lane];
    float d2 = sqq + pt.w - 2.0f * (qx * pt.x + qy * pt.y + qz * pt.z);
    d2r[i] = d2;
    lmin = fminf(lmin, d2);
  }
  {
    int dummy = lane;
    bitonic64(lmin, dummy, lane);
  }
  const float thrA = __shfl(lmin, 15) + 1e-3f;
  float thr = thrA;

  #pragma unroll
  for (int i = 0; i < 16; ++i) {
    if (d2r[i] <= thr) {
      int pos = atomicAdd(&cnt[w], 1);
      if (pos < kCap) { bufv[w][pos] = d2r[i]; bufi[w][pos] = i * 64 + lane; }
    }
  }
  {
    int n = cnt[w];
    if (n > 0) {
      if (n > kCap) {
        for (int g0 = 0; g0 < 1024; g0 += 48) {
          float mv; int mi;
          if (lane < 16) { mv = sv; mi = si; }
          else {
            int jj = g0 + (lane - 16);
            if (jj < 1024) {
              float4 pt = pts[jj];
              mv = sqq + pt.w - 2.0f * (qx * pt.x + qy * pt.y + qz * pt.z);
              mi = jj;
            } else { mv = kFltMax; mi = 0x7fffffff; }
          }
          bitonic64(mv, mi, lane);
          sv = mv; si = mi;
        }
      } else {
        for (int g0 = 0; g0 < n; g0 += 48) {
          float mv; int mi;
          if (lane < 16) { mv = sv; mi = si; }
          else {
            int pos = g0 + (lane - 16);
            if (pos < n) { mv = bufv[w][pos]; mi = bufi[w][pos]; }
            else { mv = kFltMax; mi = 0x7fffffff; }
          }
          bitonic64(mv, mi, lane);
          sv = mv; si = mi;
        }
      }
      if (lane == 0) cnt[w] = 0;
      thr = fminf(thrA, __shfl(sv, 15));
    }
  }

  for (int c0 = 1024; c0 < kN; c0 += 1024) {
    __syncthreads();
    #pragma unroll
    for (int i = 0; i < 4; ++i) {
      int j = t + i * 256;
      int g = b * kN + c0 + j;
      float px = p[g * 3], py = p[g * 3 + 1], pz = p[g * 3 + 2];
      pts[j] = make_float4(px, py, pz, px * px + py * py + pz * pz);
    }
    __syncthreads();
    #pragma unroll
    for (int i = 0; i < 16; ++i) {
      float4 pt = pts[i * 64 + lane];
      float d2 = sqq + pt.w - 2.0f * (qx * pt.x + qy * pt.y + qz * pt.z);
      if (d2 <= thr) {
        int pos = atomicAdd(&cnt[w], 1);
        if (pos < kCap) { bufv[w][pos] = d2; bufi[w][pos] = c0 + i * 64 + lane; }
      }
    }
    int n = cnt[w];
    if (n > 0) {
      if (n > kCap) {
        for (int g0 = 0; g0 < 1024; g0 += 48) {
          float mv; int mi;
          if (lane < 16) { mv = sv; mi = si; }
          else {
            int jj = g0 + (lane - 16);
            if (jj < 1024) {
              float4 pt = pts[jj];
              mv = sqq + pt.w - 2.0f * (qx * pt.x + qy * pt.y + qz * pt.z);
              mi = c0 + jj;
            } else { mv = kFltMax; mi = 0x7fffffff; }
          }
          bitonic64(mv, mi, lane);
          sv = mv; si = mi;
        }
      } else {
        for (int g0 = 0; g0 < n; g0 += 48) {
          float mv; int mi;
          if (lane < 16) { mv = sv; mi = si; }
          else {
            int pos = g0 + (lane - 16);
            if (pos < n) { mv = bufv[w][pos]; mi = bufi[w][pos]; }
            else { mv = kFltMax; mi = 0x7fffffff; }
          }
          bitonic64(mv, mi, lane);
          sv = mv; si = mi;
        }
      }
      if (lane == 0) cnt[w] = 0;
      thr = fminf(thrA, __shfl(sv, 15));
    }
  }
  if (lane < 16) {
    int out = si;
    if ((unsigned)out >= (unsigned)kN) out = 0;
    idxf[q * 16 + lane] = out;
  }
}

// ---------------- fused MFMA attention v3: bf16 qkv + XCD swizzle ----------------
// One wave per point, zero barriers. XCD swizzle: blocks with equal blk%8
// (same XCD under round-robin dispatch) take a contiguous work range within
// one batch -> per-XCD L2 working set ~1.3 MB (fits 4 MB). pe-hidden stays in
// registers (lane (l,q) produces exactly its own MFMA B-fragment).
__global__ __launch_bounds__(256) void attn_mfma3_kernel(
    const float* __restrict__ p, const unsigned short* __restrict__ qkv,
    const int* __restrict__ idxf,
    const float* __restrict__ pos_w1, const float* __restrict__ pos_b1,
    const float* __restrict__ pos_b2,
    const float* __restrict__ attn_b1, const float* __restrict__ attn_b2,
    const unsigned short* __restrict__ w1f,
    const unsigned short* __restrict__ w2f,
    const unsigned short* __restrict__ pw2t,
    float* __restrict__ agg) {
  __shared__ unsigned short Ulds[64 * 72];   // [row][c] bf16
  __shared__ float VVlds[64 * 65];           // [c][row] fp32 transposed

  const int t = threadIdx.x;
  const int lane = t & 63, w = t >> 6;
  const int l = lane & 15, q = lane >> 4;
  const int work = ((blockIdx.x & 7) << 9) | (blockIdx.x >> 3);  // XCD swizzle
  const int b = work >> 10;
  const int n0 = (work & 1023) * 4;
  const int pt_row = b * kN + n0 + w;
  const f32x4 zero = {0.f, 0.f, 0.f, 0.f};

  int idxv = 0;
  if (lane < 16) idxv = idxf[(work * 4 + w) * 16 + lane];

  // phase 1a: gather k/v (bf16); U = bf16(q - k); VV^T[c][row] = v
  {
    const int r = lane >> 2, seg = lane & 3;
    const unsigned short* jrow = qkv + (b * kN + __shfl(idxv, r)) * 192;
    const int c0 = seg * 16;
    uint4 k0 = *reinterpret_cast<const uint4*>(jrow + 64 + c0);
    uint4 k1 = *reinterpret_cast<const uint4*>(jrow + 64 + c0 + 8);
    uint4 v0 = *reinterpret_cast<const uint4*>(jrow + 128 + c0);
    uint4 v1 = *reinterpret_cast<const uint4*>(jrow + 128 + c0 + 8);
    uint4 q0 = *reinterpret_cast<const uint4*>(qkv + pt_row * 192 + c0);
    uint4 q1 = *reinterpret_cast<const uint4*>(qkv + pt_row * 192 + c0 + 8);
    auto diff2 = [](unsigned int qu, unsigned int ku) -> unsigned int {
      float a = bf2f(qu & 0xffffu) - bf2f(ku & 0xffffu);
      float c = bf2f(qu >> 16) - bf2f(ku >> 16);
      return (unsigned int)f2bf(a) | ((unsigned int)f2bf(c) << 16);
    };
    uint4 u0, u1;
    u0.x = diff2(q0.x, k0.x); u0.y = diff2(q0.y, k0.y);
    u0.z = diff2(q0.z, k0.z); u0.w = diff2(q0.w, k0.w);
    u1.x = diff2(q1.x, k1.x); u1.y = diff2(q1.y, k1.y);
    u1.z = diff2(q1.z, k1.z); u1.w = diff2(q1.w, k1.w);
    *reinterpret_cast<uint4*>(&Ulds[(w * 16 + r) * 72 + c0]) = u0;
    *reinterpret_cast<uint4*>(&Ulds[(w * 16 + r) * 72 + c0 + 8]) = u1;
    const unsigned int vs[8] = {v0.x, v0.y, v0.z, v0.w, v1.x, v1.y, v1.z, v1.w};
    #pragma unroll
    for (int i = 0; i < 8; ++i) {
      VVlds[(c0 + 2 * i + 0) * 65 + w * 16 + r] = bf2f(vs[i] & 0xffffu);
      VVlds[(c0 + 2 * i + 1) * 65 + w * 16 + r] = bf2f(vs[i] >> 16);
    }
  }
  // phase 1b: pe hidden (3->32) for row l, chunk q*8 — stays in registers
  short8 pbf;
  {
    const float* pn = p + pt_row * 3;
    const int nj = __shfl(idxv, l);
    const float* pj = p + (b * kN + nj) * 3;
    float rx = pn[0] - pj[0], ry = pn[1] - pj[1], rz = pn[2] - pj[2];
    unsigned short tmp[8];
    #pragma unroll
    for (int j = 0; j < 8; ++j) {
      int hh = q * 8 + j;
      float v = pos_b1[hh] + rx * pos_w1[hh] + ry * pos_w1[32 + hh] + rz * pos_w1[64 + hh];
      tmp[j] = f2bf(fmaxf(v, 0.0f));
    }
    union { unsigned int u[4]; short8 s; } pk;
    #pragma unroll
    for (int ii = 0; ii < 4; ++ii)
      pk.u[ii] = (unsigned int)tmp[2 * ii] | ((unsigned int)tmp[2 * ii + 1] << 16);
    pbf = pk.s;
  }

  // phase 2: pe = pehid @ pos_w2 (transposed MFMA, D[c][row]); RMW U and VV
  {
    const int urow = (w * 16 + l) * 72;
    #pragma unroll
    for (int mt = 0; mt < 4; ++mt) {
      short8 paf = *reinterpret_cast<const short8*>(&pw2t[(mt * 16 + l) * 32 + q * 8]);
      f32x4 pe = __builtin_amdgcn_mfma_f32_16x16x32_bf16(paf, pbf, zero, 0, 0, 0);
      const int c0 = mt * 16 + q * 4;
      float4 b2v = *reinterpret_cast<const float4*>(&pos_b2[c0]);
      float pe0 = pe[0] + b2v.x, pe1 = pe[1] + b2v.y;
      float pe2 = pe[2] + b2v.z, pe3 = pe[3] + b2v.w;
      uint2 u2 = *reinterpret_cast<uint2*>(&Ulds[urow + c0]);
      uint2 o;
      o.x = (unsigned int)f2bf(bf2f(u2.x & 0xffffu) + pe0) |
            ((unsigned int)f2bf(bf2f(u2.x >> 16) + pe1) << 16);
      o.y = (unsigned int)f2bf(bf2f(u2.y & 0xffffu) + pe2) |
            ((unsigned int)f2bf(bf2f(u2.y >> 16) + pe3) << 16);
      *reinterpret_cast<uint2*>(&Ulds[urow + c0]) = o;
      VVlds[(c0 + 0) * 65 + w * 16 + l] += pe0;
      VVlds[(c0 + 1) * 65 + w * 16 + l] += pe1;
      VVlds[(c0 + 2) * 65 + w * 16 + l] += pe2;
      VVlds[(c0 + 3) * 65 + w * 16 + l] += pe3;
    }
  }

  // phase 3: GEMM1 transposed: hr[mt] = H[row w*16+l][mt*16+q*4+i]
  f32x4 hr[16];
  {
    const int urow = (w * 16 + l) * 72;
    short8 ub0 = *reinterpret_cast<const short8*>(&Ulds[urow + q * 8]);
    short8 ub1 = *reinterpret_cast<const short8*>(&Ulds[urow + 32 + q * 8]);
    #pragma unroll
    for (int mt = 0; mt < 16; ++mt) {
      short8 a0 = *reinterpret_cast<const short8*>(&w1f[(mt * 2 + 0) * 512 + lane * 8]);
      short8 a1 = *reinterpret_cast<const short8*>(&w1f[(mt * 2 + 1) * 512 + lane * 8]);
      f32x4 acc = __builtin_amdgcn_mfma_f32_16x16x32_bf16(a0, ub0, zero, 0, 0, 0);
      acc = __builtin_amdgcn_mfma_f32_16x16x32_bf16(a1, ub1, acc, 0, 0, 0);
      float4 bb = *reinterpret_cast<const float4*>(&attn_b1[mt * 16 + q * 4]);
      hr[mt][0] = fmaxf(acc[0] + bb.x, 0.f);
      hr[mt][1] = fmaxf(acc[1] + bb.y, 0.f);
      hr[mt][2] = fmaxf(acc[2] + bb.z, 0.f);
      hr[mt][3] = fmaxf(acc[3] + bb.w, 0.f);
    }
  }

  // phase 4: GEMM2 via in-register repack; softmax; weighted sum of VV
  {
    f32x4 acc2[4];
    #pragma unroll
    for (int ct = 0; ct < 4; ++ct) acc2[ct] = zero;
    const int s0 = (2 * (q & 1)) * 16 + l;
    const int s1 = (1 + 2 * (q & 1)) * 16 + l;
    const bool hiq = (q >= 2);
    #pragma unroll
    for (int f = 0; f < 8; ++f) {
      unsigned short fr[8];
      #pragma unroll
      for (int j = 0; j < 8; ++j) {
        const int src = (j < 4) ? s0 : s1;
        float va = __shfl(hr[2 * f + 0][j & 3], src);
        float vb = __shfl(hr[2 * f + 1][j & 3], src);
        fr[j] = f2bf(hiq ? vb : va);
      }
      union { unsigned int u[4]; short8 s; } pk;
      #pragma unroll
      for (int ii = 0; ii < 4; ++ii)
        pk.u[ii] = (unsigned int)fr[2 * ii] | ((unsigned int)fr[2 * ii + 1] << 16);
      short8 afr = pk.s;
      #pragma unroll
      for (int ct = 0; ct < 4; ++ct) {
        short8 bfr = *reinterpret_cast<const short8*>(&w2f[((ct * 8 + f) * 64 + lane) * 8]);
        acc2[ct] = __builtin_amdgcn_mfma_f32_16x16x32_bf16(afr, bfr, acc2[ct], 0, 0, 0);
      }
    }
    #pragma unroll
    for (int ct = 0; ct < 4; ++ct) {
      const int ch = ct * 16 + l;
      const float bv = attn_b2[ch];
      float s0v = acc2[ct][0] + bv, s1v = acc2[ct][1] + bv;
      float s2v = acc2[ct][2] + bv, s3v = acc2[ct][3] + bv;
      float mx = fmaxf(fmaxf(s0v, s1v), fmaxf(s2v, s3v));
      mx = fmaxf(mx, __shfl_xor(mx, 16, 64));
      mx = fmaxf(mx, __shfl_xor(mx, 32, 64));
      float e0 = __expf(s0v - mx), e1 = __expf(s1v - mx);
      float e2 = __expf(s2v - mx), e3 = __expf(s3v - mx);
      float se = e0 + e1 + e2 + e3;
      se += __shfl_xor(se, 16, 64);
      se += __shfl_xor(se, 32, 64);
      const int vbase = ch * 65 + w * 16 + q * 4;
      float a = e0 * VVlds[vbase + 0] + e1 * VVlds[vbase + 1] +
                e2 * VVlds[vbase + 2] + e3 * VVlds[vbase + 3];
      a += __shfl_xor(a, 16, 64);
      a += __shfl_xor(a, 32, 64);
      if (q == 0) agg[(work * 4 + w) * 64 + ch] = a / se;
    }
  }
}

// ---------------- fc2 (MFMA) with fused bn2+relu+residual prologue ----------------
__global__ __launch_bounds__(256) void fc2_mfma_kernel(
    const float* __restrict__ aggp, const float* __restrict__ hres,
    const float* __restrict__ A2, const float* __restrict__ B2,
    const unsigned short* __restrict__ fc2f, const float* __restrict__ bias,
    float* __restrict__ z) {
  const int t = threadIdx.x, lane = t & 63, wv = t >> 6;
  const int l = lane & 15, q = lane >> 4;
  const int r0 = blockIdx.x * 64;
  const int row = r0 + wv * 16 + l;
  const f32x4 zero = {0.f, 0.f, 0.f, 0.f};
  short8 af[2];
  #pragma unroll
  for (int hh = 0; hh < 2; ++hh) {
    const int c0 = 32 * hh + q * 8;
    float4 v0 = *reinterpret_cast<const float4*>(&aggp[row * 64 + c0]);
    float4 v1 = *reinterpret_cast<const float4*>(&aggp[row * 64 + c0 + 4]);
    float4 r0v = *reinterpret_cast<const float4*>(&hres[row * 64 + c0]);
    float4 r1v = *reinterpret_cast<const float4*>(&hres[row * 64 + c0 + 4]);
    float4 Aa = *reinterpret_cast<const float4*>(&A2[c0]);
    float4 Ab = *reinterpret_cast<const float4*>(&A2[c0 + 4]);
    float4 Ba = *reinterpret_cast<const float4*>(&B2[c0]);
    float4 Bb = *reinterpret_cast<const float4*>(&B2[c0 + 4]);
    v0.x = fmaxf(Aa.x * v0.x + Ba.x, 0.f) + r0v.x;
    v0.y = fmaxf(Aa.y * v0.y + Ba.y, 0.f) + r0v.y;
    v0.z = fmaxf(Aa.z * v0.z + Ba.z, 0.f) + r0v.z;
    v0.w = fmaxf(Aa.w * v0.w + Ba.w, 0.f) + r0v.w;
    v1.x = fmaxf(Ab.x * v1.x + Bb.x, 0.f) + r1v.x;
    v1.y = fmaxf(Ab.y * v1.y + Bb.y, 0.f) + r1v.y;
    v1.z = fmaxf(Ab.z * v1.z + Bb.z, 0.f) + r1v.z;
    v1.w = fmaxf(Ab.w * v1.w + Bb.w, 0.f) + r1v.w;
    af[hh] = pack8f(v0, v1);
  }
  #pragma unroll
  for (int ct = 0; ct < 4; ++ct) {
    short8 b0 = *reinterpret_cast<const short8*>(&fc2f[((ct * 2 + 0) * 64 + lane) * 8]);
    short8 b1 = *reinterpret_cast<const short8*>(&fc2f[((ct * 2 + 1) * 64 + lane) * 8]);
    f32x4 acc = __builtin_amdgcn_mfma_f32_16x16x32_bf16(af[0], b0, zero, 0, 0, 0);
    acc = __builtin_amdgcn_mfma_f32_16x16x32_bf16(af[1], b1, acc, 0, 0, 0);
    const float bc = bias[ct * 16 + l];
    #pragma unroll
    for (int i = 0; i < 4; ++i)
      z[(r0 + wv * 16 + q * 4 + i) * 64 + ct * 16 + l] = acc[i] + bc;
  }
}

// ---------------- final bn3+relu, fused p-copy ----------------
__global__ void final_kernel(const float* __restrict__ z, const float* __restrict__ A3,
                             const float* __restrict__ B3, const float* __restrict__ p,
                             float* __restrict__ y) {
  const int blk = blockIdx.x, t = threadIdx.x;
  if (blk < 4096) {
    int i = blk * 256 + t;
    int c = i & 63;
    y[i] = fmaxf(A3[c] * z[i] + B3[c], 0.0f);
  } else {
    int i = (blk - 4096) * 256 + t;
    y[1048576 + i] = p[i];
  }
}

extern "C" void kernel_launch(void* const* d_in, const int* in_sizes, int n_in,
                              void* d_out, int out_size, void* d_ws, size_t ws_size,
                              hipStream_t stream) {
  const float* x       = (const float*)d_in[0];
  const float* p       = (const float*)d_in[1];
  const float* fc1_w   = (const float*)d_in[2];
  const float* fc1_b   = (const float*)d_in[3];
  const float* bn1_g   = (const float*)d_in[4];
  const float* bn1_b   = (const float*)d_in[5];
  const float* qkv_w   = (const float*)d_in[6];
  const float* pos_w1  = (const float*)d_in[7];
  const float* pos_b1  = (const float*)d_in[8];
  const float* pos_w2  = (const float*)d_in[9];
  const float* pos_b2  = (const float*)d_in[10];
  const float* attn_w1 = (const float*)d_in[11];
  const float* attn_b1 = (const float*)d_in[12];
  const float* attn_w2 = (const float*)d_in[13];
  const float* attn_b2 = (const float*)d_in[14];
  const float* bn2_g   = (const float*)d_in[15];
  const float* bn2_b   = (const float*)d_in[16];
  const float* fc2_w   = (const float*)d_in[17];
  const float* fc2_b   = (const float*)d_in[18];
  const float* bn3_g   = (const float*)d_in[19];
  const float* bn3_b   = (const float*)d_in[20];

  float* ws   = (float*)d_ws;
  float* h    = ws;                     // residual, fp32
  unsigned short* qkvb = (unsigned short*)(ws + 1048576);  // bf16 [16384][192]
  float* hpre = ws + 4194304;
  float* aggv = ws + 5242880;           // also stats partials 1,3
  float* z    = ws + 6291456;           // also stats partials 2
  float* st   = ws + 7340032;           // A1,B1,A2,B2,A3,B3
  int*   idxf = (int*)(ws + 7356800);
  unsigned short* wpak = (unsigned short*)(ws + 7618944);
  unsigned short* w1f  = wpak;
  unsigned short* w2f  = wpak + 16384;
  unsigned short* pw2t = wpak + 32768;
  unsigned short* wqf  = wpak + 34816;
  unsigned short* fc2f = wpak + 47104;

  float* A1 = st,       *B1 = st + 64;
  float* A2 = st + 128, *B2 = st + 192;
  float* A3 = st + 256, *B3 = st + 320;
  float* y = (float*)d_out;

  fc1_conv_kernel<<<256, 256, 0, stream>>>(x, fc1_w, fc1_b, attn_w1, attn_w2,
                                           pos_w2, qkv_w, fc2_w, wpak, hpre);
  stats_part_kernel<<<256, 256, 0, stream>>>(hpre, aggv);
  stats_fin_kernel<<<1, 64, 0, stream>>>(aggv, bn1_g, bn1_b, A1, B1);
  qkv_bn_kernel<<<256, 256, 0, stream>>>(hpre, A1, B1, wqf, h, qkvb);
  knn_kernel<<<4096, 256, 0, stream>>>(p, idxf);
  attn_mfma3_kernel<<<4096, 256, 0, stream>>>(p, qkvb, idxf, pos_w1, pos_b1, pos_b2,
                                              attn_b1, attn_b2, w1f, w2f, pw2t, aggv);
  stats_part_kernel<<<256, 256, 0, stream>>>(aggv, z);
  stats_fin_kernel<<<1, 64, 0, stream>>>(z, bn2_g, bn2_b, A2, B2);
  fc2_mfma_kernel<<<256, 256, 0, stream>>>(aggv, h, A2, B2, fc2f, fc2_b, z);
  stats_part_kernel<<<256, 256, 0, stream>>>(z, aggv);
  stats_fin_kernel<<<1, 64, 0, stream>>>(aggv, bn3_g, bn3_b, A3, B3);
  final_kernel<<<4288, 256, 0, stream>>>(z, A3, B3, p, y);
}

// Round 9
// 300.880 us; speedup vs baseline: 4.0234x; 1.0530x over previous
//
#include <hip/hip_runtime.h>
#include <math.h>

constexpr int kB = 4, kN = 4096, kK = 16;
constexpr int kRows = kB * kN;          // 16384
constexpr float kEps = 1e-5f;
constexpr float kFltMax = 3.402823466e38f;
constexpr int kCap = 240;               // per-wave qualifier buffer (knn)

typedef __attribute__((ext_vector_type(8))) short short8;
typedef __attribute__((ext_vector_type(4))) float f32x4;

// bf16 round-half-up (2 ops vs 4 for RNE; <=1 ulp difference, well inside margin)
__device__ __forceinline__ unsigned short f2bf(float x) {
  return (unsigned short)((__float_as_uint(x) + 0x8000u) >> 16);
}
// pack two floats -> bf16x2 dword (5 ops)
__device__ __forceinline__ unsigned int pkbf(float lo, float hi) {
  return ((__float_as_uint(lo) + 0x8000u) >> 16) |
         ((__float_as_uint(hi) + 0x8000u) & 0xffff0000u);
}
__device__ __forceinline__ short8 pack8f(float4 a, float4 b) {
  union { unsigned int u[4]; short8 s; } pk;
  pk.u[0] = pkbf(a.x, a.y);
  pk.u[1] = pkbf(a.z, a.w);
  pk.u[2] = pkbf(b.x, b.y);
  pk.u[3] = pkbf(b.z, b.w);
  return pk.s;
}

// Full 64-lane bitonic sort, ascending by (v, i) lexicographic.
__device__ __forceinline__ void bitonic64(float& sv, int& si, int lane) {
  #pragma unroll
  for (int k = 2; k <= 64; k <<= 1) {
    #pragma unroll
    for (int j = k >> 1; j > 0; j >>= 1) {
      float ov = __shfl_xor(sv, j);
      int   oi = __shfl_xor(si, j);
      bool up = ((lane & k) == 0);
      bool lower = ((lane & j) == 0);
      bool osm = (ov < sv) || (ov == sv && oi < si);
      bool take = (lower == up) ? osm : !osm;
      if (take) { sv = ov; si = oi; }
    }
  }
}

// ---------------- fc1 (MFMA bf16) + fused weight pre-pack ----------------
__global__ __launch_bounds__(256) void fc1_conv_kernel(
    const float* __restrict__ x, const float* __restrict__ w,
    const float* __restrict__ bias,
    const float* __restrict__ aw1, const float* __restrict__ aw2,
    const float* __restrict__ pw2, const float* __restrict__ qw,
    const float* __restrict__ f2w,
    unsigned short* __restrict__ wpak,
    float* __restrict__ out) {
  __shared__ unsigned short wf[8 * 512];   // fc1_w B-frags, 8 KB
  const int t = threadIdx.x;
  const int blk = blockIdx.x;              // 256 blocks
  {
    int id = blk * 256 + t;
    if (id < 16384) {
      int j = id & 7, lane = (id >> 3) & 63, rest = id >> 9;
      int mt = rest >> 1, hh = rest & 1;
      wpak[id] = f2bf(aw1[(32 * hh + 8 * (lane >> 4) + j) * 256 + mt * 16 + (lane & 15)]);
    } else if (id < 32768) {
      int i = id - 16384;
      int j = i & 7, lane = (i >> 3) & 63, rest = i >> 9;
      int ct = rest >> 3, f = rest & 7;
      wpak[id] = f2bf(aw2[(32 * f + 8 * (lane >> 4) + j) * 64 + ct * 16 + (lane & 15)]);
    } else if (id < 34816) {
      int i = id - 32768;
      int c = i >> 5, hh = i & 31;
      wpak[id] = f2bf(pw2[hh * 64 + c]);
    } else if (id < 47104) {
      int i = id - 34816;
      int j = i & 7, lane = (i >> 3) & 63, rest = i >> 9;
      int ct = rest >> 1, hh = rest & 1;
      wpak[id] = f2bf(qw[(32 * hh + 8 * (lane >> 4) + j) * 192 + ct * 16 + (lane & 15)]);
    } else if (id < 51200) {
      int i = id - 47104;
      int j = i & 7, lane = (i >> 3) & 63, rest = i >> 9;
      int ct = rest >> 1, hh = rest & 1;
      wpak[id] = f2bf(f2w[(32 * hh + 8 * (lane >> 4) + j) * 64 + ct * 16 + (lane & 15)]);
    }
  }
  for (int i = t; i < 4096; i += 256) {
    int j = i & 7, lane = (i >> 3) & 63, rest = i >> 9;
    int ct = rest >> 1, hh = rest & 1;
    wf[i] = f2bf(w[(32 * hh + 8 * (lane >> 4) + j) * 64 + ct * 16 + (lane & 15)]);
  }
  __syncthreads();
  const int lane = t & 63, wv = t >> 6;
  const int l = lane & 15, q = lane >> 4;
  const int r0 = blk * 64;
  const int row = r0 + wv * 16 + l;
  const f32x4 zero = {0.f, 0.f, 0.f, 0.f};
  float4 xa0 = *reinterpret_cast<const float4*>(&x[row * 64 + q * 8]);
  float4 xa1 = *reinterpret_cast<const float4*>(&x[row * 64 + q * 8 + 4]);
  float4 xb0 = *reinterpret_cast<const float4*>(&x[row * 64 + 32 + q * 8]);
  float4 xb1 = *reinterpret_cast<const float4*>(&x[row * 64 + 32 + q * 8 + 4]);
  short8 a0 = pack8f(xa0, xa1), a1 = pack8f(xb0, xb1);
  #pragma unroll
  for (int ct = 0; ct < 4; ++ct) {
    short8 b0 = *reinterpret_cast<const short8*>(&wf[(ct * 2 + 0) * 512 + lane * 8]);
    short8 b1 = *reinterpret_cast<const short8*>(&wf[(ct * 2 + 1) * 512 + lane * 8]);
    f32x4 acc = __builtin_amdgcn_mfma_f32_16x16x32_bf16(a0, b0, zero, 0, 0, 0);
    acc = __builtin_amdgcn_mfma_f32_16x16x32_bf16(a1, b1, acc, 0, 0, 0);
    const float bc = bias[ct * 16 + l];
    #pragma unroll
    for (int i = 0; i < 4; ++i)
      out[(r0 + wv * 16 + q * 4 + i) * 64 + ct * 16 + l] = acc[i] + bc;
  }
}

// ---------------- batchnorm stats ----------------
__global__ void stats_part_kernel(const float* __restrict__ src, float* __restrict__ part) {
  __shared__ float sb[256], sb2[256];
  const int t = threadIdx.x, blk = blockIdx.x;
  const int c = t & 63, rg = t >> 6;
  float s = 0.f, s2 = 0.f;
  for (int r = rg; r < 64; r += 4) {
    float v = src[(blk * 64 + r) * 64 + c];
    s += v; s2 += v * v;
  }
  sb[t] = s; sb2[t] = s2; __syncthreads();
  if (t < 64) {
    float ts  = sb[t] + sb[64 + t] + sb[128 + t] + sb[192 + t];
    float ts2 = sb2[t] + sb2[64 + t] + sb2[128 + t] + sb2[192 + t];
    part[blk * 128 + t] = ts;
    part[blk * 128 + 64 + t] = ts2;
  }
}

// emits affine form: A = g*rs, B = b - mu*g*rs  (bn(v) = A*v + B)
__global__ void stats_fin_kernel(const float* __restrict__ part,
                                 const float* __restrict__ g, const float* __restrict__ b,
                                 float* __restrict__ A, float* __restrict__ Bv) {
  const int c = threadIdx.x;  // 64
  double s = 0.0, s2 = 0.0;
  for (int i = 0; i < 256; ++i) { s += part[i * 128 + c]; s2 += part[i * 128 + 64 + c]; }
  double mean = s / (double)kRows;
  double var = s2 / (double)kRows - mean * mean;
  float rs = (float)(1.0 / sqrt(var + (double)kEps));
  float Af = g[c] * rs;
  A[c] = Af;
  Bv[c] = b[c] - (float)mean * Af;
}

// ---------------- qkv (MFMA) with fused bn1+relu; h fp32 + qkv BF16 out ----------------
__global__ __launch_bounds__(256) void qkv_bn_kernel(
    const float* __restrict__ hpre, const float* __restrict__ A1,
    const float* __restrict__ B1, const unsigned short* __restrict__ wqf,
    float* __restrict__ hout, unsigned short* __restrict__ out) {
  const int t = threadIdx.x, lane = t & 63, wv = t >> 6;
  const int l = lane & 15, q = lane >> 4;
  const int r0 = blockIdx.x * 64;
  const int row = r0 + wv * 16 + l;
  const f32x4 zero = {0.f, 0.f, 0.f, 0.f};
  short8 af[2];
  #pragma unroll
  for (int hh = 0; hh < 2; ++hh) {
    const int c0 = 32 * hh + q * 8;
    float4 v0 = *reinterpret_cast<const float4*>(&hpre[row * 64 + c0]);
    float4 v1 = *reinterpret_cast<const float4*>(&hpre[row * 64 + c0 + 4]);
    float4 Aa = *reinterpret_cast<const float4*>(&A1[c0]);
    float4 Ab = *reinterpret_cast<const float4*>(&A1[c0 + 4]);
    float4 Ba = *reinterpret_cast<const float4*>(&B1[c0]);
    float4 Bb = *reinterpret_cast<const float4*>(&B1[c0 + 4]);
    v0.x = fmaxf(Aa.x * v0.x + Ba.x, 0.f); v0.y = fmaxf(Aa.y * v0.y + Ba.y, 0.f);
    v0.z = fmaxf(Aa.z * v0.z + Ba.z, 0.f); v0.w = fmaxf(Aa.w * v0.w + Ba.w, 0.f);
    v1.x = fmaxf(Ab.x * v1.x + Bb.x, 0.f); v1.y = fmaxf(Ab.y * v1.y + Bb.y, 0.f);
    v1.z = fmaxf(Ab.z * v1.z + Bb.z, 0.f); v1.w = fmaxf(Ab.w * v1.w + Bb.w, 0.f);
    *reinterpret_cast<float4*>(&hout[row * 64 + c0]) = v0;
    *reinterpret_cast<float4*>(&hout[row * 64 + c0 + 4]) = v1;
    af[hh] = pack8f(v0, v1);
  }
  #pragma unroll
  for (int ct = 0; ct < 12; ++ct) {
    short8 b0 = *reinterpret_cast<const short8*>(&wqf[((ct * 2 + 0) * 64 + lane) * 8]);
    short8 b1 = *reinterpret_cast<const short8*>(&wqf[((ct * 2 + 1) * 64 + lane) * 8]);
    f32x4 acc = __builtin_amdgcn_mfma_f32_16x16x32_bf16(af[0], b0, zero, 0, 0, 0);
    acc = __builtin_amdgcn_mfma_f32_16x16x32_bf16(af[1], b1, acc, 0, 0, 0);
    #pragma unroll
    for (int i = 0; i < 4; ++i)
      out[(r0 + wv * 16 + q * 4 + i) * 192 + ct * 16 + l] = f2bf(acc[i]);
  }
}

// ---------------- kNN v3: barrier-free, register/global-direct ----------------
// No LDS point staging: lanes read p directly (dwordx3, L1/L2-resident per batch).
// Chunk-0 d2 kept in registers -> tau is SAME-SITE exact for its defining
// candidates; margin covers the i>=16 recompute site. All merges deferred to
// one end phase (E[qualifiers] ~ 64 -> 2 bitonics). Overflow (impossible on
// real data) falls back to a full direct-scan merge with a fresh list.
__global__ __launch_bounds__(256) void knn_kernel(
    const float* __restrict__ p, int* __restrict__ idxf) {
  __shared__ float bufv[4][kCap];
  __shared__ int   bufi[4][kCap];
  __shared__ int   cnt[4];
  const int t = threadIdx.x;
  const int lane = t & 63, w = t >> 6;
  const int blk = blockIdx.x;
  const int b = blk >> 10;
  const int q = blk * 4 + w;
  const float3 qp = *reinterpret_cast<const float3*>(p + 3 * q);
  const float qx = qp.x, qy = qp.y, qz = qp.z;
  const float sqq = qx * qx + qy * qy + qz * qz;
  if (lane == 0) cnt[w] = 0;
  const int base = b * kN;

  // pass A: first 1024 candidates, d2 in registers
  float d2r[16];
  float lmin = kFltMax;
  #pragma unroll
  for (int i = 0; i < 16; ++i) {
    float3 c = *reinterpret_cast<const float3*>(p + 3 * (base + i * 64 + lane));
    float d2 = sqq + (c.x * c.x + c.y * c.y + c.z * c.z)
             - 2.0f * (qx * c.x + qy * c.y + qz * c.z);
    d2r[i] = d2;
    lmin = fminf(lmin, d2);
  }
  { int dummy = lane; bitonic64(lmin, dummy, lane); }
  const float thrA = __shfl(lmin, 15) + 1e-3f;  // margin: cross-site FMA wobble

  // append qualifiers (chunk 0 from registers, rest direct)
  #pragma unroll
  for (int i = 0; i < 16; ++i) {
    if (d2r[i] <= thrA) {
      int pos = atomicAdd(&cnt[w], 1);
      if (pos < kCap) { bufv[w][pos] = d2r[i]; bufi[w][pos] = i * 64 + lane; }
    }
  }
  for (int i = 16; i < 64; ++i) {
    float3 c = *reinterpret_cast<const float3*>(p + 3 * (base + i * 64 + lane));
    float d2 = sqq + (c.x * c.x + c.y * c.y + c.z * c.z)
             - 2.0f * (qx * c.x + qy * c.y + qz * c.z);
    if (d2 <= thrA) {
      int pos = atomicAdd(&cnt[w], 1);
      if (pos < kCap) { bufv[w][pos] = d2; bufi[w][pos] = i * 64 + lane; }
    }
  }

  const int n = cnt[w];   // same-wave LDS ops are ordered
  float sv = kFltMax;
  int   si = 0x7fffffff;
  if (n <= kCap) {
    for (int g0 = 0; g0 < n; g0 += 48) {
      float mv; int mi;
      if (lane < 16) { mv = sv; mi = si; }
      else {
        int pos = g0 + (lane - 16);
        if (pos < n) { mv = bufv[w][pos]; mi = bufi[w][pos]; }
        else { mv = kFltMax; mi = 0x7fffffff; }
      }
      bitonic64(mv, mi, lane);
      sv = mv; si = mi;
    }
  } else {
    // degenerate-data slow path: full direct rescan, fresh list (no dupes)
    for (int g0 = 0; g0 < kN; g0 += 48) {
      float mv; int mi;
      if (lane < 16) { mv = sv; mi = si; }
      else {
        int j = g0 + (lane - 16);
        if (j < kN) {
          float3 c = *reinterpret_cast<const float3*>(p + 3 * (base + j));
          mv = sqq + (c.x * c.x + c.y * c.y + c.z * c.z)
             - 2.0f * (qx * c.x + qy * c.y + qz * c.z);
          mi = j;
        } else { mv = kFltMax; mi = 0x7fffffff; }
      }
      bitonic64(mv, mi, lane);
      sv = mv; si = mi;
    }
  }
  if (lane < 16) {
    int out = si;
    if ((unsigned)out >= (unsigned)kN) out = 0;  // safety net: wrong beats fault
    idxf[q * 16 + lane] = out;
  }
}

// ---------------- fused MFMA attention v4 ----------------
// v3 + (a) VV row-major [row][68] fp32: b128 writes/RMW, 2-way-free scalar
// reads in softmax; (b) H pre-packed to bf16 dwords once, repack = 2 shfl +
// 1 select per dword; (c) cheap half-up bf16 packing everywhere.
__global__ __launch_bounds__(256) void attn_mfma4_kernel(
    const float* __restrict__ p, const unsigned short* __restrict__ qkv,
    const int* __restrict__ idxf,
    const float* __restrict__ pos_w1, const float* __restrict__ pos_b1,
    const float* __restrict__ pos_b2,
    const float* __restrict__ attn_b1, const float* __restrict__ attn_b2,
    const unsigned short* __restrict__ w1f,
    const unsigned short* __restrict__ w2f,
    const unsigned short* __restrict__ pw2t,
    float* __restrict__ agg) {
  __shared__ unsigned short Ulds[64 * 72];   // [row][c] bf16, stride 72
  __shared__ float VVlds[64 * 68];           // [row][c] fp32, stride 68

  const int t = threadIdx.x;
  const int lane = t & 63, w = t >> 6;
  const int l = lane & 15, q = lane >> 4;
  const int work = ((blockIdx.x & 7) << 9) | (blockIdx.x >> 3);  // XCD swizzle
  const int b = work >> 10;
  const int n0 = (work & 1023) * 4;
  const int pt_row = b * kN + n0 + w;
  const f32x4 zero = {0.f, 0.f, 0.f, 0.f};

  int idxv = 0;
  if (lane < 16) idxv = idxf[(work * 4 + w) * 16 + lane];

  // phase 1a: gather k/v (bf16); U = bf16(q - k); VV[row][c] = v
  {
    const int r = lane >> 2, seg = lane & 3;
    const unsigned short* jrow = qkv + (b * kN + __shfl(idxv, r)) * 192;
    const int c0 = seg * 16;
    uint4 k0 = *reinterpret_cast<const uint4*>(jrow + 64 + c0);
    uint4 k1 = *reinterpret_cast<const uint4*>(jrow + 64 + c0 + 8);
    uint4 v0 = *reinterpret_cast<const uint4*>(jrow + 128 + c0);
    uint4 v1 = *reinterpret_cast<const uint4*>(jrow + 128 + c0 + 8);
    uint4 q0 = *reinterpret_cast<const uint4*>(qkv + pt_row * 192 + c0);
    uint4 q1 = *reinterpret_cast<const uint4*>(qkv + pt_row * 192 + c0 + 8);
    auto diff2 = [](unsigned int qu, unsigned int ku) -> unsigned int {
      float lo = __uint_as_float(qu << 16) - __uint_as_float(ku << 16);
      float hi = __uint_as_float(qu & 0xffff0000u) - __uint_as_float(ku & 0xffff0000u);
      return pkbf(lo, hi);
    };
    uint4 u0, u1;
    u0.x = diff2(q0.x, k0.x); u0.y = diff2(q0.y, k0.y);
    u0.z = diff2(q0.z, k0.z); u0.w = diff2(q0.w, k0.w);
    u1.x = diff2(q1.x, k1.x); u1.y = diff2(q1.y, k1.y);
    u1.z = diff2(q1.z, k1.z); u1.w = diff2(q1.w, k1.w);
    *reinterpret_cast<uint4*>(&Ulds[(w * 16 + r) * 72 + c0]) = u0;
    *reinterpret_cast<uint4*>(&Ulds[(w * 16 + r) * 72 + c0 + 8]) = u1;
    const unsigned int vs[8] = {v0.x, v0.y, v0.z, v0.w, v1.x, v1.y, v1.z, v1.w};
    #pragma unroll
    for (int i = 0; i < 4; ++i) {
      float4 vv;
      vv.x = __uint_as_float(vs[2 * i] << 16);
      vv.y = __uint_as_float(vs[2 * i] & 0xffff0000u);
      vv.z = __uint_as_float(vs[2 * i + 1] << 16);
      vv.w = __uint_as_float(vs[2 * i + 1] & 0xffff0000u);
      *reinterpret_cast<float4*>(&VVlds[(w * 16 + r) * 68 + c0 + 4 * i]) = vv;
    }
  }
  // phase 1b: pe hidden (3->32) for row l, chunk q*8 — registers only
  short8 pbf;
  {
    const float3 pn = *reinterpret_cast<const float3*>(p + pt_row * 3);
    const int nj = __shfl(idxv, l);
    const float3 pj = *reinterpret_cast<const float3*>(p + (b * kN + nj) * 3);
    float rx = pn.x - pj.x, ry = pn.y - pj.y, rz = pn.z - pj.z;
    float hv[8];
    #pragma unroll
    for (int j = 0; j < 8; ++j) {
      int hh = q * 8 + j;
      hv[j] = fmaxf(pos_b1[hh] + rx * pos_w1[hh] + ry * pos_w1[32 + hh] +
                    rz * pos_w1[64 + hh], 0.0f);
    }
    union { unsigned int u[4]; short8 s; } pk;
    #pragma unroll
    for (int ii = 0; ii < 4; ++ii) pk.u[ii] = pkbf(hv[2 * ii], hv[2 * ii + 1]);
    pbf = pk.s;
  }

  // phase 2: pe = pehid @ pos_w2 (transposed MFMA, D[c][row]); RMW U and VV
  {
    const int urow = (w * 16 + l) * 72;
    const int vrow = (w * 16 + l) * 68;
    #pragma unroll
    for (int mt = 0; mt < 4; ++mt) {
      short8 paf = *reinterpret_cast<const short8*>(&pw2t[(mt * 16 + l) * 32 + q * 8]);
      f32x4 pe = __builtin_amdgcn_mfma_f32_16x16x32_bf16(paf, pbf, zero, 0, 0, 0);
      const int c0 = mt * 16 + q * 4;
      float4 b2v = *reinterpret_cast<const float4*>(&pos_b2[c0]);
      float pe0 = pe[0] + b2v.x, pe1 = pe[1] + b2v.y;
      float pe2 = pe[2] + b2v.z, pe3 = pe[3] + b2v.w;
      uint2 u2 = *reinterpret_cast<uint2*>(&Ulds[urow + c0]);
      uint2 o;
      o.x = pkbf(__uint_as_float(u2.x << 16) + pe0,
                 __uint_as_float(u2.x & 0xffff0000u) + pe1);
      o.y = pkbf(__uint_as_float(u2.y << 16) + pe2,
                 __uint_as_float(u2.y & 0xffff0000u) + pe3);
      *reinterpret_cast<uint2*>(&Ulds[urow + c0]) = o;
      float4 vv = *reinterpret_cast<float4*>(&VVlds[vrow + c0]);
      vv.x += pe0; vv.y += pe1; vv.z += pe2; vv.w += pe3;
      *reinterpret_cast<float4*>(&VVlds[vrow + c0]) = vv;
    }
  }

  // phase 3: GEMM1 transposed; H packed to bf16 dwords immediately
  unsigned int plo[16], phi[16];
  {
    const int urow = (w * 16 + l) * 72;
    short8 ub0 = *reinterpret_cast<const short8*>(&Ulds[urow + q * 8]);
    short8 ub1 = *reinterpret_cast<const short8*>(&Ulds[urow + 32 + q * 8]);
    #pragma unroll
    for (int mt = 0; mt < 16; ++mt) {
      short8 a0 = *reinterpret_cast<const short8*>(&w1f[(mt * 2 + 0) * 512 + lane * 8]);
      short8 a1 = *reinterpret_cast<const short8*>(&w1f[(mt * 2 + 1) * 512 + lane * 8]);
      f32x4 acc = __builtin_amdgcn_mfma_f32_16x16x32_bf16(a0, ub0, zero, 0, 0, 0);
      acc = __builtin_amdgcn_mfma_f32_16x16x32_bf16(a1, ub1, acc, 0, 0, 0);
      float4 bb = *reinterpret_cast<const float4*>(&attn_b1[mt * 16 + q * 4]);
      plo[mt] = pkbf(fmaxf(acc[0] + bb.x, 0.f), fmaxf(acc[1] + bb.y, 0.f));
      phi[mt] = pkbf(fmaxf(acc[2] + bb.z, 0.f), fmaxf(acc[3] + bb.w, 0.f));
    }
  }

  // phase 4: GEMM2 via cheap repack (2 shfl + 1 select per dword)
  {
    f32x4 acc2[4];
    #pragma unroll
    for (int ct = 0; ct < 4; ++ct) acc2[ct] = zero;
    const int sbase = l + 32 * (q & 1);   // + 16*(d>>1)
    const bool hi_mt = (q >= 2);
    #pragma unroll
    for (int f = 0; f < 8; ++f) {
      union { unsigned int u[4]; short8 s; } pk;
      #pragma unroll
      for (int d = 0; d < 4; ++d) {
        const int src = sbase + ((d >> 1) << 4);
        const unsigned int w0 = (d & 1) ? phi[2 * f] : plo[2 * f];
        const unsigned int w1v = (d & 1) ? phi[2 * f + 1] : plo[2 * f + 1];
        unsigned int va = (unsigned int)__shfl((int)w0, src);
        unsigned int vb = (unsigned int)__shfl((int)w1v, src);
        pk.u[d] = hi_mt ? vb : va;
      }
      short8 afr = pk.s;
      #pragma unroll
      for (int ct = 0; ct < 4; ++ct) {
        short8 bfr = *reinterpret_cast<const short8*>(&w2f[((ct * 8 + f) * 64 + lane) * 8]);
        acc2[ct] = __builtin_amdgcn_mfma_f32_16x16x32_bf16(afr, bfr, acc2[ct], 0, 0, 0);
      }
    }
    #pragma unroll
    for (int ct = 0; ct < 4; ++ct) {
      const int ch = ct * 16 + l;
      const float bv = attn_b2[ch];
      float s0v = acc2[ct][0] + bv, s1v = acc2[ct][1] + bv;
      float s2v = acc2[ct][2] + bv, s3v = acc2[ct][3] + bv;
      float mx = fmaxf(fmaxf(s0v, s1v), fmaxf(s2v, s3v));
      mx = fmaxf(mx, __shfl_xor(mx, 16, 64));
      mx = fmaxf(mx, __shfl_xor(mx, 32, 64));
      float e0 = __expf(s0v - mx), e1 = __expf(s1v - mx);
      float e2 = __expf(s2v - mx), e3 = __expf(s3v - mx);
      float se = e0 + e1 + e2 + e3;
      se += __shfl_xor(se, 16, 64);
      se += __shfl_xor(se, 32, 64);
      const int vbase = (w * 16 + q * 4) * 68 + ch;
      float a = e0 * VVlds[vbase] + e1 * VVlds[vbase + 68] +
                e2 * VVlds[vbase + 136] + e3 * VVlds[vbase + 204];
      a += __shfl_xor(a, 16, 64);
      a += __shfl_xor(a, 32, 64);
      if (q == 0) agg[(work * 4 + w) * 64 + ch] = a / se;
    }
  }
}

// ---------------- fc2 (MFMA) with fused bn2+relu+residual prologue ----------------
__global__ __launch_bounds__(256) void fc2_mfma_kernel(
    const float* __restrict__ aggp, const float* __restrict__ hres,
    const float* __restrict__ A2, const float* __restrict__ B2,
    const unsigned short* __restrict__ fc2f, const float* __restrict__ bias,
    float* __restrict__ z) {
  const int t = threadIdx.x, lane = t & 63, wv = t >> 6;
  const int l = lane & 15, q = lane >> 4;
  const int r0 = blockIdx.x * 64;
  const int row = r0 + wv * 16 + l;
  const f32x4 zero = {0.f, 0.f, 0.f, 0.f};
  short8 af[2];
  #pragma unroll
  for (int hh = 0; hh < 2; ++hh) {
    const int c0 = 32 * hh + q * 8;
    float4 v0 = *reinterpret_cast<const float4*>(&aggp[row * 64 + c0]);
    float4 v1 = *reinterpret_cast<const float4*>(&aggp[row * 64 + c0 + 4]);
    float4 r0v = *reinterpret_cast<const float4*>(&hres[row * 64 + c0]);
    float4 r1v = *reinterpret_cast<const float4*>(&hres[row * 64 + c0 + 4]);
    float4 Aa = *reinterpret_cast<const float4*>(&A2[c0]);
    float4 Ab = *reinterpret_cast<const float4*>(&A2[c0 + 4]);
    float4 Ba = *reinterpret_cast<const float4*>(&B2[c0]);
    float4 Bb = *reinterpret_cast<const float4*>(&B2[c0 + 4]);
    v0.x = fmaxf(Aa.x * v0.x + Ba.x, 0.f) + r0v.x;
    v0.y = fmaxf(Aa.y * v0.y + Ba.y, 0.f) + r0v.y;
    v0.z = fmaxf(Aa.z * v0.z + Ba.z, 0.f) + r0v.z;
    v0.w = fmaxf(Aa.w * v0.w + Ba.w, 0.f) + r0v.w;
    v1.x = fmaxf(Ab.x * v1.x + Bb.x, 0.f) + r1v.x;
    v1.y = fmaxf(Ab.y * v1.y + Bb.y, 0.f) + r1v.y;
    v1.z = fmaxf(Ab.z * v1.z + Bb.z, 0.f) + r1v.z;
    v1.w = fmaxf(Ab.w * v1.w + Bb.w, 0.f) + r1v.w;
    af[hh] = pack8f(v0, v1);
  }
  #pragma unroll
  for (int ct = 0; ct < 4; ++ct) {
    short8 b0 = *reinterpret_cast<const short8*>(&fc2f[((ct * 2 + 0) * 64 + lane) * 8]);
    short8 b1 = *reinterpret_cast<const short8*>(&fc2f[((ct * 2 + 1) * 64 + lane) * 8]);
    f32x4 acc = __builtin_amdgcn_mfma_f32_16x16x32_bf16(af[0], b0, zero, 0, 0, 0);
    acc = __builtin_amdgcn_mfma_f32_16x16x32_bf16(af[1], b1, acc, 0, 0, 0);
    const float bc = bias[ct * 16 + l];
    #pragma unroll
    for (int i = 0; i < 4; ++i)
      z[(r0 + wv * 16 + q * 4 + i) * 64 + ct * 16 + l] = acc[i] + bc;
  }
}

// ---------------- final bn3+relu, fused p-copy ----------------
__global__ void final_kernel(const float* __restrict__ z, const float* __restrict__ A3,
                             const float* __restrict__ B3, const float* __restrict__ p,
                             float* __restrict__ y) {
  const int blk = blockIdx.x, t = threadIdx.x;
  if (blk < 4096) {
    int i = blk * 256 + t;
    int c = i & 63;
    y[i] = fmaxf(A3[c] * z[i] + B3[c], 0.0f);
  } else {
    int i = (blk - 4096) * 256 + t;
    y[1048576 + i] = p[i];
  }
}

extern "C" void kernel_launch(void* const* d_in, const int* in_sizes, int n_in,
                              void* d_out, int out_size, void* d_ws, size_t ws_size,
                              hipStream_t stream) {
  const float* x       = (const float*)d_in[0];
  const float* p       = (const float*)d_in[1];
  const float* fc1_w   = (const float*)d_in[2];
  const float* fc1_b   = (const float*)d_in[3];
  const float* bn1_g   = (const float*)d_in[4];
  const float* bn1_b   = (const float*)d_in[5];
  const float* qkv_w   = (const float*)d_in[6];
  const float* pos_w1  = (const float*)d_in[7];
  const float* pos_b1  = (const float*)d_in[8];
  const float* pos_w2  = (const float*)d_in[9];
  const float* pos_b2  = (const float*)d_in[10];
  const float* attn_w1 = (const float*)d_in[11];
  const float* attn_b1 = (const float*)d_in[12];
  const float* attn_w2 = (const float*)d_in[13];
  const float* attn_b2 = (const float*)d_in[14];
  const float* bn2_g   = (const float*)d_in[15];
  const float* bn2_b   = (const float*)d_in[16];
  const float* fc2_w   = (const float*)d_in[17];
  const float* fc2_b   = (const float*)d_in[18];
  const float* bn3_g   = (const float*)d_in[19];
  const float* bn3_b   = (const float*)d_in[20];

  float* ws   = (float*)d_ws;
  float* h    = ws;                     // residual, fp32
  unsigned short* qkvb = (unsigned short*)(ws + 1048576);  // bf16 [16384][192]
  float* hpre = ws + 4194304;
  float* aggv = ws + 5242880;           // also stats partials 1,3
  float* z    = ws + 6291456;           // also stats partials 2
  float* st   = ws + 7340032;           // A1,B1,A2,B2,A3,B3
  int*   idxf = (int*)(ws + 7356800);
  unsigned short* wpak = (unsigned short*)(ws + 7618944);
  unsigned short* w1f  = wpak;
  unsigned short* w2f  = wpak + 16384;
  unsigned short* pw2t = wpak + 32768;
  unsigned short* wqf  = wpak + 34816;
  unsigned short* fc2f = wpak + 47104;

  float* A1 = st,       *B1 = st + 64;
  float* A2 = st + 128, *B2 = st + 192;
  float* A3 = st + 256, *B3 = st + 320;
  float* y = (float*)d_out;

  fc1_conv_kernel<<<256, 256, 0, stream>>>(x, fc1_w, fc1_b, attn_w1, attn_w2,
                                           pos_w2, qkv_w, fc2_w, wpak, hpre);
  stats_part_kernel<<<256, 256, 0, stream>>>(hpre, aggv);
  stats_fin_kernel<<<1, 64, 0, stream>>>(aggv, bn1_g, bn1_b, A1, B1);
  qkv_bn_kernel<<<256, 256, 0, stream>>>(hpre, A1, B1, wqf, h, qkvb);
  knn_kernel<<<4096, 256, 0, stream>>>(p, idxf);
  attn_mfma4_kernel<<<4096, 256, 0, stream>>>(p, qkvb, idxf, pos_w1, pos_b1, pos_b2,
                                              attn_b1, attn_b2, w1f, w2f, pw2t, aggv);
  stats_part_kernel<<<256, 256, 0, stream>>>(aggv, z);
  stats_fin_kernel<<<1, 64, 0, stream>>>(z, bn2_g, bn2_b, A2, B2);
  fc2_mfma_kernel<<<256, 256, 0, stream>>>(aggv, h, A2, B2, fc2f, fc2_b, z);
  stats_part_kernel<<<256, 256, 0, stream>>>(z, aggv);
  stats_fin_kernel<<<1, 64, 0, stream>>>(aggv, bn3_g, bn3_b, A3, B3);
  final_kernel<<<4288, 256, 0, stream>>>(z, A3, B3, p, y);
}